// Round 1
// baseline (3469.966 us; speedup 1.0000x reference)
//
#include <hip/hip_runtime.h>

#define DD 1024
#define NHH 16
#define HDD 64
#define BB 2
#define LL 2048
#define MM (BB*LL)          // 4096 rows
#define HG 256
#define HN 128

#define LOG_FAST 0.48121182f   // ln((1+sqrt(5))/2)
#define LOG_SLOW 7.3889461f    // ln(1618.0)
#define LOG_GLU  9.6915312f    // ln(16180.0)

__device__ __forceinline__ float gelu_f(float x) {
    return 0.5f * x * (1.0f + erff(x * 0.70710678f));
}

// ---------------- 1. causal cumulative mean pool ----------------
__global__ void pool_kernel(const float* __restrict__ z, float* __restrict__ pool) {
    int col = blockIdx.x * 256 + threadIdx.x;   // b*DD + d
    int b = col >> 10, d = col & 1023;
    const float* zp = z + ((size_t)b * LL) * DD + d;
    float* pp = pool + ((size_t)b * LL) * DD + d;
    float sum = 0.f;
    for (int t = 0; t < LL; ++t) {
        sum += zp[(size_t)t * DD];
        pp[(size_t)t * DD] = sum / (float)(t + 1);
    }
}

// ---------------- generic fp32 GEMM: C = A@W (+bias), 128x128 tile ----------------
__global__ __launch_bounds__(256) void gemm_kernel(
        const float* __restrict__ A, const float* __restrict__ W,
        const float* __restrict__ bias, float* __restrict__ C,
        int Kdim, int Ndim) {
    __shared__ float As[16][132];
    __shared__ float Bs[16][132];
    int tid = threadIdx.x;
    int n0 = blockIdx.x * 128, m0 = blockIdx.y * 128;
    int ty = tid >> 4, tx = tid & 15;
    float acc[8][8];
#pragma unroll
    for (int u = 0; u < 8; ++u)
#pragma unroll
        for (int v = 0; v < 8; ++v) acc[u][v] = 0.f;

    int arow = tid >> 1;
    int acol = (tid & 1) * 8;
    int wrow = tid >> 4;
    int wcol = (tid & 15) * 8;

    for (int kb = 0; kb < Kdim; kb += 16) {
        const float* Ap = A + (size_t)(m0 + arow) * Kdim + kb + acol;
        float4 a0 = *(const float4*)Ap;
        float4 a1 = *(const float4*)(Ap + 4);
        As[acol + 0][arow] = a0.x; As[acol + 1][arow] = a0.y;
        As[acol + 2][arow] = a0.z; As[acol + 3][arow] = a0.w;
        As[acol + 4][arow] = a1.x; As[acol + 5][arow] = a1.y;
        As[acol + 6][arow] = a1.z; As[acol + 7][arow] = a1.w;
        const float* Wp = W + (size_t)(kb + wrow) * Ndim + n0 + wcol;
        *(float4*)&Bs[wrow][wcol]     = *(const float4*)Wp;
        *(float4*)&Bs[wrow][wcol + 4] = *(const float4*)(Wp + 4);
        __syncthreads();
#pragma unroll
        for (int k = 0; k < 16; ++k) {
            float a[8], bb2[8];
            *(float4*)&a[0]   = *(const float4*)&As[k][ty * 8];
            *(float4*)&a[4]   = *(const float4*)&As[k][ty * 8 + 4];
            *(float4*)&bb2[0] = *(const float4*)&Bs[k][tx * 8];
            *(float4*)&bb2[4] = *(const float4*)&Bs[k][tx * 8 + 4];
#pragma unroll
            for (int u = 0; u < 8; ++u)
#pragma unroll
                for (int v = 0; v < 8; ++v)
                    acc[u][v] += a[u] * bb2[v];
        }
        __syncthreads();
    }
    float bb[8];
    if (bias) {
        *(float4*)&bb[0] = *(const float4*)&bias[n0 + tx * 8];
        *(float4*)&bb[4] = *(const float4*)&bias[n0 + tx * 8 + 4];
    } else {
#pragma unroll
        for (int v = 0; v < 8; ++v) bb[v] = 0.f;
    }
#pragma unroll
    for (int u = 0; u < 8; ++u) {
        float* Cp = C + (size_t)(m0 + ty * 8 + u) * Ndim + n0 + tx * 8;
        float4 o0, o1;
        o0.x = acc[u][0] + bb[0]; o0.y = acc[u][1] + bb[1];
        o0.z = acc[u][2] + bb[2]; o0.w = acc[u][3] + bb[3];
        o1.x = acc[u][4] + bb[4]; o1.y = acc[u][5] + bb[5];
        o1.z = acc[u][6] + bb[6]; o1.w = acc[u][7] + bb[7];
        *(float4*)Cp = o0;
        *(float4*)(Cp + 4) = o1;
    }
}

// ---------------- gb = tanh(gamma)*d^-0.5 * gk @ K^T (causal-lower tiles only) ----------------
__global__ __launch_bounds__(256) void gb_kernel(
        const float* __restrict__ gk, const float* __restrict__ Kmat,
        const float* __restrict__ gamma, float* __restrict__ gb) {
    int lt = blockIdx.x >> 5, mt = blockIdx.x & 31;
    if (mt > lt) return;
    int b = blockIdx.y;
    __shared__ float As[32][68];
    __shared__ float Bs[32][68];
    int tid = threadIdx.x;
    int ty = tid >> 4, tx = tid & 15;
    int l0 = lt * 64, m0 = mt * 64;
    float acc[4][4];
#pragma unroll
    for (int u = 0; u < 4; ++u)
#pragma unroll
        for (int v = 0; v < 4; ++v) acc[u][v] = 0.f;
    int arow = tid >> 2, acol = (tid & 3) * 8;
    const float* Abase = gk   + ((size_t)b * LL + l0 + arow) * DD + acol;
    const float* Bbase = Kmat + ((size_t)b * LL + m0 + arow) * DD + acol;
    for (int kb = 0; kb < DD; kb += 32) {
        float4 a0 = *(const float4*)(Abase + kb);
        float4 a1 = *(const float4*)(Abase + kb + 4);
        As[acol + 0][arow] = a0.x; As[acol + 1][arow] = a0.y;
        As[acol + 2][arow] = a0.z; As[acol + 3][arow] = a0.w;
        As[acol + 4][arow] = a1.x; As[acol + 5][arow] = a1.y;
        As[acol + 6][arow] = a1.z; As[acol + 7][arow] = a1.w;
        float4 b0 = *(const float4*)(Bbase + kb);
        float4 b1 = *(const float4*)(Bbase + kb + 4);
        Bs[acol + 0][arow] = b0.x; Bs[acol + 1][arow] = b0.y;
        Bs[acol + 2][arow] = b0.z; Bs[acol + 3][arow] = b0.w;
        Bs[acol + 4][arow] = b1.x; Bs[acol + 5][arow] = b1.y;
        Bs[acol + 6][arow] = b1.z; Bs[acol + 7][arow] = b1.w;
        __syncthreads();
#pragma unroll 8
        for (int k = 0; k < 32; ++k) {
            float4 av = *(const float4*)&As[k][ty * 4];
            float4 bv = *(const float4*)&Bs[k][tx * 4];
            float aa[4] = {av.x, av.y, av.z, av.w};
            float ba[4] = {bv.x, bv.y, bv.z, bv.w};
#pragma unroll
            for (int u = 0; u < 4; ++u)
#pragma unroll
                for (int v = 0; v < 4; ++v)
                    acc[u][v] += aa[u] * ba[v];
        }
        __syncthreads();
    }
    float scale = tanhf(gamma[0]) * 0.03125f;   // d^-0.5 = 1/32
#pragma unroll
    for (int u = 0; u < 4; ++u) {
        float4 o;
        o.x = acc[u][0] * scale; o.y = acc[u][1] * scale;
        o.z = acc[u][2] * scale; o.w = acc[u][3] * scale;
        *(float4*)&gb[((size_t)b * LL + l0 + ty * 4 + u) * LL + m0 + tx * 4] = o;
    }
}

// ---------------- gate finisher: gate = sigmoid(gelu(H1) @ w2 + b2) ----------------
__global__ __launch_bounds__(256) void gate_fin_kernel(
        const float* __restrict__ H1, const float* __restrict__ w2,
        const float* __restrict__ b2, float* __restrict__ gate) {
    int row = blockIdx.x, tid = threadIdx.x;
    float x = H1[(size_t)row * HG + tid];
    float val = gelu_f(x) * w2[tid];
    for (int off = 32; off; off >>= 1) val += __shfl_down(val, off);
    __shared__ float part[4];
    if ((tid & 63) == 0) part[tid >> 6] = val;
    __syncthreads();
    if (tid == 0) {
        float acc = part[0] + part[1] + part[2] + part[3] + b2[0];
        gate[row] = 1.f / (1.f + expf(-acc));
    }
}

// ---------------- nu finisher ----------------
__global__ __launch_bounds__(128) void nu_fin_kernel(
        const float* __restrict__ N1, const float* __restrict__ w2,
        const float* __restrict__ b2, const float* __restrict__ nu_diff,
        const float* __restrict__ nu_adv, float* __restrict__ nub) {
    int row = blockIdx.x, tid = threadIdx.x;
    float t = tanhf(N1[(size_t)row * HN + tid]);
    float val = t * w2[tid];
    for (int off = 32; off; off >>= 1) val += __shfl_down(val, off);
    __shared__ float part[2];
    if ((tid & 63) == 0) part[tid >> 6] = val;
    __syncthreads();
    if (tid == 0) {
        float acc = part[0] + part[1] + b2[0];
        nub[row] = fabsf(nu_diff[0]) + tanhf(acc) * fabsf(nu_adv[0]);
    }
}

// ---------------- gated dual-base RoPE on Q and K (in place) ----------------
__global__ void rope_qk_kernel(float* __restrict__ Q, float* __restrict__ K,
                               const float* __restrict__ gate) {
    int idx = blockIdx.x * 256 + threadIdx.x;   // over MM*512
    int row = idx >> 9;
    int i = idx & 511;
    int t = row & (LL - 1);
    float g = gate[row];
    float fi = (float)i * (1.0f / 512.0f);
    float tf = (float)t;
    float af = tf * expf(-fi * LOG_FAST);
    float as = tf * expf(-fi * LOG_SLOW);
    float c = g * cosf(af) + (1.f - g) * cosf(as);
    float s = g * sinf(af) + (1.f - g) * sinf(as);
    size_t base = (size_t)row * DD;
    float x = Q[base + i], y = Q[base + 512 + i];
    Q[base + i]       = x * c - y * s;
    Q[base + 512 + i] = y * c + x * s;
    x = K[base + i]; y = K[base + 512 + i];
    K[base + i]       = x * c - y * s;
    K[base + 512 + i] = y * c + x * s;
}

// ---------------- fixed-base RoPE for GLU branch: zg = rope(z) ----------------
__global__ void rope_glu_kernel(const float* __restrict__ z, float* __restrict__ zg) {
    int idx = blockIdx.x * 256 + threadIdx.x;
    int row = idx >> 9;
    int i = idx & 511;
    int t = row & (LL - 1);
    float fi = (float)i * (1.0f / 512.0f);
    float ag = (float)t * expf(-fi * LOG_GLU);
    float c = cosf(ag), s = sinf(ag);
    size_t base = (size_t)row * DD;
    float x = z[base + i], y = z[base + 512 + i];
    zg[base + i]       = x * c - y * s;
    zg[base + 512 + i] = y * c + x * s;
}

// ---------------- flash attention (per b,h,q-tile of 64; K-tiles of 32) ----------------
__global__ __launch_bounds__(256) void attn_flash_kernel(
        const float* __restrict__ Q, const float* __restrict__ K,
        const float* __restrict__ V, const float* __restrict__ gb,
        float* __restrict__ attn_out, float* __restrict__ stats) {
    int qt = blockIdx.x, h = blockIdx.y, b = blockIdx.z;
    __shared__ float Qs[64][68];
    __shared__ float Ks[32][68];
    __shared__ float Vs[32][68];
    __shared__ float Ps[64][36];
    __shared__ float redm[64][17];
    __shared__ float reds[64][17];
    int tid = threadIdx.x;
    int ty = tid >> 4, tx = tid & 15;
    int q0 = qt * 64;
    {
        int i = tid >> 2, d0 = (tid & 3) * 16;
        const float* Qp = Q + ((size_t)(b * LL) + q0 + i) * DD + h * 64 + d0;
        float4 v0 = *(const float4*)Qp;
        float4 v1 = *(const float4*)(Qp + 4);
        float4 v2 = *(const float4*)(Qp + 8);
        float4 v3 = *(const float4*)(Qp + 12);
        *(float4*)&Qs[i][d0]      = v0;
        *(float4*)&Qs[i][d0 + 4]  = v1;
        *(float4*)&Qs[i][d0 + 8]  = v2;
        *(float4*)&Qs[i][d0 + 12] = v3;
    }
    float o[4][4];
    float m_r[4], s_r[4];
#pragma unroll
    for (int u = 0; u < 4; ++u) {
        m_r[u] = -3e38f; s_r[u] = 0.f;
#pragma unroll
        for (int v = 0; v < 4; ++v) o[u][v] = 0.f;
    }
    const float* gbb = gb + (size_t)b * LL * LL;
    int ktmax = 2 * qt + 1;
    for (int kt = 0; kt <= ktmax; ++kt) {
        int k0 = kt * 32;
        __syncthreads();   // protects Ks/Vs/Ps/red reuse
        {
            int i = tid >> 3, d0 = (tid & 7) * 8;
            const float* Kp = K + ((size_t)(b * LL) + k0 + i) * DD + h * 64 + d0;
            const float* Vp = V + ((size_t)(b * LL) + k0 + i) * DD + h * 64 + d0;
            float4 k0v = *(const float4*)Kp;
            float4 k1v = *(const float4*)(Kp + 4);
            float4 v0v = *(const float4*)Vp;
            float4 v1v = *(const float4*)(Vp + 4);
            *(float4*)&Ks[i][d0]     = k0v;
            *(float4*)&Ks[i][d0 + 4] = k1v;
            *(float4*)&Vs[i][d0]     = v0v;
            *(float4*)&Vs[i][d0 + 4] = v1v;
        }
        __syncthreads();
        float sv[4][2];
#pragma unroll
        for (int u = 0; u < 4; ++u) { sv[u][0] = 0.f; sv[u][1] = 0.f; }
#pragma unroll 8
        for (int k4 = 0; k4 < 16; ++k4) {
            float4 qa[4], ka[2];
#pragma unroll
            for (int u = 0; u < 4; ++u) qa[u] = *(const float4*)&Qs[ty * 4 + u][k4 * 4];
#pragma unroll
            for (int v = 0; v < 2; ++v) ka[v] = *(const float4*)&Ks[tx * 2 + v][k4 * 4];
#pragma unroll
            for (int u = 0; u < 4; ++u)
#pragma unroll
                for (int v = 0; v < 2; ++v)
                    sv[u][v] += qa[u].x * ka[v].x + qa[u].y * ka[v].y
                              + qa[u].z * ka[v].z + qa[u].w * ka[v].w;
        }
        float smv[4][2];
#pragma unroll
        for (int u = 0; u < 4; ++u) {
            int qg = q0 + ty * 4 + u;
            const float* gbp = gbb + (size_t)qg * LL + k0 + tx * 2;
#pragma unroll
            for (int v = 0; v < 2; ++v) {
                int kg = k0 + tx * 2 + v;
                float sval = sv[u][v] * 0.125f + gbp[v];
                smv[u][v] = (kg <= qg) ? sval : -1e30f;
            }
            redm[ty * 4 + u][tx] = fmaxf(smv[u][0], smv[u][1]);
        }
        __syncthreads();
        float newm[4], alpha[4];
#pragma unroll
        for (int u = 0; u < 4; ++u) {
            float mx = m_r[u];
#pragma unroll
            for (int j = 0; j < 16; ++j) mx = fmaxf(mx, redm[ty * 4 + u][j]);
            newm[u] = mx;
            alpha[u] = expf(m_r[u] - mx);
        }
#pragma unroll
        for (int u = 0; u < 4; ++u) {
            int qg = q0 + ty * 4 + u;
            float p0 = (k0 + tx * 2 + 0 <= qg) ? expf(smv[u][0] - newm[u]) : 0.f;
            float p1 = (k0 + tx * 2 + 1 <= qg) ? expf(smv[u][1] - newm[u]) : 0.f;
            Ps[ty * 4 + u][tx * 2 + 0] = p0;
            Ps[ty * 4 + u][tx * 2 + 1] = p1;
            reds[ty * 4 + u][tx] = p0 + p1;
        }
        __syncthreads();
#pragma unroll
        for (int u = 0; u < 4; ++u) {
            float ssum = 0.f;
#pragma unroll
            for (int j = 0; j < 16; ++j) ssum += reds[ty * 4 + u][j];
            s_r[u] = s_r[u] * alpha[u] + ssum;
            m_r[u] = newm[u];
            o[u][0] *= alpha[u]; o[u][1] *= alpha[u];
            o[u][2] *= alpha[u]; o[u][3] *= alpha[u];
        }
#pragma unroll 8
        for (int m = 0; m < 32; ++m) {
            float a0 = Ps[ty * 4 + 0][m];
            float a1 = Ps[ty * 4 + 1][m];
            float a2 = Ps[ty * 4 + 2][m];
            float a3 = Ps[ty * 4 + 3][m];
            float4 bv = *(const float4*)&Vs[m][tx * 4];
            o[0][0] += a0 * bv.x; o[0][1] += a0 * bv.y; o[0][2] += a0 * bv.z; o[0][3] += a0 * bv.w;
            o[1][0] += a1 * bv.x; o[1][1] += a1 * bv.y; o[1][2] += a1 * bv.z; o[1][3] += a1 * bv.w;
            o[2][0] += a2 * bv.x; o[2][1] += a2 * bv.y; o[2][2] += a2 * bv.z; o[2][3] += a2 * bv.w;
            o[3][0] += a3 * bv.x; o[3][1] += a3 * bv.y; o[3][2] += a3 * bv.z; o[3][3] += a3 * bv.w;
        }
    }
#pragma unroll
    for (int u = 0; u < 4; ++u) {
        float rinv = 1.0f / s_r[u];
        float4 ov;
        ov.x = o[u][0] * rinv; ov.y = o[u][1] * rinv;
        ov.z = o[u][2] * rinv; ov.w = o[u][3] * rinv;
        *(float4*)&attn_out[((size_t)(b * LL) + q0 + ty * 4 + u) * DD + h * 64 + tx * 4] = ov;
    }
    if (tx == 0) {
#pragma unroll
        for (int u = 0; u < 4; ++u) {
            size_t si = (((size_t)b * NHH + h) * LL + q0 + ty * 4 + u) * 2;
            stats[si]     = m_r[u];
            stats[si + 1] = s_r[u];
        }
    }
}

// ---------------- attn_w = mean over heads of softmax probs (recompute from stats) ----------------
__global__ __launch_bounds__(256) void attn_w_kernel(
        const float* __restrict__ Q, const float* __restrict__ K,
        const float* __restrict__ gb, const float* __restrict__ stats,
        float* __restrict__ aw) {
    int qt = blockIdx.x >> 5, kt = blockIdx.x & 31;
    int b = blockIdx.y;
    int tid = threadIdx.x;
    int ty = tid >> 4, tx = tid & 15;
    int q0 = qt * 64, k0 = kt * 64;
    if (kt > qt) {
        float4 zv = make_float4(0.f, 0.f, 0.f, 0.f);
#pragma unroll
        for (int u = 0; u < 4; ++u)
            *(float4*)&aw[((size_t)(b * LL) + q0 + ty * 4 + u) * LL + k0 + tx * 4] = zv;
        return;
    }
    __shared__ float Qs[64][68];
    __shared__ float Ks[64][68];
    __shared__ float sm[64], ssm[64];
    float acc[4][4];
    float gbt[4][4];
#pragma unroll
    for (int u = 0; u < 4; ++u) {
        float4 g4 = *(const float4*)&gb[((size_t)b * LL + q0 + ty * 4 + u) * LL + k0 + tx * 4];
        gbt[u][0] = g4.x; gbt[u][1] = g4.y; gbt[u][2] = g4.z; gbt[u][3] = g4.w;
#pragma unroll
        for (int v = 0; v < 4; ++v) acc[u][v] = 0.f;
    }
    for (int h = 0; h < NHH; ++h) {
        __syncthreads();
        {
            int i = tid >> 2, d0 = (tid & 3) * 16;
            const float* Qp = Q + ((size_t)(b * LL) + q0 + i) * DD + h * 64 + d0;
            const float* Kp = K + ((size_t)(b * LL) + k0 + i) * DD + h * 64 + d0;
            float4 q0v = *(const float4*)Qp;
            float4 q1v = *(const float4*)(Qp + 4);
            float4 q2v = *(const float4*)(Qp + 8);
            float4 q3v = *(const float4*)(Qp + 12);
            *(float4*)&Qs[i][d0]      = q0v;
            *(float4*)&Qs[i][d0 + 4]  = q1v;
            *(float4*)&Qs[i][d0 + 8]  = q2v;
            *(float4*)&Qs[i][d0 + 12] = q3v;
            float4 k0v = *(const float4*)Kp;
            float4 k1v = *(const float4*)(Kp + 4);
            float4 k2v = *(const float4*)(Kp + 8);
            float4 k3v = *(const float4*)(Kp + 12);
            *(float4*)&Ks[i][d0]      = k0v;
            *(float4*)&Ks[i][d0 + 4]  = k1v;
            *(float4*)&Ks[i][d0 + 8]  = k2v;
            *(float4*)&Ks[i][d0 + 12] = k3v;
        }
        if (tid < 64) {
            size_t si = (((size_t)b * NHH + h) * LL + q0 + tid) * 2;
            sm[tid]  = stats[si];
            ssm[tid] = stats[si + 1];
        }
        __syncthreads();
        float sv[4][4];
#pragma unroll
        for (int u = 0; u < 4; ++u)
#pragma unroll
            for (int v = 0; v < 4; ++v) sv[u][v] = 0.f;
#pragma unroll 4
        for (int k4 = 0; k4 < 16; ++k4) {
            float4 qa[4], ka[4];
#pragma unroll
            for (int u = 0; u < 4; ++u) qa[u] = *(const float4*)&Qs[ty * 4 + u][k4 * 4];
#pragma unroll
            for (int v = 0; v < 4; ++v) ka[v] = *(const float4*)&Ks[tx * 4 + v][k4 * 4];
#pragma unroll
            for (int u = 0; u < 4; ++u)
#pragma unroll
                for (int v = 0; v < 4; ++v)
                    sv[u][v] += qa[u].x * ka[v].x + qa[u].y * ka[v].y
                              + qa[u].z * ka[v].z + qa[u].w * ka[v].w;
        }
#pragma unroll
        for (int u = 0; u < 4; ++u) {
            int qg = q0 + ty * 4 + u;
            float mrow = sm[ty * 4 + u];
            float rs = 1.0f / ssm[ty * 4 + u];
#pragma unroll
            for (int v = 0; v < 4; ++v) {
                int kg = k0 + tx * 4 + v;
                if (kg <= qg)
                    acc[u][v] += expf(sv[u][v] * 0.125f + gbt[u][v] - mrow) * rs;
            }
        }
    }
#pragma unroll
    for (int u = 0; u < 4; ++u) {
        float4 ov;
        ov.x = acc[u][0] * 0.0625f; ov.y = acc[u][1] * 0.0625f;
        ov.z = acc[u][2] * 0.0625f; ov.w = acc[u][3] * 0.0625f;
        *(float4*)&aw[((size_t)(b * LL) + q0 + ty * 4 + u) * LL + k0 + tx * 4] = ov;
    }
}

// ---------------- adv = -nu*U*G, layernorm -> adv_n ----------------
__global__ __launch_bounds__(256) void adv_ln_kernel(
        const float* __restrict__ U, const float* __restrict__ G,
        const float* __restrict__ nub, const float* __restrict__ lnw,
        const float* __restrict__ lnb, float* __restrict__ out) {
    int row = blockIdx.x, tid = threadIdx.x;
    size_t base = (size_t)row * DD + tid * 4;
    float4 u4 = *(const float4*)&U[base];
    float4 g4 = *(const float4*)&G[base];
    float nu = nub[row];
    float a[4];
    a[0] = -nu * u4.x * g4.x;
    a[1] = -nu * u4.y * g4.y;
    a[2] = -nu * u4.z * g4.z;
    a[3] = -nu * u4.w * g4.w;
    float ts = a[0] + a[1] + a[2] + a[3];
    float tq = a[0] * a[0] + a[1] * a[1] + a[2] * a[2] + a[3] * a[3];
    for (int off = 32; off; off >>= 1) {
        ts += __shfl_down(ts, off);
        tq += __shfl_down(tq, off);
    }
    __shared__ float r1[4], r2[4];
    if ((tid & 63) == 0) { r1[tid >> 6] = ts; r2[tid >> 6] = tq; }
    __syncthreads();
    __shared__ float s_mu, s_rs;
    if (tid == 0) {
        float S  = r1[0] + r1[1] + r1[2] + r1[3];
        float Qq = r2[0] + r2[1] + r2[2] + r2[3];
        float mu = S * (1.0f / 1024.f);
        float var = Qq * (1.0f / 1024.f) - mu * mu;
        s_mu = mu;
        s_rs = rsqrtf(var + 1e-5f);
    }
    __syncthreads();
    float mu = s_mu, rs = s_rs;
    float4 w4 = *(const float4*)&lnw[tid * 4];
    float4 b4 = *(const float4*)&lnb[tid * 4];
    float4 ov;
    ov.x = (a[0] - mu) * rs * w4.x + b4.x;
    ov.y = (a[1] - mu) * rs * w4.y + b4.y;
    ov.z = (a[2] - mu) * rs * w4.z + b4.z;
    ov.w = (a[3] - mu) * rs * w4.w + b4.w;
    *(float4*)&out[base] = ov;
}

// ---------------- final residual combine ----------------
__global__ void final_kernel(const float* __restrict__ z, const float* __restrict__ ao,
                             const float* __restrict__ mlp, float* __restrict__ out) {
    size_t i = ((size_t)blockIdx.x * 256 + threadIdx.x) * 4;
    float4 z4 = *(const float4*)&z[i];
    float4 a4 = *(const float4*)&ao[i];
    float4 m4 = *(const float4*)&mlp[i];
    float4 o;
    o.x = z4.x + 0.42f * a4.x + 1.07f * m4.x;
    o.y = z4.y + 0.42f * a4.y + 1.07f * m4.y;
    o.z = z4.z + 0.42f * a4.z + 1.07f * m4.z;
    o.w = z4.w + 0.42f * a4.w + 1.07f * m4.w;
    *(float4*)&out[i] = o;
}

extern "C" void kernel_launch(void* const* d_in, const int* in_sizes, int n_in,
                              void* d_out, int out_size, void* d_ws, size_t ws_size,
                              hipStream_t stream) {
    const float* z       = (const float*)d_in[0];
    const float* Wq      = (const float*)d_in[1];
    const float* bq      = (const float*)d_in[2];
    const float* Wk      = (const float*)d_in[3];
    const float* bk      = (const float*)d_in[4];
    const float* Wv      = (const float*)d_in[5];
    const float* bv      = (const float*)d_in[6];
    const float* Wcoh    = (const float*)d_in[7];
    const float* gamma   = (const float*)d_in[8];
    const float* rg_w1   = (const float*)d_in[9];
    const float* rg_b1   = (const float*)d_in[10];
    const float* rg_w2   = (const float*)d_in[11];
    const float* rg_b2   = (const float*)d_in[12];
    const float* nu_diff = (const float*)d_in[13];
    const float* nu_adv  = (const float*)d_in[14];
    const float* nu_w1   = (const float*)d_in[15];
    const float* nu_b1   = (const float*)d_in[16];
    const float* nu_w2   = (const float*)d_in[17];
    const float* nu_b2   = (const float*)d_in[18];
    const float* Wu      = (const float*)d_in[19];
    const float* bu      = (const float*)d_in[20];
    const float* Wg      = (const float*)d_in[21];
    const float* bg      = (const float*)d_in[22];
    const float* ln_w    = (const float*)d_in[23];
    const float* ln_b    = (const float*)d_in[24];
    const float* Cw      = (const float*)d_in[25];
    const float* Cb      = (const float*)d_in[26];

    float* out_z  = (float*)d_out;
    float* out_aw = out_z + (size_t)MM * DD;

    float* ws = (float*)d_ws;
    const size_t MD = (size_t)MM * DD;   // 4,194,304
    float* pool  = ws;               // later reused as z_glu
    float* Qb    = ws + MD;          // later U
    float* Kb    = ws + 2 * MD;      // later G
    float* Vb    = ws + 3 * MD;      // later adv_n
    float* gkb   = ws + 4 * MD;      // later attn_out
    float* gbb   = ws + 5 * MD;      // B*L*L = 2*MD; later mlp_out
    float* H1    = ws + 7 * MD;      // MM*256
    float* N1    = H1 + (size_t)MM * HG;
    float* gate  = N1 + (size_t)MM * HN;
    float* nub   = gate + MM;
    float* stats = nub + MM;         // B*NH*L*2

    // 1. pool
    pool_kernel<<<dim3((BB * DD) / 256), 256, 0, stream>>>(z, pool);
    // 2. Q,K,V
    dim3 gemm_grid(DD / 128, MM / 128);
    gemm_kernel<<<gemm_grid, 256, 0, stream>>>(z, Wq, bq, Qb, DD, DD);
    gemm_kernel<<<gemm_grid, 256, 0, stream>>>(z, Wk, bk, Kb, DD, DD);
    gemm_kernel<<<gemm_grid, 256, 0, stream>>>(z, Wv, bv, Vb, DD, DD);
    // 3. gk = pool @ Wcoh
    gemm_kernel<<<gemm_grid, 256, 0, stream>>>(pool, Wcoh, nullptr, gkb, DD, DD);
    // 4. gb
    gb_kernel<<<dim3(1024, BB), 256, 0, stream>>>(gkb, Kb, gamma, gbb);
    // 5. gate MLP
    gemm_kernel<<<dim3(HG / 128, MM / 128), 256, 0, stream>>>(pool, rg_w1, rg_b1, H1, DD, HG);
    gate_fin_kernel<<<dim3(MM), 256, 0, stream>>>(H1, rg_w2, rg_b2, gate);
    // 6. nu MLP
    gemm_kernel<<<dim3(HN / 128, MM / 128), 256, 0, stream>>>(pool, nu_w1, nu_b1, N1, DD, HN);
    nu_fin_kernel<<<dim3(MM), 128, 0, stream>>>(N1, nu_w2, nu_b2, nu_diff, nu_adv, nub);
    // 7. rope Q,K in place
    rope_qk_kernel<<<dim3((MM * 512) / 256), 256, 0, stream>>>(Qb, Kb, gate);
    // 8. flash attention -> attn_out (reuses gk buffer) + stats
    attn_flash_kernel<<<dim3(32, NHH, BB), 256, 0, stream>>>(Qb, Kb, Vb, gbb, gkb, stats);
    // 9. attn_w -> second half of d_out
    attn_w_kernel<<<dim3(1024, BB), 256, 0, stream>>>(Qb, Kb, gbb, stats, out_aw);
    // 10. z_glu (reuses pool buffer)
    rope_glu_kernel<<<dim3((MM * 512) / 256), 256, 0, stream>>>(z, pool);
    // 11. U, G (reuse Q,K buffers)
    gemm_kernel<<<gemm_grid, 256, 0, stream>>>(pool, Wu, bu, Qb, DD, DD);
    gemm_kernel<<<gemm_grid, 256, 0, stream>>>(pool, Wg, bg, Kb, DD, DD);
    // 12. adv + layernorm -> Vb
    adv_ln_kernel<<<dim3(MM), 256, 0, stream>>>(Qb, Kb, nub, ln_w, ln_b, Vb);
    // 13. mlp_out = adv_n @ Cw + Cb  (reuses gb buffer)
    gemm_kernel<<<gemm_grid, 256, 0, stream>>>(Vb, Cw, Cb, gbb, DD, DD);
    // 14. final combine
    final_kernel<<<dim3(MD / 4 / 256), 256, 0, stream>>>(z, gkb, gbb, out_z);
}

// Round 2
// 1618.217 us; speedup vs baseline: 2.1443x; 2.1443x over previous
//
#include <hip/hip_runtime.h>

#define DD 1024
#define NHH 16
#define HDD 64
#define BB 2
#define LL 2048
#define MM (BB*LL)          // 4096 rows
#define HG 256
#define HN 128

#define LOG_FAST 0.48121182f   // ln((1+sqrt(5))/2)
#define LOG_SLOW 7.3889461f    // ln(1618.0)
#define LOG_GLU  9.6915312f    // ln(16180.0)

typedef __attribute__((ext_vector_type(8))) short short8;
typedef __attribute__((ext_vector_type(4))) float f32x4;

__device__ __forceinline__ float gelu_f(float x) {
    return 0.5f * x * (1.0f + erff(x * 0.70710678f));
}

__device__ __forceinline__ ushort f2b(float x) {
    unsigned u = __float_as_uint(x);
    unsigned r = (u + 0x7FFFu + ((u >> 16) & 1u)) >> 16;
    return (ushort)r;
}

__device__ __forceinline__ void gl_lds16(const ushort* g, ushort* l) {
    __builtin_amdgcn_global_load_lds(
        (const __attribute__((address_space(1))) unsigned int*)g,
        (__attribute__((address_space(3))) unsigned int*)l, 16, 0, 0);
}

// ---------------- parallel causal cumulative mean pool ----------------
#define LCH 128
#define NCH 16
__global__ void pool_scan1(const float* __restrict__ z, float* __restrict__ pool,
                           float* __restrict__ ctot) {
    int ch = blockIdx.x, dg = blockIdx.y, b = blockIdx.z;
    int d = dg * 256 + threadIdx.x;
    const float* zp = z + ((size_t)b * LL + ch * LCH) * DD + d;
    float* pp = pool + ((size_t)b * LL + ch * LCH) * DD + d;
    float s = 0.f;
    for (int t = 0; t < LCH; ++t) {
        s += zp[(size_t)t * DD];
        pp[(size_t)t * DD] = s;
    }
    ctot[((size_t)b * NCH + ch) * DD + d] = s;
}
__global__ void pool_scan2(const float* __restrict__ ctot, float* __restrict__ pool) {
    int ch = blockIdx.x, dg = blockIdx.y, b = blockIdx.z;
    int d = dg * 256 + threadIdx.x;
    float off = 0.f;
    for (int c = 0; c < ch; ++c) off += ctot[((size_t)b * NCH + c) * DD + d];
    int t0 = ch * LCH;
    float* pp = pool + ((size_t)b * LL + t0) * DD + d;
    for (int t = 0; t < LCH; ++t) {
        pp[(size_t)t * DD] = (pp[(size_t)t * DD] + off) / (float)(t0 + t + 1);
    }
}

// ---------------- fp32 -> bf16 converters ----------------
__global__ void f2b_kernel(const float* __restrict__ in, ushort* __restrict__ out) {
    size_t i = ((size_t)blockIdx.x * 256 + threadIdx.x) * 4;
    float4 v = *(const float4*)&in[i];
    ushort4 o;
    o.x = f2b(v.x); o.y = f2b(v.y); o.z = f2b(v.z); o.w = f2b(v.w);
    *(ushort4*)&out[i] = o;
}

// W (1024 x Ndim) fp32 -> Wt (Ndim x 1024) bf16
__global__ void f2bT_kernel(const float* __restrict__ W, ushort* __restrict__ Wt, int Ndim) {
    __shared__ float t[32][33];
    int n0 = blockIdx.x * 32, k0 = blockIdx.y * 32;
    int tx = threadIdx.x & 31, ty = threadIdx.x >> 5;   // ty 0..7
#pragma unroll
    for (int j = 0; j < 4; ++j)
        t[ty + j * 8][tx] = W[(size_t)(k0 + ty + j * 8) * Ndim + n0 + tx];
    __syncthreads();
#pragma unroll
    for (int j = 0; j < 4; ++j)
        Wt[(size_t)(n0 + ty + j * 8) * 1024 + k0 + tx] = f2b(t[tx][ty + j * 8]);
}

// ---------------- bf16 MFMA GEMM: C(fp32, M x Ndim) = A(M x 1024 bf16) @ Wt^T + bias
// Wt is (Ndim x 1024) bf16 (transposed weight). Tile 128x128, BK=32, 4 waves.
__global__ __launch_bounds__(256) void gemm_mfma(
        const ushort* __restrict__ A, const ushort* __restrict__ Wt,
        const float* __restrict__ bias, float* __restrict__ C, int Ndim) {
    __shared__ ushort As[4096];   // [quad][row 0..127][8]
    __shared__ ushort Bs[4096];
    int tid = threadIdx.x;
    int wid = tid >> 6, lane = tid & 63;
    int n0 = blockIdx.x * 128, m0 = blockIdx.y * 128;
    int wm = wid >> 1, wn = wid & 1;
    int quad = lane >> 4, l16 = lane & 15;

    f32x4 acc[4][4];
#pragma unroll
    for (int mi = 0; mi < 4; ++mi)
#pragma unroll
        for (int ni = 0; ni < 4; ++ni) acc[mi][ni] = (f32x4){0.f, 0.f, 0.f, 0.f};

    int c0 = wid * 128 + lane;
    int c1 = c0 + 64;
    const ushort* Ag0 = A + (size_t)(m0 + (c0 & 127)) * 1024 + (c0 >> 7) * 8;
    const ushort* Ag1 = A + (size_t)(m0 + (c1 & 127)) * 1024 + (c1 >> 7) * 8;
    const ushort* Bg0 = Wt + (size_t)(n0 + (c0 & 127)) * 1024 + (c0 >> 7) * 8;
    const ushort* Bg1 = Wt + (size_t)(n0 + (c1 & 127)) * 1024 + (c1 >> 7) * 8;
    ushort* Al0 = As + wid * 1024;
    ushort* Al1 = As + wid * 1024 + 512;
    ushort* Bl0 = Bs + wid * 1024;
    ushort* Bl1 = Bs + wid * 1024 + 512;

    const ushort* a_rd = &As[(quad * 128 + wm * 64 + l16) * 8];
    const ushort* b_rd = &Bs[(quad * 128 + wn * 64 + l16) * 8];

    for (int kb = 0; kb < 1024; kb += 32) {
        gl_lds16(Ag0 + kb, Al0);
        gl_lds16(Ag1 + kb, Al1);
        gl_lds16(Bg0 + kb, Bl0);
        gl_lds16(Bg1 + kb, Bl1);
        __syncthreads();
        short8 af[4], bf[4];
#pragma unroll
        for (int mi = 0; mi < 4; ++mi)
            af[mi] = *(const short8*)(a_rd + mi * 16 * 8);
#pragma unroll
        for (int ni = 0; ni < 4; ++ni)
            bf[ni] = *(const short8*)(b_rd + ni * 16 * 8);
#pragma unroll
        for (int mi = 0; mi < 4; ++mi)
#pragma unroll
            for (int ni = 0; ni < 4; ++ni)
                acc[mi][ni] = __builtin_amdgcn_mfma_f32_16x16x32_bf16(
                    af[mi], bf[ni], acc[mi][ni], 0, 0, 0);
        __syncthreads();
    }
    int bcol[4];
    float bval[4];
#pragma unroll
    for (int ni = 0; ni < 4; ++ni) {
        bcol[ni] = n0 + wn * 64 + ni * 16 + l16;
        bval[ni] = bias ? bias[bcol[ni]] : 0.f;
    }
#pragma unroll
    for (int mi = 0; mi < 4; ++mi) {
#pragma unroll
        for (int r = 0; r < 4; ++r) {
            int row = m0 + wm * 64 + mi * 16 + quad * 4 + r;
            float* Cp = C + (size_t)row * Ndim;
#pragma unroll
            for (int ni = 0; ni < 4; ++ni)
                Cp[bcol[ni]] = acc[mi][ni][r] + bval[ni];
        }
    }
}

// ---------------- gb = tanh(gamma)*d^-0.5 * gk @ K^T (causal-lower tiles only) ----------------
__global__ __launch_bounds__(256) void gb_kernel(
        const float* __restrict__ gk, const float* __restrict__ Kmat,
        const float* __restrict__ gamma, float* __restrict__ gb) {
    int lt = blockIdx.x >> 5, mt = blockIdx.x & 31;
    if (mt > lt) return;
    int b = blockIdx.y;
    __shared__ float As[32][68];
    __shared__ float Bs[32][68];
    int tid = threadIdx.x;
    int ty = tid >> 4, tx = tid & 15;
    int l0 = lt * 64, m0 = mt * 64;
    float acc[4][4];
#pragma unroll
    for (int u = 0; u < 4; ++u)
#pragma unroll
        for (int v = 0; v < 4; ++v) acc[u][v] = 0.f;
    int arow = tid >> 2, acol = (tid & 3) * 8;
    const float* Abase = gk   + ((size_t)b * LL + l0 + arow) * DD + acol;
    const float* Bbase = Kmat + ((size_t)b * LL + m0 + arow) * DD + acol;
    for (int kb = 0; kb < DD; kb += 32) {
        float4 a0 = *(const float4*)(Abase + kb);
        float4 a1 = *(const float4*)(Abase + kb + 4);
        As[acol + 0][arow] = a0.x; As[acol + 1][arow] = a0.y;
        As[acol + 2][arow] = a0.z; As[acol + 3][arow] = a0.w;
        As[acol + 4][arow] = a1.x; As[acol + 5][arow] = a1.y;
        As[acol + 6][arow] = a1.z; As[acol + 7][arow] = a1.w;
        float4 b0 = *(const float4*)(Bbase + kb);
        float4 b1 = *(const float4*)(Bbase + kb + 4);
        Bs[acol + 0][arow] = b0.x; Bs[acol + 1][arow] = b0.y;
        Bs[acol + 2][arow] = b0.z; Bs[acol + 3][arow] = b0.w;
        Bs[acol + 4][arow] = b1.x; Bs[acol + 5][arow] = b1.y;
        Bs[acol + 6][arow] = b1.z; Bs[acol + 7][arow] = b1.w;
        __syncthreads();
#pragma unroll 8
        for (int k = 0; k < 32; ++k) {
            float4 av = *(const float4*)&As[k][ty * 4];
            float4 bv = *(const float4*)&Bs[k][tx * 4];
            float aa[4] = {av.x, av.y, av.z, av.w};
            float ba[4] = {bv.x, bv.y, bv.z, bv.w};
#pragma unroll
            for (int u = 0; u < 4; ++u)
#pragma unroll
                for (int v = 0; v < 4; ++v)
                    acc[u][v] += aa[u] * ba[v];
        }
        __syncthreads();
    }
    float scale = tanhf(gamma[0]) * 0.03125f;
#pragma unroll
    for (int u = 0; u < 4; ++u) {
        float4 o;
        o.x = acc[u][0] * scale; o.y = acc[u][1] * scale;
        o.z = acc[u][2] * scale; o.w = acc[u][3] * scale;
        *(float4*)&gb[((size_t)b * LL + l0 + ty * 4 + u) * LL + m0 + tx * 4] = o;
    }
}

// ---------------- gate finisher ----------------
__global__ __launch_bounds__(256) void gate_fin_kernel(
        const float* __restrict__ H1, const float* __restrict__ w2,
        const float* __restrict__ b2, float* __restrict__ gate) {
    int row = blockIdx.x, tid = threadIdx.x;
    float x = H1[(size_t)row * HG + tid];
    float val = gelu_f(x) * w2[tid];
    for (int off = 32; off; off >>= 1) val += __shfl_down(val, off);
    __shared__ float part[4];
    if ((tid & 63) == 0) part[tid >> 6] = val;
    __syncthreads();
    if (tid == 0) {
        float acc = part[0] + part[1] + part[2] + part[3] + b2[0];
        gate[row] = 1.f / (1.f + expf(-acc));
    }
}

// ---------------- nu finisher ----------------
__global__ __launch_bounds__(128) void nu_fin_kernel(
        const float* __restrict__ N1, const float* __restrict__ w2,
        const float* __restrict__ b2, const float* __restrict__ nu_diff,
        const float* __restrict__ nu_adv, float* __restrict__ nub) {
    int row = blockIdx.x, tid = threadIdx.x;
    float t = tanhf(N1[(size_t)row * HN + tid]);
    float val = t * w2[tid];
    for (int off = 32; off; off >>= 1) val += __shfl_down(val, off);
    __shared__ float part[2];
    if ((tid & 63) == 0) part[tid >> 6] = val;
    __syncthreads();
    if (tid == 0) {
        float acc = part[0] + part[1] + b2[0];
        nub[row] = fabsf(nu_diff[0]) + tanhf(acc) * fabsf(nu_adv[0]);
    }
}

// ---------------- gated dual-base RoPE on Q and K (in place) ----------------
__global__ void rope_qk_kernel(float* __restrict__ Q, float* __restrict__ K,
                               const float* __restrict__ gate) {
    int idx = blockIdx.x * 256 + threadIdx.x;
    int row = idx >> 9;
    int i = idx & 511;
    int t = row & (LL - 1);
    float g = gate[row];
    float fi = (float)i * (1.0f / 512.0f);
    float tf = (float)t;
    float af = tf * expf(-fi * LOG_FAST);
    float as = tf * expf(-fi * LOG_SLOW);
    float c = g * cosf(af) + (1.f - g) * cosf(as);
    float s = g * sinf(af) + (1.f - g) * sinf(as);
    size_t base = (size_t)row * DD;
    float x = Q[base + i], y = Q[base + 512 + i];
    Q[base + i]       = x * c - y * s;
    Q[base + 512 + i] = y * c + x * s;
    x = K[base + i]; y = K[base + 512 + i];
    K[base + i]       = x * c - y * s;
    K[base + 512 + i] = y * c + x * s;
}

// ---------------- fixed-base RoPE for GLU branch ----------------
__global__ void rope_glu_kernel(const float* __restrict__ z, float* __restrict__ zg) {
    int idx = blockIdx.x * 256 + threadIdx.x;
    int row = idx >> 9;
    int i = idx & 511;
    int t = row & (LL - 1);
    float fi = (float)i * (1.0f / 512.0f);
    float ag = (float)t * expf(-fi * LOG_GLU);
    float c = cosf(ag), s = sinf(ag);
    size_t base = (size_t)row * DD;
    float x = z[base + i], y = z[base + 512 + i];
    zg[base + i]       = x * c - y * s;
    zg[base + 512 + i] = y * c + x * s;
}

// ---------------- flash attention; block handles q-tiles (x, 31-x) for uniform work ----------------
__global__ __launch_bounds__(256) void attn_flash_kernel(
        const float* __restrict__ Q, const float* __restrict__ K,
        const float* __restrict__ V, const float* __restrict__ gb,
        float* __restrict__ attn_out, float* __restrict__ stats) {
    int h = blockIdx.y, b = blockIdx.z;
    __shared__ float Qs[64][68];
    __shared__ float Ks[32][68];
    __shared__ float Vs[32][68];
    __shared__ float Ps[64][36];
    __shared__ float redm[64][17];
    __shared__ float reds[64][17];
    int tid = threadIdx.x;
    int ty = tid >> 4, tx = tid & 15;
    const float* gbb = gb + (size_t)b * LL * LL;

    for (int rep = 0; rep < 2; ++rep) {
        int qt = (rep == 0) ? blockIdx.x : (31 - blockIdx.x);
        int q0 = qt * 64;
        __syncthreads();
        {
            int i = tid >> 2, d0 = (tid & 3) * 16;
            const float* Qp = Q + ((size_t)(b * LL) + q0 + i) * DD + h * 64 + d0;
            float4 v0 = *(const float4*)Qp;
            float4 v1 = *(const float4*)(Qp + 4);
            float4 v2 = *(const float4*)(Qp + 8);
            float4 v3 = *(const float4*)(Qp + 12);
            *(float4*)&Qs[i][d0]      = v0;
            *(float4*)&Qs[i][d0 + 4]  = v1;
            *(float4*)&Qs[i][d0 + 8]  = v2;
            *(float4*)&Qs[i][d0 + 12] = v3;
        }
        float o[4][4];
        float m_r[4], s_r[4];
#pragma unroll
        for (int u = 0; u < 4; ++u) {
            m_r[u] = -3e38f; s_r[u] = 0.f;
#pragma unroll
            for (int v = 0; v < 4; ++v) o[u][v] = 0.f;
        }
        int ktmax = 2 * qt + 1;
        for (int kt = 0; kt <= ktmax; ++kt) {
            int k0 = kt * 32;
            __syncthreads();
            {
                int i = tid >> 3, d0 = (tid & 7) * 8;
                const float* Kp = K + ((size_t)(b * LL) + k0 + i) * DD + h * 64 + d0;
                const float* Vp = V + ((size_t)(b * LL) + k0 + i) * DD + h * 64 + d0;
                float4 k0v = *(const float4*)Kp;
                float4 k1v = *(const float4*)(Kp + 4);
                float4 v0v = *(const float4*)Vp;
                float4 v1v = *(const float4*)(Vp + 4);
                *(float4*)&Ks[i][d0]     = k0v;
                *(float4*)&Ks[i][d0 + 4] = k1v;
                *(float4*)&Vs[i][d0]     = v0v;
                *(float4*)&Vs[i][d0 + 4] = v1v;
            }
            __syncthreads();
            float sv[4][2];
#pragma unroll
            for (int u = 0; u < 4; ++u) { sv[u][0] = 0.f; sv[u][1] = 0.f; }
#pragma unroll 8
            for (int k4 = 0; k4 < 16; ++k4) {
                float4 qa[4], ka[2];
#pragma unroll
                for (int u = 0; u < 4; ++u) qa[u] = *(const float4*)&Qs[ty * 4 + u][k4 * 4];
#pragma unroll
                for (int v = 0; v < 2; ++v) ka[v] = *(const float4*)&Ks[tx * 2 + v][k4 * 4];
#pragma unroll
                for (int u = 0; u < 4; ++u)
#pragma unroll
                    for (int v = 0; v < 2; ++v)
                        sv[u][v] += qa[u].x * ka[v].x + qa[u].y * ka[v].y
                                  + qa[u].z * ka[v].z + qa[u].w * ka[v].w;
            }
            float smv[4][2];
#pragma unroll
            for (int u = 0; u < 4; ++u) {
                int qg = q0 + ty * 4 + u;
                const float* gbp = gbb + (size_t)qg * LL + k0 + tx * 2;
#pragma unroll
                for (int v = 0; v < 2; ++v) {
                    int kg = k0 + tx * 2 + v;
                    float sval = sv[u][v] * 0.125f + gbp[v];
                    smv[u][v] = (kg <= qg) ? sval : -1e30f;
                }
                redm[ty * 4 + u][tx] = fmaxf(smv[u][0], smv[u][1]);
            }
            __syncthreads();
            float newm[4], alpha[4];
#pragma unroll
            for (int u = 0; u < 4; ++u) {
                float mx = m_r[u];
#pragma unroll
                for (int j = 0; j < 16; ++j) mx = fmaxf(mx, redm[ty * 4 + u][j]);
                newm[u] = mx;
                alpha[u] = expf(m_r[u] - mx);
            }
#pragma unroll
            for (int u = 0; u < 4; ++u) {
                int qg = q0 + ty * 4 + u;
                float p0 = (k0 + tx * 2 + 0 <= qg) ? expf(smv[u][0] - newm[u]) : 0.f;
                float p1 = (k0 + tx * 2 + 1 <= qg) ? expf(smv[u][1] - newm[u]) : 0.f;
                Ps[ty * 4 + u][tx * 2 + 0] = p0;
                Ps[ty * 4 + u][tx * 2 + 1] = p1;
                reds[ty * 4 + u][tx] = p0 + p1;
            }
            __syncthreads();
#pragma unroll
            for (int u = 0; u < 4; ++u) {
                float ssum = 0.f;
#pragma unroll
                for (int j = 0; j < 16; ++j) ssum += reds[ty * 4 + u][j];
                s_r[u] = s_r[u] * alpha[u] + ssum;
                m_r[u] = newm[u];
                o[u][0] *= alpha[u]; o[u][1] *= alpha[u];
                o[u][2] *= alpha[u]; o[u][3] *= alpha[u];
            }
#pragma unroll 8
            for (int m = 0; m < 32; ++m) {
                float a0 = Ps[ty * 4 + 0][m];
                float a1 = Ps[ty * 4 + 1][m];
                float a2 = Ps[ty * 4 + 2][m];
                float a3 = Ps[ty * 4 + 3][m];
                float4 bv = *(const float4*)&Vs[m][tx * 4];
                o[0][0] += a0 * bv.x; o[0][1] += a0 * bv.y; o[0][2] += a0 * bv.z; o[0][3] += a0 * bv.w;
                o[1][0] += a1 * bv.x; o[1][1] += a1 * bv.y; o[1][2] += a1 * bv.z; o[1][3] += a1 * bv.w;
                o[2][0] += a2 * bv.x; o[2][1] += a2 * bv.y; o[2][2] += a2 * bv.z; o[2][3] += a2 * bv.w;
                o[3][0] += a3 * bv.x; o[3][1] += a3 * bv.y; o[3][2] += a3 * bv.z; o[3][3] += a3 * bv.w;
            }
        }
#pragma unroll
        for (int u = 0; u < 4; ++u) {
            float rinv = 1.0f / s_r[u];
            float4 ov;
            ov.x = o[u][0] * rinv; ov.y = o[u][1] * rinv;
            ov.z = o[u][2] * rinv; ov.w = o[u][3] * rinv;
            *(float4*)&attn_out[((size_t)(b * LL) + q0 + ty * 4 + u) * DD + h * 64 + tx * 4] = ov;
        }
        if (tx == 0) {
#pragma unroll
            for (int u = 0; u < 4; ++u) {
                size_t si = (((size_t)b * NHH + h) * LL + q0 + ty * 4 + u) * 2;
                stats[si]     = m_r[u];
                stats[si + 1] = s_r[u];
            }
        }
    }
}

// ---------------- attn_w = mean over heads of softmax probs (recompute from stats) ----------------
__global__ __launch_bounds__(256) void attn_w_kernel(
        const float* __restrict__ Q, const float* __restrict__ K,
        const float* __restrict__ gb, const float* __restrict__ stats,
        float* __restrict__ aw) {
    int qt = blockIdx.x >> 5, kt = blockIdx.x & 31;
    int b = blockIdx.y;
    int tid = threadIdx.x;
    int ty = tid >> 4, tx = tid & 15;
    int q0 = qt * 64, k0 = kt * 64;
    if (kt > qt) {
        float4 zv = make_float4(0.f, 0.f, 0.f, 0.f);
#pragma unroll
        for (int u = 0; u < 4; ++u)
            *(float4*)&aw[((size_t)(b * LL) + q0 + ty * 4 + u) * LL + k0 + tx * 4] = zv;
        return;
    }
    __shared__ float Qs[64][68];
    __shared__ float Ks[64][68];
    __shared__ float sm[64], ssm[64];
    float acc[4][4];
    float gbt[4][4];
#pragma unroll
    for (int u = 0; u < 4; ++u) {
        float4 g4 = *(const float4*)&gb[((size_t)b * LL + q0 + ty * 4 + u) * LL + k0 + tx * 4];
        gbt[u][0] = g4.x; gbt[u][1] = g4.y; gbt[u][2] = g4.z; gbt[u][3] = g4.w;
#pragma unroll
        for (int v = 0; v < 4; ++v) acc[u][v] = 0.f;
    }
    for (int h = 0; h < NHH; ++h) {
        __syncthreads();
        {
            int i = tid >> 2, d0 = (tid & 3) * 16;
            const float* Qp = Q + ((size_t)(b * LL) + q0 + i) * DD + h * 64 + d0;
            const float* Kp = K + ((size_t)(b * LL) + k0 + i) * DD + h * 64 + d0;
            float4 q0v = *(const float4*)Qp;
            float4 q1v = *(const float4*)(Qp + 4);
            float4 q2v = *(const float4*)(Qp + 8);
            float4 q3v = *(const float4*)(Qp + 12);
            *(float4*)&Qs[i][d0]      = q0v;
            *(float4*)&Qs[i][d0 + 4]  = q1v;
            *(float4*)&Qs[i][d0 + 8]  = q2v;
            *(float4*)&Qs[i][d0 + 12] = q3v;
            float4 k0v = *(const float4*)Kp;
            float4 k1v = *(const float4*)(Kp + 4);
            float4 k2v = *(const float4*)(Kp + 8);
            float4 k3v = *(const float4*)(Kp + 12);
            *(float4*)&Ks[i][d0]      = k0v;
            *(float4*)&Ks[i][d0 + 4]  = k1v;
            *(float4*)&Ks[i][d0 + 8]  = k2v;
            *(float4*)&Ks[i][d0 + 12] = k3v;
        }
        if (tid < 64) {
            size_t si = (((size_t)b * NHH + h) * LL + q0 + tid) * 2;
            sm[tid]  = stats[si];
            ssm[tid] = stats[si + 1];
        }
        __syncthreads();
        float sv[4][4];
#pragma unroll
        for (int u = 0; u < 4; ++u)
#pragma unroll
            for (int v = 0; v < 4; ++v) sv[u][v] = 0.f;
#pragma unroll 4
        for (int k4 = 0; k4 < 16; ++k4) {
            float4 qa[4], ka[4];
#pragma unroll
            for (int u = 0; u < 4; ++u) qa[u] = *(const float4*)&Qs[ty * 4 + u][k4 * 4];
#pragma unroll
            for (int v = 0; v < 4; ++v) ka[v] = *(const float4*)&Ks[tx * 4 + v][k4 * 4];
#pragma unroll
            for (int u = 0; u < 4; ++u)
#pragma unroll
                for (int v = 0; v < 4; ++v)
                    sv[u][v] += qa[u].x * ka[v].x + qa[u].y * ka[v].y
                              + qa[u].z * ka[v].z + qa[u].w * ka[v].w;
        }
#pragma unroll
        for (int u = 0; u < 4; ++u) {
            int qg = q0 + ty * 4 + u;
            float mrow = sm[ty * 4 + u];
            float rs = 1.0f / ssm[ty * 4 + u];
#pragma unroll
            for (int v = 0; v < 4; ++v) {
                int kg = k0 + tx * 4 + v;
                if (kg <= qg)
                    acc[u][v] += expf(sv[u][v] * 0.125f + gbt[u][v] - mrow) * rs;
            }
        }
    }
#pragma unroll
    for (int u = 0; u < 4; ++u) {
        float4 ov;
        ov.x = acc[u][0] * 0.0625f; ov.y = acc[u][1] * 0.0625f;
        ov.z = acc[u][2] * 0.0625f; ov.w = acc[u][3] * 0.0625f;
        *(float4*)&aw[((size_t)(b * LL) + q0 + ty * 4 + u) * LL + k0 + tx * 4] = ov;
    }
}

// ---------------- adv = -nu*U*G, layernorm -> adv_n ----------------
__global__ __launch_bounds__(256) void adv_ln_kernel(
        const float* __restrict__ U, const float* __restrict__ G,
        const float* __restrict__ nub, const float* __restrict__ lnw,
        const float* __restrict__ lnb, float* __restrict__ out) {
    int row = blockIdx.x, tid = threadIdx.x;
    size_t base = (size_t)row * DD + tid * 4;
    float4 u4 = *(const float4*)&U[base];
    float4 g4 = *(const float4*)&G[base];
    float nu = nub[row];
    float a[4];
    a[0] = -nu * u4.x * g4.x;
    a[1] = -nu * u4.y * g4.y;
    a[2] = -nu * u4.z * g4.z;
    a[3] = -nu * u4.w * g4.w;
    float ts = a[0] + a[1] + a[2] + a[3];
    float tq = a[0] * a[0] + a[1] * a[1] + a[2] * a[2] + a[3] * a[3];
    for (int off = 32; off; off >>= 1) {
        ts += __shfl_down(ts, off);
        tq += __shfl_down(tq, off);
    }
    __shared__ float r1[4], r2[4];
    if ((tid & 63) == 0) { r1[tid >> 6] = ts; r2[tid >> 6] = tq; }
    __syncthreads();
    __shared__ float s_mu, s_rs;
    if (tid == 0) {
        float S  = r1[0] + r1[1] + r1[2] + r1[3];
        float Qq = r2[0] + r2[1] + r2[2] + r2[3];
        float mu = S * (1.0f / 1024.f);
        float var = Qq * (1.0f / 1024.f) - mu * mu;
        s_mu = mu;
        s_rs = rsqrtf(var + 1e-5f);
    }
    __syncthreads();
    float mu = s_mu, rs = s_rs;
    float4 w4 = *(const float4*)&lnw[tid * 4];
    float4 b4 = *(const float4*)&lnb[tid * 4];
    float4 ov;
    ov.x = (a[0] - mu) * rs * w4.x + b4.x;
    ov.y = (a[1] - mu) * rs * w4.y + b4.y;
    ov.z = (a[2] - mu) * rs * w4.z + b4.z;
    ov.w = (a[3] - mu) * rs * w4.w + b4.w;
    *(float4*)&out[base] = ov;
}

// ---------------- final residual combine ----------------
__global__ void final_kernel(const float* __restrict__ z, const float* __restrict__ ao,
                             const float* __restrict__ mlp, float* __restrict__ out) {
    size_t i = ((size_t)blockIdx.x * 256 + threadIdx.x) * 4;
    float4 z4 = *(const float4*)&z[i];
    float4 a4 = *(const float4*)&ao[i];
    float4 m4 = *(const float4*)&mlp[i];
    float4 o;
    o.x = z4.x + 0.42f * a4.x + 1.07f * m4.x;
    o.y = z4.y + 0.42f * a4.y + 1.07f * m4.y;
    o.z = z4.z + 0.42f * a4.z + 1.07f * m4.z;
    o.w = z4.w + 0.42f * a4.w + 1.07f * m4.w;
    *(float4*)&out[i] = o;
}

extern "C" void kernel_launch(void* const* d_in, const int* in_sizes, int n_in,
                              void* d_out, int out_size, void* d_ws, size_t ws_size,
                              hipStream_t stream) {
    const float* z       = (const float*)d_in[0];
    const float* Wq      = (const float*)d_in[1];
    const float* bq      = (const float*)d_in[2];
    const float* Wk      = (const float*)d_in[3];
    const float* bk      = (const float*)d_in[4];
    const float* Wv      = (const float*)d_in[5];
    const float* bv      = (const float*)d_in[6];
    const float* Wcoh    = (const float*)d_in[7];
    const float* gamma   = (const float*)d_in[8];
    const float* rg_w1   = (const float*)d_in[9];
    const float* rg_b1   = (const float*)d_in[10];
    const float* rg_w2   = (const float*)d_in[11];
    const float* rg_b2   = (const float*)d_in[12];
    const float* nu_diff = (const float*)d_in[13];
    const float* nu_adv  = (const float*)d_in[14];
    const float* nu_w1   = (const float*)d_in[15];
    const float* nu_b1   = (const float*)d_in[16];
    const float* nu_w2   = (const float*)d_in[17];
    const float* nu_b2   = (const float*)d_in[18];
    const float* Wu      = (const float*)d_in[19];
    const float* bu      = (const float*)d_in[20];
    const float* Wg      = (const float*)d_in[21];
    const float* bg      = (const float*)d_in[22];
    const float* ln_w    = (const float*)d_in[23];
    const float* ln_b    = (const float*)d_in[24];
    const float* Cw      = (const float*)d_in[25];
    const float* Cb      = (const float*)d_in[26];

    float* out_z  = (float*)d_out;
    float* out_aw = out_z + (size_t)MM * DD;

    float* ws = (float*)d_ws;
    const size_t MD = (size_t)MM * DD;   // 4,194,304
    float* pool  = ws;               // later reused as z_glu
    float* Qb    = ws + MD;          // later U, later mlp_out
    float* Kb    = ws + 2 * MD;      // later G
    float* Vb    = ws + 3 * MD;      // later adv_n
    float* gkb   = ws + 4 * MD;      // later attn_out
    float* gbb   = ws + 5 * MD;      // B*L*L = 2*MD (gb). bf16 Ab/Wb alias here when gb not live.
    float* H1    = ws + 7 * MD;      // MM*256
    float* N1    = H1 + (size_t)MM * HG;
    float* gate  = N1 + (size_t)MM * HN;
    float* nub   = gate + MM;
    float* stats = nub + MM;                       // B*NH*L*2
    float* ctot  = stats + (size_t)BB * NHH * LL * 2;  // B*NCH*DD

    // bf16 scratch aliases the gb region (only live when gb is not):
    ushort* Ab = (ushort*)gbb;                 // MD bf16 = MD/2 floats
    ushort* Wb = (ushort*)(gbb + MD / 2);      // up to DD*DD bf16

    dim3 g128(8, 32);      // Ndim=1024 MFMA gemm grid
    dim3 cvt_g(4096);      // MD/1024
    dim3 wT_g(32, 32);     // 1024x1024 transpose-convert

    // 1. pool (parallel scan)
    pool_scan1<<<dim3(NCH, 4, BB), 256, 0, stream>>>(z, pool, ctot);
    pool_scan2<<<dim3(NCH, 4, BB), 256, 0, stream>>>(ctot, pool);
    // 2. zb
    f2b_kernel<<<cvt_g, 256, 0, stream>>>(z, Ab);
    // 3. Q,K,V (bf16 MFMA)
    f2bT_kernel<<<wT_g, 256, 0, stream>>>(Wq, Wb, DD);
    gemm_mfma<<<g128, 256, 0, stream>>>(Ab, Wb, bq, Qb, DD);
    f2bT_kernel<<<wT_g, 256, 0, stream>>>(Wk, Wb, DD);
    gemm_mfma<<<g128, 256, 0, stream>>>(Ab, Wb, bk, Kb, DD);
    f2bT_kernel<<<wT_g, 256, 0, stream>>>(Wv, Wb, DD);
    gemm_mfma<<<g128, 256, 0, stream>>>(Ab, Wb, bv, Vb, DD);
    // 4. poolb; gk, H1, N1
    f2b_kernel<<<cvt_g, 256, 0, stream>>>(pool, Ab);
    f2bT_kernel<<<wT_g, 256, 0, stream>>>(Wcoh, Wb, DD);
    gemm_mfma<<<g128, 256, 0, stream>>>(Ab, Wb, nullptr, gkb, DD);
    f2bT_kernel<<<dim3(8, 32), 256, 0, stream>>>(rg_w1, Wb, HG);
    gemm_mfma<<<dim3(2, 32), 256, 0, stream>>>(Ab, Wb, rg_b1, H1, HG);
    f2bT_kernel<<<dim3(4, 32), 256, 0, stream>>>(nu_w1, Wb, HN);
    gemm_mfma<<<dim3(1, 32), 256, 0, stream>>>(Ab, Wb, nu_b1, N1, HN);
    // 5. gb (overwrites Ab/Wb region — they are dead until step 11)
    gb_kernel<<<dim3(1024, BB), 256, 0, stream>>>(gkb, Kb, gamma, gbb);
    // 6. gate / nu finishers
    gate_fin_kernel<<<dim3(MM), 256, 0, stream>>>(H1, rg_w2, rg_b2, gate);
    nu_fin_kernel<<<dim3(MM), 128, 0, stream>>>(N1, nu_w2, nu_b2, nu_diff, nu_adv, nub);
    // 7. rope Q,K in place
    rope_qk_kernel<<<dim3((MM * 512) / 256), 256, 0, stream>>>(Qb, Kb, gate);
    // 8. flash attention -> attn_out (gkb) + stats; paired q-tiles for balance
    attn_flash_kernel<<<dim3(16, NHH, BB), 256, 0, stream>>>(Qb, Kb, Vb, gbb, gkb, stats);
    // 9. attn_w -> second half of d_out
    attn_w_kernel<<<dim3(1024, BB), 256, 0, stream>>>(Qb, Kb, gbb, stats, out_aw);
    // 10. z_glu (reuses pool buffer)
    rope_glu_kernel<<<dim3((MM * 512) / 256), 256, 0, stream>>>(z, pool);
    // 11. U, G (bf16 MFMA; gb no longer needed so Ab/Wb space is free again)
    f2b_kernel<<<cvt_g, 256, 0, stream>>>(pool, Ab);
    f2bT_kernel<<<wT_g, 256, 0, stream>>>(Wu, Wb, DD);
    gemm_mfma<<<g128, 256, 0, stream>>>(Ab, Wb, bu, Qb, DD);
    f2bT_kernel<<<wT_g, 256, 0, stream>>>(Wg, Wb, DD);
    gemm_mfma<<<g128, 256, 0, stream>>>(Ab, Wb, bg, Kb, DD);
    // 12. adv + layernorm -> Vb
    adv_ln_kernel<<<dim3(MM), 256, 0, stream>>>(Qb, Kb, nub, ln_w, ln_b, Vb);
    // 13. mlp_out = adv_n @ Cw + Cb -> Qb (U is dead)
    f2b_kernel<<<cvt_g, 256, 0, stream>>>(Vb, Ab);
    f2bT_kernel<<<wT_g, 256, 0, stream>>>(Cw, Wb, DD);
    gemm_mfma<<<g128, 256, 0, stream>>>(Ab, Wb, Cb, Qb, DD);
    // 14. final combine
    final_kernel<<<dim3(MD / 4 / 256), 256, 0, stream>>>(z, gkb, Qb, out_z);
}

// Round 3
// 929.537 us; speedup vs baseline: 3.7330x; 1.7409x over previous
//
#include <hip/hip_runtime.h>

#define DD 1024
#define NHH 16
#define HDD 64
#define BB 2
#define LL 2048
#define MM (BB*LL)          // 4096 rows
#define HG 256
#define HN 128

#define LOG_FAST 0.48121182f   // ln((1+sqrt(5))/2)
#define LOG_SLOW 7.3889461f    // ln(1618.0)
#define LOG_GLU  9.6915312f    // ln(16180.0)

typedef __attribute__((ext_vector_type(8))) short short8;
typedef __attribute__((ext_vector_type(4))) float f32x4;

__device__ __forceinline__ float gelu_f(float x) {
    return 0.5f * x * (1.0f + erff(x * 0.70710678f));
}

__device__ __forceinline__ ushort f2b(float x) {
    unsigned u = __float_as_uint(x);
    unsigned r = (u + 0x7FFFu + ((u >> 16) & 1u)) >> 16;
    return (ushort)r;
}

__device__ __forceinline__ void gl_lds16(const ushort* g, ushort* l) {
    __builtin_amdgcn_global_load_lds(
        (const __attribute__((address_space(1))) unsigned int*)g,
        (__attribute__((address_space(3))) unsigned int*)l, 16, 0, 0);
}

// ushort offset of swizzled 16B chunk within a 64x64 bf16 tile
#define SWZC(row, c8) (((((row) << 3) | ((c8) ^ ((row) & 7)))) << 3)

// Stage a 64x64 bf16 tile (row-major, rstride in elements) into LDS with XOR swizzle.
__device__ __forceinline__ void stage_tile(const ushort* gsrc, int rstride,
                                           ushort* lds, int tid) {
    int wid = tid >> 6;
#pragma unroll
    for (int r = 0; r < 2; ++r) {
        int c = r * 256 + tid;
        int row = c >> 3;
        int c8 = (c & 7) ^ (row & 7);
        gl_lds16(gsrc + (size_t)row * rstride + c8 * 8,
                 lds + (size_t)(r * 256 + wid * 64) * 8);
    }
}

// ---------------- parallel causal cumulative mean pool ----------------
#define LCH 128
#define NCH 16
__global__ void pool_scan1(const float* __restrict__ z, float* __restrict__ pool,
                           float* __restrict__ ctot) {
    int ch = blockIdx.x, dg = blockIdx.y, b = blockIdx.z;
    int d = dg * 256 + threadIdx.x;
    const float* zp = z + ((size_t)b * LL + ch * LCH) * DD + d;
    float* pp = pool + ((size_t)b * LL + ch * LCH) * DD + d;
    float s = 0.f;
    for (int t = 0; t < LCH; ++t) {
        s += zp[(size_t)t * DD];
        pp[(size_t)t * DD] = s;
    }
    ctot[((size_t)b * NCH + ch) * DD + d] = s;
}
__global__ void pool_scan2(const float* __restrict__ ctot, float* __restrict__ pool) {
    int ch = blockIdx.x, dg = blockIdx.y, b = blockIdx.z;
    int d = dg * 256 + threadIdx.x;
    float off = 0.f;
    for (int c = 0; c < ch; ++c) off += ctot[((size_t)b * NCH + c) * DD + d];
    int t0 = ch * LCH;
    float* pp = pool + ((size_t)b * LL + t0) * DD + d;
    for (int t = 0; t < LCH; ++t) {
        pp[(size_t)t * DD] = (pp[(size_t)t * DD] + off) / (float)(t0 + t + 1);
    }
}

// ---------------- fp32 -> bf16 converters ----------------
__global__ void f2b_kernel(const float* __restrict__ in, ushort* __restrict__ out) {
    size_t i = ((size_t)blockIdx.x * 256 + threadIdx.x) * 4;
    float4 v = *(const float4*)&in[i];
    ushort4 o;
    o.x = f2b(v.x); o.y = f2b(v.y); o.z = f2b(v.z); o.w = f2b(v.w);
    *(ushort4*)&out[i] = o;
}

// W (1024 x Ndim) fp32 -> Wt (Ndim x 1024) bf16
__global__ void f2bT_kernel(const float* __restrict__ W, ushort* __restrict__ Wt, int Ndim) {
    __shared__ float t[32][33];
    int n0 = blockIdx.x * 32, k0 = blockIdx.y * 32;
    int tx = threadIdx.x & 31, ty = threadIdx.x >> 5;   // ty 0..7
#pragma unroll
    for (int j = 0; j < 4; ++j)
        t[ty + j * 8][tx] = W[(size_t)(k0 + ty + j * 8) * Ndim + n0 + tx];
    __syncthreads();
#pragma unroll
    for (int j = 0; j < 4; ++j)
        Wt[(size_t)(n0 + ty + j * 8) * 1024 + k0 + tx] = f2b(t[tx][ty + j * 8]);
}

// ---------------- bf16 MFMA GEMM: C(fp32, M x Ndim) = A(M x 1024 bf16) @ Wt^T + bias
__global__ __launch_bounds__(256) void gemm_mfma(
        const ushort* __restrict__ A, const ushort* __restrict__ Wt,
        const float* __restrict__ bias, float* __restrict__ C, int Ndim) {
    __shared__ ushort As[4096];   // [quad][row 0..127][8]
    __shared__ ushort Bs[4096];
    int tid = threadIdx.x;
    int wid = tid >> 6, lane = tid & 63;
    int n0 = blockIdx.x * 128, m0 = blockIdx.y * 128;
    int wm = wid >> 1, wn = wid & 1;
    int quad = lane >> 4, l16 = lane & 15;

    f32x4 acc[4][4];
#pragma unroll
    for (int mi = 0; mi < 4; ++mi)
#pragma unroll
        for (int ni = 0; ni < 4; ++ni) acc[mi][ni] = (f32x4){0.f, 0.f, 0.f, 0.f};

    int c0 = wid * 128 + lane;
    int c1 = c0 + 64;
    const ushort* Ag0 = A + (size_t)(m0 + (c0 & 127)) * 1024 + (c0 >> 7) * 8;
    const ushort* Ag1 = A + (size_t)(m0 + (c1 & 127)) * 1024 + (c1 >> 7) * 8;
    const ushort* Bg0 = Wt + (size_t)(n0 + (c0 & 127)) * 1024 + (c0 >> 7) * 8;
    const ushort* Bg1 = Wt + (size_t)(n0 + (c1 & 127)) * 1024 + (c1 >> 7) * 8;
    ushort* Al0 = As + wid * 1024;
    ushort* Al1 = As + wid * 1024 + 512;
    ushort* Bl0 = Bs + wid * 1024;
    ushort* Bl1 = Bs + wid * 1024 + 512;

    const ushort* a_rd = &As[(quad * 128 + wm * 64 + l16) * 8];
    const ushort* b_rd = &Bs[(quad * 128 + wn * 64 + l16) * 8];

    for (int kb = 0; kb < 1024; kb += 32) {
        gl_lds16(Ag0 + kb, Al0);
        gl_lds16(Ag1 + kb, Al1);
        gl_lds16(Bg0 + kb, Bl0);
        gl_lds16(Bg1 + kb, Bl1);
        __syncthreads();
        short8 af[4], bf[4];
#pragma unroll
        for (int mi = 0; mi < 4; ++mi)
            af[mi] = *(const short8*)(a_rd + mi * 16 * 8);
#pragma unroll
        for (int ni = 0; ni < 4; ++ni)
            bf[ni] = *(const short8*)(b_rd + ni * 16 * 8);
#pragma unroll
        for (int mi = 0; mi < 4; ++mi)
#pragma unroll
            for (int ni = 0; ni < 4; ++ni)
                acc[mi][ni] = __builtin_amdgcn_mfma_f32_16x16x32_bf16(
                    af[mi], bf[ni], acc[mi][ni], 0, 0, 0);
        __syncthreads();
    }
    int bcol[4];
    float bval[4];
#pragma unroll
    for (int ni = 0; ni < 4; ++ni) {
        bcol[ni] = n0 + wn * 64 + ni * 16 + l16;
        bval[ni] = bias ? bias[bcol[ni]] : 0.f;
    }
#pragma unroll
    for (int mi = 0; mi < 4; ++mi) {
#pragma unroll
        for (int r = 0; r < 4; ++r) {
            int row = m0 + wm * 64 + mi * 16 + quad * 4 + r;
            float* Cp = C + (size_t)row * Ndim;
#pragma unroll
            for (int ni = 0; ni < 4; ++ni)
                Cp[bcol[ni]] = acc[mi][ni][r] + bval[ni];
        }
    }
}

// ---------------- gb = tanh(gamma)*d^-0.5 * gk @ K^T (causal-lower tiles only, fp32) ------
__global__ __launch_bounds__(256) void gb_kernel(
        const float* __restrict__ gk, const float* __restrict__ Kmat,
        const float* __restrict__ gamma, float* __restrict__ gb) {
    int lt = blockIdx.x >> 5, mt = blockIdx.x & 31;
    if (mt > lt) return;
    int b = blockIdx.y;
    __shared__ float As[32][68];
    __shared__ float Bs[32][68];
    int tid = threadIdx.x;
    int ty = tid >> 4, tx = tid & 15;
    int l0 = lt * 64, m0 = mt * 64;
    float acc[4][4];
#pragma unroll
    for (int u = 0; u < 4; ++u)
#pragma unroll
        for (int v = 0; v < 4; ++v) acc[u][v] = 0.f;
    int arow = tid >> 2, acol = (tid & 3) * 8;
    const float* Abase = gk   + ((size_t)b * LL + l0 + arow) * DD + acol;
    const float* Bbase = Kmat + ((size_t)b * LL + m0 + arow) * DD + acol;
    for (int kb = 0; kb < DD; kb += 32) {
        float4 a0 = *(const float4*)(Abase + kb);
        float4 a1 = *(const float4*)(Abase + kb + 4);
        As[acol + 0][arow] = a0.x; As[acol + 1][arow] = a0.y;
        As[acol + 2][arow] = a0.z; As[acol + 3][arow] = a0.w;
        As[acol + 4][arow] = a1.x; As[acol + 5][arow] = a1.y;
        As[acol + 6][arow] = a1.z; As[acol + 7][arow] = a1.w;
        float4 b0 = *(const float4*)(Bbase + kb);
        float4 b1 = *(const float4*)(Bbase + kb + 4);
        Bs[acol + 0][arow] = b0.x; Bs[acol + 1][arow] = b0.y;
        Bs[acol + 2][arow] = b0.z; Bs[acol + 3][arow] = b0.w;
        Bs[acol + 4][arow] = b1.x; Bs[acol + 5][arow] = b1.y;
        Bs[acol + 6][arow] = b1.z; Bs[acol + 7][arow] = b1.w;
        __syncthreads();
#pragma unroll 8
        for (int k = 0; k < 32; ++k) {
            float4 av = *(const float4*)&As[k][ty * 4];
            float4 bv = *(const float4*)&Bs[k][tx * 4];
            float aa[4] = {av.x, av.y, av.z, av.w};
            float ba[4] = {bv.x, bv.y, bv.z, bv.w};
#pragma unroll
            for (int u = 0; u < 4; ++u)
#pragma unroll
                for (int v = 0; v < 4; ++v)
                    acc[u][v] += aa[u] * ba[v];
        }
        __syncthreads();
    }
    float scale = tanhf(gamma[0]) * 0.03125f;
#pragma unroll
    for (int u = 0; u < 4; ++u) {
        float4 o;
        o.x = acc[u][0] * scale; o.y = acc[u][1] * scale;
        o.z = acc[u][2] * scale; o.w = acc[u][3] * scale;
        *(float4*)&gb[((size_t)b * LL + l0 + ty * 4 + u) * LL + m0 + tx * 4] = o;
    }
}

// ---------------- gate finisher ----------------
__global__ __launch_bounds__(256) void gate_fin_kernel(
        const float* __restrict__ H1, const float* __restrict__ w2,
        const float* __restrict__ b2, float* __restrict__ gate) {
    int row = blockIdx.x, tid = threadIdx.x;
    float x = H1[(size_t)row * HG + tid];
    float val = gelu_f(x) * w2[tid];
    for (int off = 32; off; off >>= 1) val += __shfl_down(val, off);
    __shared__ float part[4];
    if ((tid & 63) == 0) part[tid >> 6] = val;
    __syncthreads();
    if (tid == 0) {
        float acc = part[0] + part[1] + part[2] + part[3] + b2[0];
        gate[row] = 1.f / (1.f + expf(-acc));
    }
}

// ---------------- nu finisher ----------------
__global__ __launch_bounds__(128) void nu_fin_kernel(
        const float* __restrict__ N1, const float* __restrict__ w2,
        const float* __restrict__ b2, const float* __restrict__ nu_diff,
        const float* __restrict__ nu_adv, float* __restrict__ nub) {
    int row = blockIdx.x, tid = threadIdx.x;
    float t = tanhf(N1[(size_t)row * HN + tid]);
    float val = t * w2[tid];
    for (int off = 32; off; off >>= 1) val += __shfl_down(val, off);
    __shared__ float part[2];
    if ((tid & 63) == 0) part[tid >> 6] = val;
    __syncthreads();
    if (tid == 0) {
        float acc = part[0] + part[1] + b2[0];
        nub[row] = fabsf(nu_diff[0]) + tanhf(acc) * fabsf(nu_adv[0]);
    }
}

// ---------------- gated dual-base RoPE on Q and K -> bf16 head-blocked [b,h,L,64] -------
__global__ void rope_qk_bf16(const float* __restrict__ Q, const float* __restrict__ K,
                             const float* __restrict__ gate,
                             ushort* __restrict__ Q16, ushort* __restrict__ K16) {
    int idx = blockIdx.x * 256 + threadIdx.x;   // over MM*512
    int row = idx >> 9;
    int i = idx & 511;
    int b = row >> 11, t = row & (LL - 1);
    float g = gate[row];
    float fi = (float)i * (1.0f / 512.0f);
    float tf = (float)t;
    float af = tf * expf(-fi * LOG_FAST);
    float as = tf * expf(-fi * LOG_SLOW);
    float c = g * cosf(af) + (1.f - g) * cosf(as);
    float s = g * sinf(af) + (1.f - g) * sinf(as);
    size_t base = (size_t)row * DD;
    float x = Q[base + i], y = Q[base + 512 + i];
    float q1 = x * c - y * s, q2 = y * c + x * s;
    x = K[base + i]; y = K[base + 512 + i];
    float k1 = x * c - y * s, k2 = y * c + x * s;
    int h1 = i >> 6, d1 = i & 63;
    size_t o1 = ((size_t)(b * 16 + h1) * LL + t) * 64 + d1;
    size_t o2 = ((size_t)(b * 16 + 8 + h1) * LL + t) * 64 + d1;
    Q16[o1] = f2b(q1); Q16[o2] = f2b(q2);
    K16[o1] = f2b(k1); K16[o2] = f2b(k2);
}

// ---------------- V fp32 [b*L,1024] -> V^T bf16 [b,h,64,L] ----------------
__global__ __launch_bounds__(256) void vt16_kernel(const float* __restrict__ V,
                                                   ushort* __restrict__ VT) {
    __shared__ ushort t[64][72];
    int lb = blockIdx.x, hb = blockIdx.y, b = blockIdx.z;
    int tid = threadIdx.x;
    {
        int l = tid >> 2, c0 = (tid & 3) * 16;
        const float* Vp = V + ((size_t)(b * LL) + lb * 64 + l) * DD + hb * 64 + c0;
#pragma unroll
        for (int j = 0; j < 4; ++j) {
            float4 v = *(const float4*)(Vp + j * 4);
            t[l][c0 + j * 4 + 0] = f2b(v.x);
            t[l][c0 + j * 4 + 1] = f2b(v.y);
            t[l][c0 + j * 4 + 2] = f2b(v.z);
            t[l][c0 + j * 4 + 3] = f2b(v.w);
        }
    }
    __syncthreads();
    {
        int d = tid >> 2, l0 = (tid & 3) * 16;
        ushort tmp[16];
#pragma unroll
        for (int j = 0; j < 16; ++j) tmp[j] = t[l0 + j][d];
        ushort* Op = VT + ((size_t)((b * 16 + hb) * 64) + d) * LL + lb * 64 + l0;
        *(ushort4*)(Op + 0)  = *(ushort4*)&tmp[0];
        *(ushort4*)(Op + 4)  = *(ushort4*)&tmp[4];
        *(ushort4*)(Op + 8)  = *(ushort4*)&tmp[8];
        *(ushort4*)(Op + 12) = *(ushort4*)&tmp[12];
    }
}

// ---------------- fixed-base RoPE for GLU branch ----------------
__global__ void rope_glu_kernel(const float* __restrict__ z, float* __restrict__ zg) {
    int idx = blockIdx.x * 256 + threadIdx.x;
    int row = idx >> 9;
    int i = idx & 511;
    int t = row & (LL - 1);
    float fi = (float)i * (1.0f / 512.0f);
    float ag = (float)t * expf(-fi * LOG_GLU);
    float c = cosf(ag), s = sinf(ag);
    size_t base = (size_t)row * DD;
    float x = z[base + i], y = z[base + 512 + i];
    zg[base + i]       = x * c - y * s;
    zg[base + 512 + i] = y * c + x * s;
}

// ---------------- MFMA flash attention: 64-q tiles, 64-k tiles ----------------
// grid (h=16, qp=16, b=2); block 256 = 4 waves; each wave owns 16 q rows.
__global__ __launch_bounds__(256) void attn_flash_mfma(
        const ushort* __restrict__ Q16, const ushort* __restrict__ K16,
        const ushort* __restrict__ VT16, const float* __restrict__ gb,
        float* __restrict__ attn_out, float* __restrict__ stats) {
    int h = blockIdx.x, qp = blockIdx.y, b = blockIdx.z;
    __shared__ ushort Qs[4096], Ks[4096], Vs[4096];
    __shared__ ushort Ps[4][16 * 72];
    int tid = threadIdx.x, wid = tid >> 6, lane = tid & 63;
    int quad = lane >> 4, l16 = lane & 15;
    const ushort* Qg = Q16 + ((size_t)(b * 16 + h) * LL) * 64;
    const ushort* Kg = K16 + ((size_t)(b * 16 + h) * LL) * 64;
    const ushort* Vg = VT16 + ((size_t)(b * 16 + h) * 64) * LL;
    const float*  gbB = gb + (size_t)b * LL * LL;
    float* stB = stats + ((size_t)(b * 16 + h) * LL) * 2;
    int qrow = wid * 16 + quad * 4;   // + r = local q row of C-frags

    for (int rep = 0; rep < 2; ++rep) {
        int qt = rep ? (31 - qp) : qp;
        int q0 = qt * 64;
        __syncthreads();
        stage_tile(Qg + (size_t)q0 * 64, 64, Qs, tid);
        __syncthreads();
        short8 qf[2];
#pragma unroll
        for (int ks = 0; ks < 2; ++ks)
            qf[ks] = *(const short8*)(Qs + SWZC(wid * 16 + l16, ks * 4 + quad));
        f32x4 ofr[4];
        float m_r[4], l_r[4];
#pragma unroll
        for (int nt = 0; nt < 4; ++nt) ofr[nt] = (f32x4){0.f, 0.f, 0.f, 0.f};
#pragma unroll
        for (int r = 0; r < 4; ++r) { m_r[r] = -3e38f; l_r[r] = 0.f; }

        for (int kt = 0; kt <= qt; ++kt) {
            int k0 = kt * 64;
            float gbv[4][4];
#pragma unroll
            for (int r = 0; r < 4; ++r) {
                const float* gp = gbB + (size_t)(q0 + qrow + r) * LL + k0 + l16;
#pragma unroll
                for (int nt = 0; nt < 4; ++nt) gbv[nt][r] = gp[nt * 16];
            }
            __syncthreads();
            stage_tile(Kg + (size_t)k0 * 64, 64, Ks, tid);
            stage_tile(Vg + k0, LL, Vs, tid);
            __syncthreads();
            f32x4 sf[4];
#pragma unroll
            for (int nt = 0; nt < 4; ++nt) sf[nt] = (f32x4){0.f, 0.f, 0.f, 0.f};
#pragma unroll
            for (int ks = 0; ks < 2; ++ks)
#pragma unroll
                for (int nt = 0; nt < 4; ++nt) {
                    short8 kf = *(const short8*)(Ks + SWZC(nt * 16 + l16, ks * 4 + quad));
                    sf[nt] = __builtin_amdgcn_mfma_f32_16x16x32_bf16(qf[ks], kf, sf[nt], 0, 0, 0);
                }
            float sc[4][4];
            bool diag = (kt == qt);
#pragma unroll
            for (int nt = 0; nt < 4; ++nt)
#pragma unroll
                for (int r = 0; r < 4; ++r) {
                    float v = sf[nt][r] * 0.125f + gbv[nt][r];
                    if (diag && (nt * 16 + l16 > qrow + r)) v = -1e30f;
                    sc[nt][r] = v;
                }
            float alpha[4];
#pragma unroll
            for (int r = 0; r < 4; ++r) {
                float m = fmaxf(fmaxf(sc[0][r], sc[1][r]), fmaxf(sc[2][r], sc[3][r]));
#pragma unroll
                for (int off = 1; off < 16; off <<= 1)
                    m = fmaxf(m, __shfl_xor(m, off));
                float nm = fmaxf(m_r[r], m);
                alpha[r] = expf(m_r[r] - nm);
                m_r[r] = nm;
            }
            float rs[4] = {0.f, 0.f, 0.f, 0.f};
#pragma unroll
            for (int nt = 0; nt < 4; ++nt)
#pragma unroll
                for (int r = 0; r < 4; ++r) {
                    float p = expf(sc[nt][r] - m_r[r]);
                    rs[r] += p;
                    Ps[wid][(quad * 4 + r) * 72 + nt * 16 + l16] = f2b(p);
                }
#pragma unroll
            for (int r = 0; r < 4; ++r) {
#pragma unroll
                for (int off = 1; off < 16; off <<= 1)
                    rs[r] += __shfl_xor(rs[r], off);
                l_r[r] = l_r[r] * alpha[r] + rs[r];
            }
#pragma unroll
            for (int nt = 0; nt < 4; ++nt)
#pragma unroll
                for (int r = 0; r < 4; ++r) ofr[nt][r] *= alpha[r];
            short8 pf[2];
#pragma unroll
            for (int ks = 0; ks < 2; ++ks)
                pf[ks] = *(const short8*)(Ps[wid] + l16 * 72 + ks * 32 + quad * 8);
#pragma unroll
            for (int ks = 0; ks < 2; ++ks)
#pragma unroll
                for (int nt = 0; nt < 4; ++nt) {
                    short8 vf = *(const short8*)(Vs + SWZC(nt * 16 + l16, ks * 4 + quad));
                    ofr[nt] = __builtin_amdgcn_mfma_f32_16x16x32_bf16(pf[ks], vf, ofr[nt], 0, 0, 0);
                }
        }
#pragma unroll
        for (int r = 0; r < 4; ++r) {
            float rinv = 1.0f / l_r[r];
            float* op = attn_out + ((size_t)(b * LL) + q0 + qrow + r) * DD + h * 64 + l16;
#pragma unroll
            for (int nt = 0; nt < 4; ++nt)
                op[nt * 16] = ofr[nt][r] * rinv;
        }
        if (l16 == 0) {
#pragma unroll
            for (int r = 0; r < 4; ++r) {
                size_t si = (size_t)(q0 + qrow + r) * 2;
                stB[si]     = m_r[r];
                stB[si + 1] = l_r[r];
            }
        }
    }
}

// ---------------- attn_w = mean over heads (MFMA recompute from stats) ----------------
__global__ __launch_bounds__(256) void attn_w_mfma(
        const ushort* __restrict__ Q16, const ushort* __restrict__ K16,
        const float* __restrict__ gb, const float* __restrict__ stats,
        float* __restrict__ aw) {
    int qt = blockIdx.x >> 5, kt = blockIdx.x & 31;
    int b = blockIdx.y;
    int tid = threadIdx.x, wid = tid >> 6, lane = tid & 63;
    int quad = lane >> 4, l16 = lane & 15;
    int q0 = qt * 64, k0 = kt * 64;
    int qrow = wid * 16 + quad * 4;
    if (kt > qt) {
        int rr = tid >> 2, c0 = (tid & 3) * 16;
        float4 zv = make_float4(0.f, 0.f, 0.f, 0.f);
        float* p = aw + ((size_t)(b * LL) + q0 + rr) * LL + k0 + c0;
#pragma unroll
        for (int j = 0; j < 4; ++j) *(float4*)(p + j * 4) = zv;
        return;
    }
    __shared__ ushort Qs[4096], Ks[4096];
    __shared__ float sm[64], sli[64];
    float acc[4][4];
#pragma unroll
    for (int nt = 0; nt < 4; ++nt)
#pragma unroll
        for (int r = 0; r < 4; ++r) acc[nt][r] = 0.f;
    float gbv[4][4];
    const float* gbB = gb + (size_t)b * LL * LL;
#pragma unroll
    for (int r = 0; r < 4; ++r) {
        const float* gp = gbB + (size_t)(q0 + qrow + r) * LL + k0 + l16;
#pragma unroll
        for (int nt = 0; nt < 4; ++nt) gbv[nt][r] = gp[nt * 16];
    }
    bool diag = (kt == qt);
    for (int h = 0; h < NHH; ++h) {
        __syncthreads();
        stage_tile(Q16 + ((size_t)(b * 16 + h) * LL + q0) * 64, 64, Qs, tid);
        stage_tile(K16 + ((size_t)(b * 16 + h) * LL + k0) * 64, 64, Ks, tid);
        if (tid < 64) {
            const float* sp = stats + ((size_t)(b * 16 + h) * LL + q0 + tid) * 2;
            sm[tid]  = sp[0];
            sli[tid] = 1.0f / sp[1];
        }
        __syncthreads();
        short8 qf[2];
#pragma unroll
        for (int ks = 0; ks < 2; ++ks)
            qf[ks] = *(const short8*)(Qs + SWZC(wid * 16 + l16, ks * 4 + quad));
        f32x4 sf[4];
#pragma unroll
        for (int nt = 0; nt < 4; ++nt) sf[nt] = (f32x4){0.f, 0.f, 0.f, 0.f};
#pragma unroll
        for (int ks = 0; ks < 2; ++ks)
#pragma unroll
            for (int nt = 0; nt < 4; ++nt) {
                short8 kf = *(const short8*)(Ks + SWZC(nt * 16 + l16, ks * 4 + quad));
                sf[nt] = __builtin_amdgcn_mfma_f32_16x16x32_bf16(qf[ks], kf, sf[nt], 0, 0, 0);
            }
#pragma unroll
        for (int nt = 0; nt < 4; ++nt)
#pragma unroll
            for (int r = 0; r < 4; ++r) {
                int row = qrow + r;
                if (!diag || (nt * 16 + l16 <= row))
                    acc[nt][r] += expf(sf[nt][r] * 0.125f + gbv[nt][r] - sm[row]) * sli[row];
            }
    }
#pragma unroll
    for (int r = 0; r < 4; ++r) {
        float* op = aw + ((size_t)(b * LL) + q0 + qrow + r) * LL + k0 + l16;
#pragma unroll
        for (int nt = 0; nt < 4; ++nt)
            op[nt * 16] = acc[nt][r] * 0.0625f;
    }
}

// ---------------- adv = -nu*U*G, layernorm -> adv_n ----------------
__global__ __launch_bounds__(256) void adv_ln_kernel(
        const float* __restrict__ U, const float* __restrict__ G,
        const float* __restrict__ nub, const float* __restrict__ lnw,
        const float* __restrict__ lnb, float* __restrict__ out) {
    int row = blockIdx.x, tid = threadIdx.x;
    size_t base = (size_t)row * DD + tid * 4;
    float4 u4 = *(const float4*)&U[base];
    float4 g4 = *(const float4*)&G[base];
    float nu = nub[row];
    float a[4];
    a[0] = -nu * u4.x * g4.x;
    a[1] = -nu * u4.y * g4.y;
    a[2] = -nu * u4.z * g4.z;
    a[3] = -nu * u4.w * g4.w;
    float ts = a[0] + a[1] + a[2] + a[3];
    float tq = a[0] * a[0] + a[1] * a[1] + a[2] * a[2] + a[3] * a[3];
    for (int off = 32; off; off >>= 1) {
        ts += __shfl_down(ts, off);
        tq += __shfl_down(tq, off);
    }
    __shared__ float r1[4], r2[4];
    if ((tid & 63) == 0) { r1[tid >> 6] = ts; r2[tid >> 6] = tq; }
    __syncthreads();
    __shared__ float s_mu, s_rs;
    if (tid == 0) {
        float S  = r1[0] + r1[1] + r1[2] + r1[3];
        float Qq = r2[0] + r2[1] + r2[2] + r2[3];
        float mu = S * (1.0f / 1024.f);
        float var = Qq * (1.0f / 1024.f) - mu * mu;
        s_mu = mu;
        s_rs = rsqrtf(var + 1e-5f);
    }
    __syncthreads();
    float mu = s_mu, rs = s_rs;
    float4 w4 = *(const float4*)&lnw[tid * 4];
    float4 b4 = *(const float4*)&lnb[tid * 4];
    float4 ov;
    ov.x = (a[0] - mu) * rs * w4.x + b4.x;
    ov.y = (a[1] - mu) * rs * w4.y + b4.y;
    ov.z = (a[2] - mu) * rs * w4.z + b4.z;
    ov.w = (a[3] - mu) * rs * w4.w + b4.w;
    *(float4*)&out[base] = ov;
}

// ---------------- final residual combine ----------------
__global__ void final_kernel(const float* __restrict__ z, const float* __restrict__ ao,
                             const float* __restrict__ mlp, float* __restrict__ out) {
    size_t i = ((size_t)blockIdx.x * 256 + threadIdx.x) * 4;
    float4 z4 = *(const float4*)&z[i];
    float4 a4 = *(const float4*)&ao[i];
    float4 m4 = *(const float4*)&mlp[i];
    float4 o;
    o.x = z4.x + 0.42f * a4.x + 1.07f * m4.x;
    o.y = z4.y + 0.42f * a4.y + 1.07f * m4.y;
    o.z = z4.z + 0.42f * a4.z + 1.07f * m4.z;
    o.w = z4.w + 0.42f * a4.w + 1.07f * m4.w;
    *(float4*)&out[i] = o;
}

extern "C" void kernel_launch(void* const* d_in, const int* in_sizes, int n_in,
                              void* d_out, int out_size, void* d_ws, size_t ws_size,
                              hipStream_t stream) {
    const float* z       = (const float*)d_in[0];
    const float* Wq      = (const float*)d_in[1];
    const float* bq      = (const float*)d_in[2];
    const float* Wk      = (const float*)d_in[3];
    const float* bk      = (const float*)d_in[4];
    const float* Wv      = (const float*)d_in[5];
    const float* bv      = (const float*)d_in[6];
    const float* Wcoh    = (const float*)d_in[7];
    const float* gamma   = (const float*)d_in[8];
    const float* rg_w1   = (const float*)d_in[9];
    const float* rg_b1   = (const float*)d_in[10];
    const float* rg_w2   = (const float*)d_in[11];
    const float* rg_b2   = (const float*)d_in[12];
    const float* nu_diff = (const float*)d_in[13];
    const float* nu_adv  = (const float*)d_in[14];
    const float* nu_w1   = (const float*)d_in[15];
    const float* nu_b1   = (const float*)d_in[16];
    const float* nu_w2   = (const float*)d_in[17];
    const float* nu_b2   = (const float*)d_in[18];
    const float* Wu      = (const float*)d_in[19];
    const float* bu      = (const float*)d_in[20];
    const float* Wg      = (const float*)d_in[21];
    const float* bg      = (const float*)d_in[22];
    const float* ln_w    = (const float*)d_in[23];
    const float* ln_b    = (const float*)d_in[24];
    const float* Cw      = (const float*)d_in[25];
    const float* Cb      = (const float*)d_in[26];

    float* out_z  = (float*)d_out;
    float* out_aw = out_z + (size_t)MM * DD;

    float* ws = (float*)d_ws;
    const size_t MD = (size_t)MM * DD;   // 4,194,304
    float* pool  = ws;               // later: VT16 (bf16), then z_glu
    float* Qb    = ws + MD;          // later U, later mlp_out
    float* Kb    = ws + 2 * MD;      // later G
    float* Vb    = ws + 3 * MD;      // later Q16/K16 (bf16), then adv_n
    float* gkb   = ws + 4 * MD;      // later attn_out
    float* gbb   = ws + 5 * MD;      // B*L*L = 2*MD (gb); Ab/Wb alias when gb dead
    float* H1    = ws + 7 * MD;      // MM*256
    float* N1    = H1 + (size_t)MM * HG;
    float* gate  = N1 + (size_t)MM * HN;
    float* nub   = gate + MM;
    float* stats = nub + MM;                       // B*NH*L*2
    float* ctot  = stats + (size_t)BB * NHH * LL * 2;  // B*NCH*DD

    // bf16 aliases
    ushort* Ab   = (ushort*)gbb;                 // staging for GEMM A
    ushort* Wb   = (ushort*)(gbb + MD / 2);      // staging for GEMM W^T
    ushort* Q16  = (ushort*)Vb;                  // [b,h,L,64]
    ushort* K16  = (ushort*)Vb + MD;             // [b,h,L,64]
    ushort* VT16 = (ushort*)pool;                // [b,h,64,L]

    dim3 g128(8, 32);
    dim3 cvt_g(4096);
    dim3 wT_g(32, 32);

    // 1. pool (parallel scan)
    pool_scan1<<<dim3(NCH, 4, BB), 256, 0, stream>>>(z, pool, ctot);
    pool_scan2<<<dim3(NCH, 4, BB), 256, 0, stream>>>(ctot, pool);
    // 2. zb -> Ab; Q,K,V GEMMs
    f2b_kernel<<<cvt_g, 256, 0, stream>>>(z, Ab);
    f2bT_kernel<<<wT_g, 256, 0, stream>>>(Wq, Wb, DD);
    gemm_mfma<<<g128, 256, 0, stream>>>(Ab, Wb, bq, Qb, DD);
    f2bT_kernel<<<wT_g, 256, 0, stream>>>(Wk, Wb, DD);
    gemm_mfma<<<g128, 256, 0, stream>>>(Ab, Wb, bk, Kb, DD);
    f2bT_kernel<<<wT_g, 256, 0, stream>>>(Wv, Wb, DD);
    gemm_mfma<<<g128, 256, 0, stream>>>(Ab, Wb, bv, Vb, DD);
    // 3. pool GEMMs: gk, H1, N1
    f2b_kernel<<<cvt_g, 256, 0, stream>>>(pool, Ab);
    f2bT_kernel<<<wT_g, 256, 0, stream>>>(Wcoh, Wb, DD);
    gemm_mfma<<<g128, 256, 0, stream>>>(Ab, Wb, nullptr, gkb, DD);
    f2bT_kernel<<<dim3(8, 32), 256, 0, stream>>>(rg_w1, Wb, HG);
    gemm_mfma<<<dim3(2, 32), 256, 0, stream>>>(Ab, Wb, rg_b1, H1, HG);
    f2bT_kernel<<<dim3(4, 32), 256, 0, stream>>>(nu_w1, Wb, HN);
    gemm_mfma<<<dim3(1, 32), 256, 0, stream>>>(Ab, Wb, nu_b1, N1, HN);
    // 4. gb (fp32) — overwrites Ab/Wb region (dead until step 11)
    gb_kernel<<<dim3(1024, BB), 256, 0, stream>>>(gkb, Kb, gamma, gbb);
    // 5. gate / nu finishers
    gate_fin_kernel<<<dim3(MM), 256, 0, stream>>>(H1, rg_w2, rg_b2, gate);
    nu_fin_kernel<<<dim3(MM), 128, 0, stream>>>(N1, nu_w2, nu_b2, nu_diff, nu_adv, nub);
    // 6. V^T bf16 (reads Vb fp32, writes pool region) — BEFORE rope overwrites Vb
    vt16_kernel<<<dim3(32, 16, BB), 256, 0, stream>>>(Vb, VT16);
    // 7. rope Q,K -> bf16 head-blocked (into Vb region)
    rope_qk_bf16<<<dim3((MM * 512) / 256), 256, 0, stream>>>(Qb, Kb, gate, Q16, K16);
    // 8. MFMA flash attention -> attn_out (gkb) + stats
    attn_flash_mfma<<<dim3(NHH, 16, BB), 256, 0, stream>>>(Q16, K16, VT16, gbb, gkb, stats);
    // 9. attn_w -> second half of d_out
    attn_w_mfma<<<dim3(1024, BB), 256, 0, stream>>>(Q16, K16, gbb, stats, out_aw);
    // 10. z_glu (reuses pool buffer; VT16 dead)
    rope_glu_kernel<<<dim3((MM * 512) / 256), 256, 0, stream>>>(z, pool);
    // 11. U, G GEMMs (gb dead -> Ab/Wb free)
    f2b_kernel<<<cvt_g, 256, 0, stream>>>(pool, Ab);
    f2bT_kernel<<<wT_g, 256, 0, stream>>>(Wu, Wb, DD);
    gemm_mfma<<<g128, 256, 0, stream>>>(Ab, Wb, bu, Qb, DD);
    f2bT_kernel<<<wT_g, 256, 0, stream>>>(Wg, Wb, DD);
    gemm_mfma<<<g128, 256, 0, stream>>>(Ab, Wb, bg, Kb, DD);
    // 12. adv + layernorm -> Vb (Q16/K16 dead)
    adv_ln_kernel<<<dim3(MM), 256, 0, stream>>>(Qb, Kb, nub, ln_w, ln_b, Vb);
    // 13. mlp_out = adv_n @ Cw + Cb -> Qb
    f2b_kernel<<<cvt_g, 256, 0, stream>>>(Vb, Ab);
    f2bT_kernel<<<wT_g, 256, 0, stream>>>(Cw, Wb, DD);
    gemm_mfma<<<g128, 256, 0, stream>>>(Ab, Wb, Cb, Qb, DD);
    // 14. final combine
    final_kernel<<<dim3(MD / 4 / 256), 256, 0, stream>>>(z, gkb, Qb, out_z);
}

// Round 4
// 758.578 us; speedup vs baseline: 4.5743x; 1.2254x over previous
//
#include <hip/hip_runtime.h>

#define DD 1024
#define NHH 16
#define HDD 64
#define BB 2
#define LL 2048
#define MM (BB*LL)          // 4096 rows
#define HG 256
#define HN 128

#define LOG_FAST 0.48121182f   // ln((1+sqrt(5))/2)
#define LOG_SLOW 7.3889461f    // ln(1618.0)
#define LOG_GLU  9.6915312f    // ln(16180.0)

typedef __attribute__((ext_vector_type(8))) short short8;
typedef __attribute__((ext_vector_type(4))) float f32x4;

__device__ __forceinline__ float gelu_f(float x) {
    return 0.5f * x * (1.0f + erff(x * 0.70710678f));
}

__device__ __forceinline__ ushort f2b(float x) {
    unsigned u = __float_as_uint(x);
    unsigned r = (u + 0x7FFFu + ((u >> 16) & 1u)) >> 16;
    return (ushort)r;
}

__device__ __forceinline__ void gl_lds16(const ushort* g, ushort* l) {
    __builtin_amdgcn_global_load_lds(
        (const __attribute__((address_space(1))) unsigned int*)g,
        (__attribute__((address_space(3))) unsigned int*)l, 16, 0, 0);
}

// ushort offset of swizzled 16B chunk within a 64x64 bf16 tile
#define SWZC(row, c8) (((((row) << 3) | ((c8) ^ ((row) & 7)))) << 3)

// Stage a 64x64 bf16 tile (row-major, rstride in elements) into LDS with XOR swizzle.
__device__ __forceinline__ void stage_tile(const ushort* gsrc, int rstride,
                                           ushort* lds, int tid) {
    int wid = tid >> 6;
#pragma unroll
    for (int r = 0; r < 2; ++r) {
        int c = r * 256 + tid;
        int row = c >> 3;
        int c8 = (c & 7) ^ (row & 7);
        gl_lds16(gsrc + (size_t)row * rstride + c8 * 8,
                 lds + (size_t)(r * 256 + wid * 64) * 8);
    }
}

// ---------------- parallel causal cumulative mean pool ----------------
#define LCH 128
#define NCH 16
__global__ void pool_scan1(const float* __restrict__ z, float* __restrict__ pool,
                           float* __restrict__ ctot) {
    int ch = blockIdx.x, dg = blockIdx.y, b = blockIdx.z;
    int d = dg * 256 + threadIdx.x;
    const float* zp = z + ((size_t)b * LL + ch * LCH) * DD + d;
    float* pp = pool + ((size_t)b * LL + ch * LCH) * DD + d;
    float s = 0.f;
    for (int t = 0; t < LCH; ++t) {
        s += zp[(size_t)t * DD];
        pp[(size_t)t * DD] = s;
    }
    ctot[((size_t)b * NCH + ch) * DD + d] = s;
}
__global__ void pool_scan2(const float* __restrict__ ctot, float* __restrict__ pool) {
    int ch = blockIdx.x, dg = blockIdx.y, b = blockIdx.z;
    int d = dg * 256 + threadIdx.x;
    float off = 0.f;
    for (int c = 0; c < ch; ++c) off += ctot[((size_t)b * NCH + c) * DD + d];
    int t0 = ch * LCH;
    float* pp = pool + ((size_t)b * LL + t0) * DD + d;
    for (int t = 0; t < LCH; ++t) {
        pp[(size_t)t * DD] = (pp[(size_t)t * DD] + off) / (float)(t0 + t + 1);
    }
}

// ---------------- fp32 -> bf16 converters ----------------
__global__ void f2b_kernel(const float* __restrict__ in, ushort* __restrict__ out) {
    size_t i = ((size_t)blockIdx.x * 256 + threadIdx.x) * 4;
    float4 v = *(const float4*)&in[i];
    ushort4 o;
    o.x = f2b(v.x); o.y = f2b(v.y); o.z = f2b(v.z); o.w = f2b(v.w);
    *(ushort4*)&out[i] = o;
}

// W (1024 x Ndim) fp32 -> Wt (Ndim x 1024) bf16
__global__ void f2bT_kernel(const float* __restrict__ W, ushort* __restrict__ Wt, int Ndim) {
    __shared__ float t[32][33];
    int n0 = blockIdx.x * 32, k0 = blockIdx.y * 32;
    int tx = threadIdx.x & 31, ty = threadIdx.x >> 5;   // ty 0..7
#pragma unroll
    for (int j = 0; j < 4; ++j)
        t[ty + j * 8][tx] = W[(size_t)(k0 + ty + j * 8) * Ndim + n0 + tx];
    __syncthreads();
#pragma unroll
    for (int j = 0; j < 4; ++j)
        Wt[(size_t)(n0 + ty + j * 8) * 1024 + k0 + tx] = f2b(t[tx][ty + j * 8]);
}

// ---------------- bf16 MFMA GEMM: C(fp32, M x Ndim) = A(M x 1024 bf16) @ Wt^T + bias
__global__ __launch_bounds__(256) void gemm_mfma(
        const ushort* __restrict__ A, const ushort* __restrict__ Wt,
        const float* __restrict__ bias, float* __restrict__ C, int Ndim) {
    __shared__ ushort As[4096];   // [quad][row 0..127][8]
    __shared__ ushort Bs[4096];
    int tid = threadIdx.x;
    int wid = tid >> 6, lane = tid & 63;
    int n0 = blockIdx.x * 128, m0 = blockIdx.y * 128;
    int wm = wid >> 1, wn = wid & 1;
    int quad = lane >> 4, l16 = lane & 15;

    f32x4 acc[4][4];
#pragma unroll
    for (int mi = 0; mi < 4; ++mi)
#pragma unroll
        for (int ni = 0; ni < 4; ++ni) acc[mi][ni] = (f32x4){0.f, 0.f, 0.f, 0.f};

    int c0 = wid * 128 + lane;
    int c1 = c0 + 64;
    const ushort* Ag0 = A + (size_t)(m0 + (c0 & 127)) * 1024 + (c0 >> 7) * 8;
    const ushort* Ag1 = A + (size_t)(m0 + (c1 & 127)) * 1024 + (c1 >> 7) * 8;
    const ushort* Bg0 = Wt + (size_t)(n0 + (c0 & 127)) * 1024 + (c0 >> 7) * 8;
    const ushort* Bg1 = Wt + (size_t)(n0 + (c1 & 127)) * 1024 + (c1 >> 7) * 8;
    ushort* Al0 = As + wid * 1024;
    ushort* Al1 = As + wid * 1024 + 512;
    ushort* Bl0 = Bs + wid * 1024;
    ushort* Bl1 = Bs + wid * 1024 + 512;

    const ushort* a_rd = &As[(quad * 128 + wm * 64 + l16) * 8];
    const ushort* b_rd = &Bs[(quad * 128 + wn * 64 + l16) * 8];

    for (int kb = 0; kb < 1024; kb += 32) {
        gl_lds16(Ag0 + kb, Al0);
        gl_lds16(Ag1 + kb, Al1);
        gl_lds16(Bg0 + kb, Bl0);
        gl_lds16(Bg1 + kb, Bl1);
        __syncthreads();
        short8 af[4], bf[4];
#pragma unroll
        for (int mi = 0; mi < 4; ++mi)
            af[mi] = *(const short8*)(a_rd + mi * 16 * 8);
#pragma unroll
        for (int ni = 0; ni < 4; ++ni)
            bf[ni] = *(const short8*)(b_rd + ni * 16 * 8);
#pragma unroll
        for (int mi = 0; mi < 4; ++mi)
#pragma unroll
            for (int ni = 0; ni < 4; ++ni)
                acc[mi][ni] = __builtin_amdgcn_mfma_f32_16x16x32_bf16(
                    af[mi], bf[ni], acc[mi][ni], 0, 0, 0);
        __syncthreads();
    }
    int bcol[4];
    float bval[4];
#pragma unroll
    for (int ni = 0; ni < 4; ++ni) {
        bcol[ni] = n0 + wn * 64 + ni * 16 + l16;
        bval[ni] = bias ? bias[bcol[ni]] : 0.f;
    }
#pragma unroll
    for (int mi = 0; mi < 4; ++mi) {
#pragma unroll
        for (int r = 0; r < 4; ++r) {
            int row = m0 + wm * 64 + mi * 16 + quad * 4 + r;
            float* Cp = C + (size_t)row * Ndim;
#pragma unroll
            for (int ni = 0; ni < 4; ++ni)
                Cp[bcol[ni]] = acc[mi][ni][r] + bval[ni];
        }
    }
}

// ---------------- same GEMM but bf16 output, no bias (for gk) ----------------
__global__ __launch_bounds__(256) void gemm_mfma_b16out(
        const ushort* __restrict__ A, const ushort* __restrict__ Wt,
        ushort* __restrict__ C, int Ndim) {
    __shared__ ushort As[4096];
    __shared__ ushort Bs[4096];
    int tid = threadIdx.x;
    int wid = tid >> 6, lane = tid & 63;
    int n0 = blockIdx.x * 128, m0 = blockIdx.y * 128;
    int wm = wid >> 1, wn = wid & 1;
    int quad = lane >> 4, l16 = lane & 15;

    f32x4 acc[4][4];
#pragma unroll
    for (int mi = 0; mi < 4; ++mi)
#pragma unroll
        for (int ni = 0; ni < 4; ++ni) acc[mi][ni] = (f32x4){0.f, 0.f, 0.f, 0.f};

    int c0 = wid * 128 + lane;
    int c1 = c0 + 64;
    const ushort* Ag0 = A + (size_t)(m0 + (c0 & 127)) * 1024 + (c0 >> 7) * 8;
    const ushort* Ag1 = A + (size_t)(m0 + (c1 & 127)) * 1024 + (c1 >> 7) * 8;
    const ushort* Bg0 = Wt + (size_t)(n0 + (c0 & 127)) * 1024 + (c0 >> 7) * 8;
    const ushort* Bg1 = Wt + (size_t)(n0 + (c1 & 127)) * 1024 + (c1 >> 7) * 8;
    ushort* Al0 = As + wid * 1024;
    ushort* Al1 = As + wid * 1024 + 512;
    ushort* Bl0 = Bs + wid * 1024;
    ushort* Bl1 = Bs + wid * 1024 + 512;

    const ushort* a_rd = &As[(quad * 128 + wm * 64 + l16) * 8];
    const ushort* b_rd = &Bs[(quad * 128 + wn * 64 + l16) * 8];

    for (int kb = 0; kb < 1024; kb += 32) {
        gl_lds16(Ag0 + kb, Al0);
        gl_lds16(Ag1 + kb, Al1);
        gl_lds16(Bg0 + kb, Bl0);
        gl_lds16(Bg1 + kb, Bl1);
        __syncthreads();
        short8 af[4], bf[4];
#pragma unroll
        for (int mi = 0; mi < 4; ++mi)
            af[mi] = *(const short8*)(a_rd + mi * 16 * 8);
#pragma unroll
        for (int ni = 0; ni < 4; ++ni)
            bf[ni] = *(const short8*)(b_rd + ni * 16 * 8);
#pragma unroll
        for (int mi = 0; mi < 4; ++mi)
#pragma unroll
            for (int ni = 0; ni < 4; ++ni)
                acc[mi][ni] = __builtin_amdgcn_mfma_f32_16x16x32_bf16(
                    af[mi], bf[ni], acc[mi][ni], 0, 0, 0);
        __syncthreads();
    }
#pragma unroll
    for (int mi = 0; mi < 4; ++mi) {
#pragma unroll
        for (int r = 0; r < 4; ++r) {
            int row = m0 + wm * 64 + mi * 16 + quad * 4 + r;
            ushort* Cp = C + (size_t)row * Ndim;
#pragma unroll
            for (int ni = 0; ni < 4; ++ni)
                Cp[n0 + wn * 64 + ni * 16 + l16] = f2b(acc[mi][ni][r]);
        }
    }
}

// ---------------- gb = tanh(gamma)/32 * gk16 @ K16r^T, causal-lower 128-tiles, MFMA ----
__global__ __launch_bounds__(256) void gb_mfma(
        const ushort* __restrict__ gk16, const ushort* __restrict__ K16r,
        const float* __restrict__ gamma, float* __restrict__ gb) {
    int lt = blockIdx.x >> 4, mt = blockIdx.x & 15;
    if (mt > lt) return;
    int b = blockIdx.y;
    __shared__ ushort As[4096];
    __shared__ ushort Bs[4096];
    int tid = threadIdx.x;
    int wid = tid >> 6, lane = tid & 63;
    int l0 = lt * 128, m0 = mt * 128;
    int wm = wid >> 1, wn = wid & 1;
    int quad = lane >> 4, l16 = lane & 15;

    f32x4 acc[4][4];
#pragma unroll
    for (int mi = 0; mi < 4; ++mi)
#pragma unroll
        for (int ni = 0; ni < 4; ++ni) acc[mi][ni] = (f32x4){0.f, 0.f, 0.f, 0.f};

    int c0 = wid * 128 + lane;
    int c1 = c0 + 64;
    const ushort* Ag0 = gk16 + ((size_t)b * LL + l0 + (c0 & 127)) * 1024 + (c0 >> 7) * 8;
    const ushort* Ag1 = gk16 + ((size_t)b * LL + l0 + (c1 & 127)) * 1024 + (c1 >> 7) * 8;
    const ushort* Bg0 = K16r + ((size_t)b * LL + m0 + (c0 & 127)) * 1024 + (c0 >> 7) * 8;
    const ushort* Bg1 = K16r + ((size_t)b * LL + m0 + (c1 & 127)) * 1024 + (c1 >> 7) * 8;
    ushort* Al0 = As + wid * 1024;
    ushort* Al1 = As + wid * 1024 + 512;
    ushort* Bl0 = Bs + wid * 1024;
    ushort* Bl1 = Bs + wid * 1024 + 512;

    const ushort* a_rd = &As[(quad * 128 + wm * 64 + l16) * 8];
    const ushort* b_rd = &Bs[(quad * 128 + wn * 64 + l16) * 8];

    for (int kb = 0; kb < 1024; kb += 32) {
        gl_lds16(Ag0 + kb, Al0);
        gl_lds16(Ag1 + kb, Al1);
        gl_lds16(Bg0 + kb, Bl0);
        gl_lds16(Bg1 + kb, Bl1);
        __syncthreads();
        short8 af[4], bf[4];
#pragma unroll
        for (int mi = 0; mi < 4; ++mi)
            af[mi] = *(const short8*)(a_rd + mi * 16 * 8);
#pragma unroll
        for (int ni = 0; ni < 4; ++ni)
            bf[ni] = *(const short8*)(b_rd + ni * 16 * 8);
#pragma unroll
        for (int mi = 0; mi < 4; ++mi)
#pragma unroll
            for (int ni = 0; ni < 4; ++ni)
                acc[mi][ni] = __builtin_amdgcn_mfma_f32_16x16x32_bf16(
                    af[mi], bf[ni], acc[mi][ni], 0, 0, 0);
        __syncthreads();
    }
    float scale = tanhf(gamma[0]) * 0.03125f;
#pragma unroll
    for (int mi = 0; mi < 4; ++mi) {
#pragma unroll
        for (int r = 0; r < 4; ++r) {
            int row = l0 + wm * 64 + mi * 16 + quad * 4 + r;
            float* Cp = gb + ((size_t)b * LL + row) * LL;
#pragma unroll
            for (int ni = 0; ni < 4; ++ni)
                Cp[m0 + wn * 64 + ni * 16 + l16] = acc[mi][ni][r] * scale;
        }
    }
}

// ---------------- gate finisher ----------------
__global__ __launch_bounds__(256) void gate_fin_kernel(
        const float* __restrict__ H1, const float* __restrict__ w2,
        const float* __restrict__ b2, float* __restrict__ gate) {
    int row = blockIdx.x, tid = threadIdx.x;
    float x = H1[(size_t)row * HG + tid];
    float val = gelu_f(x) * w2[tid];
    for (int off = 32; off; off >>= 1) val += __shfl_down(val, off);
    __shared__ float part[4];
    if ((tid & 63) == 0) part[tid >> 6] = val;
    __syncthreads();
    if (tid == 0) {
        float acc = part[0] + part[1] + part[2] + part[3] + b2[0];
        gate[row] = 1.f / (1.f + expf(-acc));
    }
}

// ---------------- nu finisher ----------------
__global__ __launch_bounds__(128) void nu_fin_kernel(
        const float* __restrict__ N1, const float* __restrict__ w2,
        const float* __restrict__ b2, const float* __restrict__ nu_diff,
        const float* __restrict__ nu_adv, float* __restrict__ nub) {
    int row = blockIdx.x, tid = threadIdx.x;
    float t = tanhf(N1[(size_t)row * HN + tid]);
    float val = t * w2[tid];
    for (int off = 32; off; off >>= 1) val += __shfl_down(val, off);
    __shared__ float part[2];
    if ((tid & 63) == 0) part[tid >> 6] = val;
    __syncthreads();
    if (tid == 0) {
        float acc = part[0] + part[1] + b2[0];
        nub[row] = fabsf(nu_diff[0]) + tanhf(acc) * fabsf(nu_adv[0]);
    }
}

// ---------------- gated dual-base RoPE on Q and K -> bf16 head-blocked [b,h,L,64] -------
__global__ void rope_qk_bf16(const float* __restrict__ Q, const float* __restrict__ K,
                             const float* __restrict__ gate,
                             ushort* __restrict__ Q16, ushort* __restrict__ K16) {
    int idx = blockIdx.x * 256 + threadIdx.x;   // over MM*512
    int row = idx >> 9;
    int i = idx & 511;
    int b = row >> 11, t = row & (LL - 1);
    float g = gate[row];
    float fi = (float)i * (1.0f / 512.0f);
    float tf = (float)t;
    float af = tf * expf(-fi * LOG_FAST);
    float as = tf * expf(-fi * LOG_SLOW);
    float c = g * cosf(af) + (1.f - g) * cosf(as);
    float s = g * sinf(af) + (1.f - g) * sinf(as);
    size_t base = (size_t)row * DD;
    float x = Q[base + i], y = Q[base + 512 + i];
    float q1 = x * c - y * s, q2 = y * c + x * s;
    x = K[base + i]; y = K[base + 512 + i];
    float k1 = x * c - y * s, k2 = y * c + x * s;
    int h1 = i >> 6, d1 = i & 63;
    size_t o1 = ((size_t)(b * 16 + h1) * LL + t) * 64 + d1;
    size_t o2 = ((size_t)(b * 16 + 8 + h1) * LL + t) * 64 + d1;
    Q16[o1] = f2b(q1); Q16[o2] = f2b(q2);
    K16[o1] = f2b(k1); K16[o2] = f2b(k2);
}

// ---------------- V fp32 [b*L,1024] -> V^T bf16 [b,h,64,L] ----------------
__global__ __launch_bounds__(256) void vt16_kernel(const float* __restrict__ V,
                                                   ushort* __restrict__ VT) {
    __shared__ ushort t[64][72];
    int lb = blockIdx.x, hb = blockIdx.y, b = blockIdx.z;
    int tid = threadIdx.x;
    {
        int l = tid >> 2, c0 = (tid & 3) * 16;
        const float* Vp = V + ((size_t)(b * LL) + lb * 64 + l) * DD + hb * 64 + c0;
#pragma unroll
        for (int j = 0; j < 4; ++j) {
            float4 v = *(const float4*)(Vp + j * 4);
            t[l][c0 + j * 4 + 0] = f2b(v.x);
            t[l][c0 + j * 4 + 1] = f2b(v.y);
            t[l][c0 + j * 4 + 2] = f2b(v.z);
            t[l][c0 + j * 4 + 3] = f2b(v.w);
        }
    }
    __syncthreads();
    {
        int d = tid >> 2, l0 = (tid & 3) * 16;
        ushort tmp[16];
#pragma unroll
        for (int j = 0; j < 16; ++j) tmp[j] = t[l0 + j][d];
        ushort* Op = VT + ((size_t)((b * 16 + hb) * 64) + d) * LL + lb * 64 + l0;
        *(ushort4*)(Op + 0)  = *(ushort4*)&tmp[0];
        *(ushort4*)(Op + 4)  = *(ushort4*)&tmp[4];
        *(ushort4*)(Op + 8)  = *(ushort4*)&tmp[8];
        *(ushort4*)(Op + 12) = *(ushort4*)&tmp[12];
    }
}

// ---------------- fixed-base RoPE for GLU branch ----------------
__global__ void rope_glu_kernel(const float* __restrict__ z, float* __restrict__ zg) {
    int idx = blockIdx.x * 256 + threadIdx.x;
    int row = idx >> 9;
    int i = idx & 511;
    int t = row & (LL - 1);
    float fi = (float)i * (1.0f / 512.0f);
    float ag = (float)t * expf(-fi * LOG_GLU);
    float c = cosf(ag), s = sinf(ag);
    size_t base = (size_t)row * DD;
    float x = z[base + i], y = z[base + 512 + i];
    zg[base + i]       = x * c - y * s;
    zg[base + 512 + i] = y * c + x * s;
}

// ---------------- MFMA flash attention: 64-q tiles, 64-k tiles ----------------
__global__ __launch_bounds__(256) void attn_flash_mfma(
        const ushort* __restrict__ Q16, const ushort* __restrict__ K16,
        const ushort* __restrict__ VT16, const float* __restrict__ gb,
        float* __restrict__ attn_out, float* __restrict__ stats) {
    int h = blockIdx.x, qp = blockIdx.y, b = blockIdx.z;
    __shared__ ushort Qs[4096], Ks[4096], Vs[4096];
    __shared__ ushort Ps[4][16 * 72];
    int tid = threadIdx.x, wid = tid >> 6, lane = tid & 63;
    int quad = lane >> 4, l16 = lane & 15;
    const ushort* Qg = Q16 + ((size_t)(b * 16 + h) * LL) * 64;
    const ushort* Kg = K16 + ((size_t)(b * 16 + h) * LL) * 64;
    const ushort* Vg = VT16 + ((size_t)(b * 16 + h) * 64) * LL;
    const float*  gbB = gb + (size_t)b * LL * LL;
    float* stB = stats + ((size_t)(b * 16 + h) * LL) * 2;
    int qrow = wid * 16 + quad * 4;

    for (int rep = 0; rep < 2; ++rep) {
        int qt = rep ? (31 - qp) : qp;
        int q0 = qt * 64;
        __syncthreads();
        stage_tile(Qg + (size_t)q0 * 64, 64, Qs, tid);
        __syncthreads();
        short8 qf[2];
#pragma unroll
        for (int ks = 0; ks < 2; ++ks)
            qf[ks] = *(const short8*)(Qs + SWZC(wid * 16 + l16, ks * 4 + quad));
        f32x4 ofr[4];
        float m_r[4], l_r[4];
#pragma unroll
        for (int nt = 0; nt < 4; ++nt) ofr[nt] = (f32x4){0.f, 0.f, 0.f, 0.f};
#pragma unroll
        for (int r = 0; r < 4; ++r) { m_r[r] = -3e38f; l_r[r] = 0.f; }

        for (int kt = 0; kt <= qt; ++kt) {
            int k0 = kt * 64;
            float gbv[4][4];
#pragma unroll
            for (int r = 0; r < 4; ++r) {
                const float* gp = gbB + (size_t)(q0 + qrow + r) * LL + k0 + l16;
#pragma unroll
                for (int nt = 0; nt < 4; ++nt) gbv[nt][r] = gp[nt * 16];
            }
            __syncthreads();
            stage_tile(Kg + (size_t)k0 * 64, 64, Ks, tid);
            stage_tile(Vg + k0, LL, Vs, tid);
            __syncthreads();
            f32x4 sf[4];
#pragma unroll
            for (int nt = 0; nt < 4; ++nt) sf[nt] = (f32x4){0.f, 0.f, 0.f, 0.f};
#pragma unroll
            for (int ks = 0; ks < 2; ++ks)
#pragma unroll
                for (int nt = 0; nt < 4; ++nt) {
                    short8 kf = *(const short8*)(Ks + SWZC(nt * 16 + l16, ks * 4 + quad));
                    sf[nt] = __builtin_amdgcn_mfma_f32_16x16x32_bf16(qf[ks], kf, sf[nt], 0, 0, 0);
                }
            float sc[4][4];
            bool diag = (kt == qt);
#pragma unroll
            for (int nt = 0; nt < 4; ++nt)
#pragma unroll
                for (int r = 0; r < 4; ++r) {
                    float v = sf[nt][r] * 0.125f + gbv[nt][r];
                    if (diag && (nt * 16 + l16 > qrow + r)) v = -1e30f;
                    sc[nt][r] = v;
                }
            float alpha[4];
#pragma unroll
            for (int r = 0; r < 4; ++r) {
                float m = fmaxf(fmaxf(sc[0][r], sc[1][r]), fmaxf(sc[2][r], sc[3][r]));
#pragma unroll
                for (int off = 1; off < 16; off <<= 1)
                    m = fmaxf(m, __shfl_xor(m, off));
                float nm = fmaxf(m_r[r], m);
                alpha[r] = expf(m_r[r] - nm);
                m_r[r] = nm;
            }
            float rs[4] = {0.f, 0.f, 0.f, 0.f};
#pragma unroll
            for (int nt = 0; nt < 4; ++nt)
#pragma unroll
                for (int r = 0; r < 4; ++r) {
                    float p = expf(sc[nt][r] - m_r[r]);
                    rs[r] += p;
                    Ps[wid][(quad * 4 + r) * 72 + nt * 16 + l16] = f2b(p);
                }
#pragma unroll
            for (int r = 0; r < 4; ++r) {
#pragma unroll
                for (int off = 1; off < 16; off <<= 1)
                    rs[r] += __shfl_xor(rs[r], off);
                l_r[r] = l_r[r] * alpha[r] + rs[r];
            }
#pragma unroll
            for (int nt = 0; nt < 4; ++nt)
#pragma unroll
                for (int r = 0; r < 4; ++r) ofr[nt][r] *= alpha[r];
            short8 pf[2];
#pragma unroll
            for (int ks = 0; ks < 2; ++ks)
                pf[ks] = *(const short8*)(Ps[wid] + l16 * 72 + ks * 32 + quad * 8);
#pragma unroll
            for (int ks = 0; ks < 2; ++ks)
#pragma unroll
                for (int nt = 0; nt < 4; ++nt) {
                    short8 vf = *(const short8*)(Vs + SWZC(nt * 16 + l16, ks * 4 + quad));
                    ofr[nt] = __builtin_amdgcn_mfma_f32_16x16x32_bf16(pf[ks], vf, ofr[nt], 0, 0, 0);
                }
        }
#pragma unroll
        for (int r = 0; r < 4; ++r) {
            float rinv = 1.0f / l_r[r];
            float* op = attn_out + ((size_t)(b * LL) + q0 + qrow + r) * DD + h * 64 + l16;
#pragma unroll
            for (int nt = 0; nt < 4; ++nt)
                op[nt * 16] = ofr[nt][r] * rinv;
        }
        if (l16 == 0) {
#pragma unroll
            for (int r = 0; r < 4; ++r) {
                size_t si = (size_t)(q0 + qrow + r) * 2;
                stB[si]     = m_r[r];
                stB[si + 1] = l_r[r];
            }
        }
    }
}

// ---------------- attn_w = mean over heads (MFMA recompute from stats) ----------------
__global__ __launch_bounds__(256) void attn_w_mfma(
        const ushort* __restrict__ Q16, const ushort* __restrict__ K16,
        const float* __restrict__ gb, const float* __restrict__ stats,
        float* __restrict__ aw) {
    int qt = blockIdx.x >> 5, kt = blockIdx.x & 31;
    int b = blockIdx.y;
    int tid = threadIdx.x, wid = tid >> 6, lane = tid & 63;
    int quad = lane >> 4, l16 = lane & 15;
    int q0 = qt * 64, k0 = kt * 64;
    int qrow = wid * 16 + quad * 4;
    if (kt > qt) {
        int rr = tid >> 2, c0 = (tid & 3) * 16;
        float4 zv = make_float4(0.f, 0.f, 0.f, 0.f);
        float* p = aw + ((size_t)(b * LL) + q0 + rr) * LL + k0 + c0;
#pragma unroll
        for (int j = 0; j < 4; ++j) *(float4*)(p + j * 4) = zv;
        return;
    }
    __shared__ ushort Qs[4096], Ks[4096];
    __shared__ float sm[64], sli[64];
    float acc[4][4];
#pragma unroll
    for (int nt = 0; nt < 4; ++nt)
#pragma unroll
        for (int r = 0; r < 4; ++r) acc[nt][r] = 0.f;
    float gbv[4][4];
    const float* gbB = gb + (size_t)b * LL * LL;
#pragma unroll
    for (int r = 0; r < 4; ++r) {
        const float* gp = gbB + (size_t)(q0 + qrow + r) * LL + k0 + l16;
#pragma unroll
        for (int nt = 0; nt < 4; ++nt) gbv[nt][r] = gp[nt * 16];
    }
    bool diag = (kt == qt);
    for (int h = 0; h < NHH; ++h) {
        __syncthreads();
        stage_tile(Q16 + ((size_t)(b * 16 + h) * LL + q0) * 64, 64, Qs, tid);
        stage_tile(K16 + ((size_t)(b * 16 + h) * LL + k0) * 64, 64, Ks, tid);
        if (tid < 64) {
            const float* sp = stats + ((size_t)(b * 16 + h) * LL + q0 + tid) * 2;
            sm[tid]  = sp[0];
            sli[tid] = 1.0f / sp[1];
        }
        __syncthreads();
        short8 qf[2];
#pragma unroll
        for (int ks = 0; ks < 2; ++ks)
            qf[ks] = *(const short8*)(Qs + SWZC(wid * 16 + l16, ks * 4 + quad));
        f32x4 sf[4];
#pragma unroll
        for (int nt = 0; nt < 4; ++nt) sf[nt] = (f32x4){0.f, 0.f, 0.f, 0.f};
#pragma unroll
        for (int ks = 0; ks < 2; ++ks)
#pragma unroll
            for (int nt = 0; nt < 4; ++nt) {
                short8 kf = *(const short8*)(Ks + SWZC(nt * 16 + l16, ks * 4 + quad));
                sf[nt] = __builtin_amdgcn_mfma_f32_16x16x32_bf16(qf[ks], kf, sf[nt], 0, 0, 0);
            }
#pragma unroll
        for (int nt = 0; nt < 4; ++nt)
#pragma unroll
            for (int r = 0; r < 4; ++r) {
                int row = qrow + r;
                if (!diag || (nt * 16 + l16 <= row))
                    acc[nt][r] += expf(sf[nt][r] * 0.125f + gbv[nt][r] - sm[row]) * sli[row];
            }
    }
#pragma unroll
    for (int r = 0; r < 4; ++r) {
        float* op = aw + ((size_t)(b * LL) + q0 + qrow + r) * LL + k0 + l16;
#pragma unroll
        for (int nt = 0; nt < 4; ++nt)
            op[nt * 16] = acc[nt][r] * 0.0625f;
    }
}

// ---------------- adv = -nu*U*G, layernorm -> adv_n ----------------
__global__ __launch_bounds__(256) void adv_ln_kernel(
        const float* __restrict__ U, const float* __restrict__ G,
        const float* __restrict__ nub, const float* __restrict__ lnw,
        const float* __restrict__ lnb, float* __restrict__ out) {
    int row = blockIdx.x, tid = threadIdx.x;
    size_t base = (size_t)row * DD + tid * 4;
    float4 u4 = *(const float4*)&U[base];
    float4 g4 = *(const float4*)&G[base];
    float nu = nub[row];
    float a[4];
    a[0] = -nu * u4.x * g4.x;
    a[1] = -nu * u4.y * g4.y;
    a[2] = -nu * u4.z * g4.z;
    a[3] = -nu * u4.w * g4.w;
    float ts = a[0] + a[1] + a[2] + a[3];
    float tq = a[0] * a[0] + a[1] * a[1] + a[2] * a[2] + a[3] * a[3];
    for (int off = 32; off; off >>= 1) {
        ts += __shfl_down(ts, off);
        tq += __shfl_down(tq, off);
    }
    __shared__ float r1[4], r2[4];
    if ((tid & 63) == 0) { r1[tid >> 6] = ts; r2[tid >> 6] = tq; }
    __syncthreads();
    __shared__ float s_mu, s_rs;
    if (tid == 0) {
        float S  = r1[0] + r1[1] + r1[2] + r1[3];
        float Qq = r2[0] + r2[1] + r2[2] + r2[3];
        float mu = S * (1.0f / 1024.f);
        float var = Qq * (1.0f / 1024.f) - mu * mu;
        s_mu = mu;
        s_rs = rsqrtf(var + 1e-5f);
    }
    __syncthreads();
    float mu = s_mu, rs = s_rs;
    float4 w4 = *(const float4*)&lnw[tid * 4];
    float4 b4 = *(const float4*)&lnb[tid * 4];
    float4 ov;
    ov.x = (a[0] - mu) * rs * w4.x + b4.x;
    ov.y = (a[1] - mu) * rs * w4.y + b4.y;
    ov.z = (a[2] - mu) * rs * w4.z + b4.z;
    ov.w = (a[3] - mu) * rs * w4.w + b4.w;
    *(float4*)&out[base] = ov;
}

// ---------------- final residual combine ----------------
__global__ void final_kernel(const float* __restrict__ z, const float* __restrict__ ao,
                             const float* __restrict__ mlp, float* __restrict__ out) {
    size_t i = ((size_t)blockIdx.x * 256 + threadIdx.x) * 4;
    float4 z4 = *(const float4*)&z[i];
    float4 a4 = *(const float4*)&ao[i];
    float4 m4 = *(const float4*)&mlp[i];
    float4 o;
    o.x = z4.x + 0.42f * a4.x + 1.07f * m4.x;
    o.y = z4.y + 0.42f * a4.y + 1.07f * m4.y;
    o.z = z4.z + 0.42f * a4.z + 1.07f * m4.z;
    o.w = z4.w + 0.42f * a4.w + 1.07f * m4.w;
    *(float4*)&out[i] = o;
}

extern "C" void kernel_launch(void* const* d_in, const int* in_sizes, int n_in,
                              void* d_out, int out_size, void* d_ws, size_t ws_size,
                              hipStream_t stream) {
    const float* z       = (const float*)d_in[0];
    const float* Wq      = (const float*)d_in[1];
    const float* bq      = (const float*)d_in[2];
    const float* Wk      = (const float*)d_in[3];
    const float* bk      = (const float*)d_in[4];
    const float* Wv      = (const float*)d_in[5];
    const float* bv      = (const float*)d_in[6];
    const float* Wcoh    = (const float*)d_in[7];
    const float* gamma   = (const float*)d_in[8];
    const float* rg_w1   = (const float*)d_in[9];
    const float* rg_b1   = (const float*)d_in[10];
    const float* rg_w2   = (const float*)d_in[11];
    const float* rg_b2   = (const float*)d_in[12];
    const float* nu_diff = (const float*)d_in[13];
    const float* nu_adv  = (const float*)d_in[14];
    const float* nu_w1   = (const float*)d_in[15];
    const float* nu_b1   = (const float*)d_in[16];
    const float* nu_w2   = (const float*)d_in[17];
    const float* nu_b2   = (const float*)d_in[18];
    const float* Wu      = (const float*)d_in[19];
    const float* bu      = (const float*)d_in[20];
    const float* Wg      = (const float*)d_in[21];
    const float* bg      = (const float*)d_in[22];
    const float* ln_w    = (const float*)d_in[23];
    const float* ln_b    = (const float*)d_in[24];
    const float* Cw      = (const float*)d_in[25];
    const float* Cb      = (const float*)d_in[26];

    float* out_z  = (float*)d_out;
    float* out_aw = out_z + (size_t)MM * DD;

    float* ws = (float*)d_ws;
    const size_t MD = (size_t)MM * DD;   // 4,194,304
    float* pool  = ws;               // later: VT16 (bf16), then z_glu
    float* Qb    = ws + MD;          // later U, later mlp_out
    float* Kb    = ws + 2 * MD;      // later G
    float* Vb    = ws + 3 * MD;      // later Q16/K16 (bf16), then adv_n
    float* gkb   = ws + 4 * MD;      // gk16+K16r (bf16); later attn_out
    float* gbb   = ws + 5 * MD;      // B*L*L = 2*MD (gb); Ab/Wb alias when gb dead
    float* H1    = ws + 7 * MD;      // MM*256
    float* N1    = H1 + (size_t)MM * HG;
    float* gate  = N1 + (size_t)MM * HN;
    float* nub   = gate + MM;
    float* stats = nub + MM;                       // B*NH*L*2
    float* ctot  = stats + (size_t)BB * NHH * LL * 2;  // B*NCH*DD

    // bf16 aliases
    ushort* Ab   = (ushort*)gbb;                 // staging for GEMM A
    ushort* Wb   = (ushort*)(gbb + MD / 2);      // staging for GEMM W^T
    ushort* Q16  = (ushort*)Vb;                  // [b,h,L,64]
    ushort* K16  = (ushort*)Vb + MD;             // [b,h,L,64]
    ushort* VT16 = (ushort*)pool;                // [b,h,64,L]
    ushort* gk16 = (ushort*)gkb;                 // [b*L,1024] bf16
    ushort* K16r = (ushort*)gkb + MD;            // [b*L,1024] bf16 (pre-RoPE K)

    dim3 g128(8, 32);
    dim3 cvt_g(4096);
    dim3 wT_g(32, 32);

    // 1. pool (parallel scan)
    pool_scan1<<<dim3(NCH, 4, BB), 256, 0, stream>>>(z, pool, ctot);
    pool_scan2<<<dim3(NCH, 4, BB), 256, 0, stream>>>(ctot, pool);
    // 2. zb -> Ab; Q,K,V GEMMs
    f2b_kernel<<<cvt_g, 256, 0, stream>>>(z, Ab);
    f2bT_kernel<<<wT_g, 256, 0, stream>>>(Wq, Wb, DD);
    gemm_mfma<<<g128, 256, 0, stream>>>(Ab, Wb, bq, Qb, DD);
    f2bT_kernel<<<wT_g, 256, 0, stream>>>(Wk, Wb, DD);
    gemm_mfma<<<g128, 256, 0, stream>>>(Ab, Wb, bk, Kb, DD);
    f2bT_kernel<<<wT_g, 256, 0, stream>>>(Wv, Wb, DD);
    gemm_mfma<<<g128, 256, 0, stream>>>(Ab, Wb, bv, Vb, DD);
    // 2b. K_raw bf16 copy for gb
    f2b_kernel<<<cvt_g, 256, 0, stream>>>(Kb, K16r);
    // 3. pool GEMMs: gk (bf16 out), H1, N1
    f2b_kernel<<<cvt_g, 256, 0, stream>>>(pool, Ab);
    f2bT_kernel<<<wT_g, 256, 0, stream>>>(Wcoh, Wb, DD);
    gemm_mfma_b16out<<<g128, 256, 0, stream>>>(Ab, Wb, gk16, DD);
    f2bT_kernel<<<dim3(8, 32), 256, 0, stream>>>(rg_w1, Wb, HG);
    gemm_mfma<<<dim3(2, 32), 256, 0, stream>>>(Ab, Wb, rg_b1, H1, HG);
    f2bT_kernel<<<dim3(4, 32), 256, 0, stream>>>(nu_w1, Wb, HN);
    gemm_mfma<<<dim3(1, 32), 256, 0, stream>>>(Ab, Wb, nu_b1, N1, HN);
    // 4. gb (MFMA) — writes gbb (Ab/Wb dead from here until step 11)
    gb_mfma<<<dim3(256, BB), 256, 0, stream>>>(gk16, K16r, gamma, gbb);
    // 5. gate / nu finishers
    gate_fin_kernel<<<dim3(MM), 256, 0, stream>>>(H1, rg_w2, rg_b2, gate);
    nu_fin_kernel<<<dim3(MM), 128, 0, stream>>>(N1, nu_w2, nu_b2, nu_diff, nu_adv, nub);
    // 6. V^T bf16 (reads Vb fp32, writes pool region) — BEFORE rope overwrites Vb
    vt16_kernel<<<dim3(32, 16, BB), 256, 0, stream>>>(Vb, VT16);
    // 7. rope Q,K -> bf16 head-blocked (into Vb region)
    rope_qk_bf16<<<dim3((MM * 512) / 256), 256, 0, stream>>>(Qb, Kb, gate, Q16, K16);
    // 8. MFMA flash attention -> attn_out (gkb; gk16/K16r dead) + stats
    attn_flash_mfma<<<dim3(NHH, 16, BB), 256, 0, stream>>>(Q16, K16, VT16, gbb, gkb, stats);
    // 9. attn_w -> second half of d_out
    attn_w_mfma<<<dim3(1024, BB), 256, 0, stream>>>(Q16, K16, gbb, stats, out_aw);
    // 10. z_glu (reuses pool buffer; VT16 dead)
    rope_glu_kernel<<<dim3((MM * 512) / 256), 256, 0, stream>>>(z, pool);
    // 11. U, G GEMMs (gb dead -> Ab/Wb free)
    f2b_kernel<<<cvt_g, 256, 0, stream>>>(pool, Ab);
    f2bT_kernel<<<wT_g, 256, 0, stream>>>(Wu, Wb, DD);
    gemm_mfma<<<g128, 256, 0, stream>>>(Ab, Wb, bu, Qb, DD);
    f2bT_kernel<<<wT_g, 256, 0, stream>>>(Wg, Wb, DD);
    gemm_mfma<<<g128, 256, 0, stream>>>(Ab, Wb, bg, Kb, DD);
    // 12. adv + layernorm -> Vb (Q16/K16 dead)
    adv_ln_kernel<<<dim3(MM), 256, 0, stream>>>(Qb, Kb, nub, ln_w, ln_b, Vb);
    // 13. mlp_out = adv_n @ Cw + Cb -> Qb
    f2b_kernel<<<cvt_g, 256, 0, stream>>>(Vb, Ab);
    f2bT_kernel<<<wT_g, 256, 0, stream>>>(Cw, Wb, DD);
    gemm_mfma<<<g128, 256, 0, stream>>>(Ab, Wb, Cb, Qb, DD);
    // 14. final combine
    final_kernel<<<dim3(MD / 4 / 256), 256, 0, stream>>>(z, gkb, Qb, out_z);
}

// Round 5
// 718.543 us; speedup vs baseline: 4.8292x; 1.0557x over previous
//
#include <hip/hip_runtime.h>

#define DD 1024
#define NHH 16
#define HDD 64
#define BB 2
#define LL 2048
#define MM (BB*LL)          // 4096 rows
#define HG 256
#define HN 128

#define LOG_FAST 0.48121182f   // ln((1+sqrt(5))/2)
#define LOG_SLOW 7.3889461f    // ln(1618.0)
#define LOG_GLU  9.6915312f    // ln(16180.0)
#define SCL 0.18033688f        // 0.125 * log2(e); scores kept in (QK + 8*gb) raw domain

typedef __attribute__((ext_vector_type(8))) short short8;
typedef __attribute__((ext_vector_type(4))) float f32x4;

__device__ __forceinline__ float gelu_f(float x) {
    return 0.5f * x * (1.0f + erff(x * 0.70710678f));
}

__device__ __forceinline__ ushort f2b(float x) {
    unsigned u = __float_as_uint(x);
    unsigned r = (u + 0x7FFFu + ((u >> 16) & 1u)) >> 16;
    return (ushort)r;
}

__device__ __forceinline__ void gl_lds16(const ushort* g, ushort* l) {
    __builtin_amdgcn_global_load_lds(
        (const __attribute__((address_space(1))) unsigned int*)g,
        (__attribute__((address_space(3))) unsigned int*)l, 16, 0, 0);
}

// ushort offset of swizzled 16B chunk within a 64x64 bf16 tile
#define SWZC(row, c8) (((((row) << 3) | ((c8) ^ ((row) & 7)))) << 3)

// Stage a 64x64 bf16 tile (row-major, rstride in elements) into LDS with XOR swizzle.
__device__ __forceinline__ void stage_tile(const ushort* gsrc, int rstride,
                                           ushort* lds, int tid) {
    int wid = tid >> 6;
#pragma unroll
    for (int r = 0; r < 2; ++r) {
        int c = r * 256 + tid;
        int row = c >> 3;
        int c8 = (c & 7) ^ (row & 7);
        gl_lds16(gsrc + (size_t)row * rstride + c8 * 8,
                 lds + (size_t)(r * 256 + wid * 64) * 8);
    }
}

// ---------------- parallel causal cumulative mean pool ----------------
#define LCH 128
#define NCH 16
__global__ void pool_scan1(const float* __restrict__ z, float* __restrict__ pool,
                           float* __restrict__ ctot) {
    int ch = blockIdx.x, dg = blockIdx.y, b = blockIdx.z;
    int d = dg * 256 + threadIdx.x;
    const float* zp = z + ((size_t)b * LL + ch * LCH) * DD + d;
    float* pp = pool + ((size_t)b * LL + ch * LCH) * DD + d;
    float s = 0.f;
    for (int t = 0; t < LCH; ++t) {
        s += zp[(size_t)t * DD];
        pp[(size_t)t * DD] = s;
    }
    ctot[((size_t)b * NCH + ch) * DD + d] = s;
}
__global__ void pool_scan2(const float* __restrict__ ctot, float* __restrict__ pool) {
    int ch = blockIdx.x, dg = blockIdx.y, b = blockIdx.z;
    int d = dg * 256 + threadIdx.x;
    float off = 0.f;
    for (int c = 0; c < ch; ++c) off += ctot[((size_t)b * NCH + c) * DD + d];
    int t0 = ch * LCH;
    float* pp = pool + ((size_t)b * LL + t0) * DD + d;
    for (int t = 0; t < LCH; ++t) {
        pp[(size_t)t * DD] = (pp[(size_t)t * DD] + off) / (float)(t0 + t + 1);
    }
}

// ---------------- fp32 -> bf16 converters ----------------
__global__ void f2b_kernel(const float* __restrict__ in, ushort* __restrict__ out) {
    size_t i = ((size_t)blockIdx.x * 256 + threadIdx.x) * 4;
    float4 v = *(const float4*)&in[i];
    ushort4 o;
    o.x = f2b(v.x); o.y = f2b(v.y); o.z = f2b(v.z); o.w = f2b(v.w);
    *(ushort4*)&out[i] = o;
}

// W (1024 x Ndim) fp32 -> Wt (Ndim x 1024) bf16
__global__ void f2bT_kernel(const float* __restrict__ W, ushort* __restrict__ Wt, int Ndim) {
    __shared__ float t[32][33];
    int n0 = blockIdx.x * 32, k0 = blockIdx.y * 32;
    int tx = threadIdx.x & 31, ty = threadIdx.x >> 5;   // ty 0..7
#pragma unroll
    for (int j = 0; j < 4; ++j)
        t[ty + j * 8][tx] = W[(size_t)(k0 + ty + j * 8) * Ndim + n0 + tx];
    __syncthreads();
#pragma unroll
    for (int j = 0; j < 4; ++j)
        Wt[(size_t)(n0 + ty + j * 8) * 1024 + k0 + tx] = f2b(t[tx][ty + j * 8]);
}

// ---------------- bf16 MFMA GEMM: C(fp32, M x Ndim) = A(M x 1024 bf16) @ Wt^T + bias
__global__ __launch_bounds__(256) void gemm_mfma(
        const ushort* __restrict__ A, const ushort* __restrict__ Wt,
        const float* __restrict__ bias, float* __restrict__ C, int Ndim) {
    __shared__ ushort As[4096];   // [quad][row 0..127][8]
    __shared__ ushort Bs[4096];
    int tid = threadIdx.x;
    int wid = tid >> 6, lane = tid & 63;
    int n0 = blockIdx.x * 128, m0 = blockIdx.y * 128;
    int wm = wid >> 1, wn = wid & 1;
    int quad = lane >> 4, l16 = lane & 15;

    f32x4 acc[4][4];
#pragma unroll
    for (int mi = 0; mi < 4; ++mi)
#pragma unroll
        for (int ni = 0; ni < 4; ++ni) acc[mi][ni] = (f32x4){0.f, 0.f, 0.f, 0.f};

    int c0 = wid * 128 + lane;
    int c1 = c0 + 64;
    const ushort* Ag0 = A + (size_t)(m0 + (c0 & 127)) * 1024 + (c0 >> 7) * 8;
    const ushort* Ag1 = A + (size_t)(m0 + (c1 & 127)) * 1024 + (c1 >> 7) * 8;
    const ushort* Bg0 = Wt + (size_t)(n0 + (c0 & 127)) * 1024 + (c0 >> 7) * 8;
    const ushort* Bg1 = Wt + (size_t)(n0 + (c1 & 127)) * 1024 + (c1 >> 7) * 8;
    ushort* Al0 = As + wid * 1024;
    ushort* Al1 = As + wid * 1024 + 512;
    ushort* Bl0 = Bs + wid * 1024;
    ushort* Bl1 = Bs + wid * 1024 + 512;

    const ushort* a_rd = &As[(quad * 128 + wm * 64 + l16) * 8];
    const ushort* b_rd = &Bs[(quad * 128 + wn * 64 + l16) * 8];

    for (int kb = 0; kb < 1024; kb += 32) {
        gl_lds16(Ag0 + kb, Al0);
        gl_lds16(Ag1 + kb, Al1);
        gl_lds16(Bg0 + kb, Bl0);
        gl_lds16(Bg1 + kb, Bl1);
        __syncthreads();
        short8 af[4], bf[4];
#pragma unroll
        for (int mi = 0; mi < 4; ++mi)
            af[mi] = *(const short8*)(a_rd + mi * 16 * 8);
#pragma unroll
        for (int ni = 0; ni < 4; ++ni)
            bf[ni] = *(const short8*)(b_rd + ni * 16 * 8);
#pragma unroll
        for (int mi = 0; mi < 4; ++mi)
#pragma unroll
            for (int ni = 0; ni < 4; ++ni)
                acc[mi][ni] = __builtin_amdgcn_mfma_f32_16x16x32_bf16(
                    af[mi], bf[ni], acc[mi][ni], 0, 0, 0);
        __syncthreads();
    }
    int bcol[4];
    float bval[4];
#pragma unroll
    for (int ni = 0; ni < 4; ++ni) {
        bcol[ni] = n0 + wn * 64 + ni * 16 + l16;
        bval[ni] = bias ? bias[bcol[ni]] : 0.f;
    }
#pragma unroll
    for (int mi = 0; mi < 4; ++mi) {
#pragma unroll
        for (int r = 0; r < 4; ++r) {
            int row = m0 + wm * 64 + mi * 16 + quad * 4 + r;
            float* Cp = C + (size_t)row * Ndim;
#pragma unroll
            for (int ni = 0; ni < 4; ++ni)
                Cp[bcol[ni]] = acc[mi][ni][r] + bval[ni];
        }
    }
}

// ---------------- same GEMM but bf16 output, no bias (for gk) ----------------
__global__ __launch_bounds__(256) void gemm_mfma_b16out(
        const ushort* __restrict__ A, const ushort* __restrict__ Wt,
        ushort* __restrict__ C, int Ndim) {
    __shared__ ushort As[4096];
    __shared__ ushort Bs[4096];
    int tid = threadIdx.x;
    int wid = tid >> 6, lane = tid & 63;
    int n0 = blockIdx.x * 128, m0 = blockIdx.y * 128;
    int wm = wid >> 1, wn = wid & 1;
    int quad = lane >> 4, l16 = lane & 15;

    f32x4 acc[4][4];
#pragma unroll
    for (int mi = 0; mi < 4; ++mi)
#pragma unroll
        for (int ni = 0; ni < 4; ++ni) acc[mi][ni] = (f32x4){0.f, 0.f, 0.f, 0.f};

    int c0 = wid * 128 + lane;
    int c1 = c0 + 64;
    const ushort* Ag0 = A + (size_t)(m0 + (c0 & 127)) * 1024 + (c0 >> 7) * 8;
    const ushort* Ag1 = A + (size_t)(m0 + (c1 & 127)) * 1024 + (c1 >> 7) * 8;
    const ushort* Bg0 = Wt + (size_t)(n0 + (c0 & 127)) * 1024 + (c0 >> 7) * 8;
    const ushort* Bg1 = Wt + (size_t)(n0 + (c1 & 127)) * 1024 + (c1 >> 7) * 8;
    ushort* Al0 = As + wid * 1024;
    ushort* Al1 = As + wid * 1024 + 512;
    ushort* Bl0 = Bs + wid * 1024;
    ushort* Bl1 = Bs + wid * 1024 + 512;

    const ushort* a_rd = &As[(quad * 128 + wm * 64 + l16) * 8];
    const ushort* b_rd = &Bs[(quad * 128 + wn * 64 + l16) * 8];

    for (int kb = 0; kb < 1024; kb += 32) {
        gl_lds16(Ag0 + kb, Al0);
        gl_lds16(Ag1 + kb, Al1);
        gl_lds16(Bg0 + kb, Bl0);
        gl_lds16(Bg1 + kb, Bl1);
        __syncthreads();
        short8 af[4], bf[4];
#pragma unroll
        for (int mi = 0; mi < 4; ++mi)
            af[mi] = *(const short8*)(a_rd + mi * 16 * 8);
#pragma unroll
        for (int ni = 0; ni < 4; ++ni)
            bf[ni] = *(const short8*)(b_rd + ni * 16 * 8);
#pragma unroll
        for (int mi = 0; mi < 4; ++mi)
#pragma unroll
            for (int ni = 0; ni < 4; ++ni)
                acc[mi][ni] = __builtin_amdgcn_mfma_f32_16x16x32_bf16(
                    af[mi], bf[ni], acc[mi][ni], 0, 0, 0);
        __syncthreads();
    }
#pragma unroll
    for (int mi = 0; mi < 4; ++mi) {
#pragma unroll
        for (int r = 0; r < 4; ++r) {
            int row = m0 + wm * 64 + mi * 16 + quad * 4 + r;
            ushort* Cp = C + (size_t)row * Ndim;
#pragma unroll
            for (int ni = 0; ni < 4; ++ni)
                Cp[n0 + wn * 64 + ni * 16 + l16] = f2b(acc[mi][ni][r]);
        }
    }
}

// ---------------- gb8 = 8 * tanh(gamma)/32 * gk16 @ K16r^T (causal-lower, MFMA) ----
// NOTE: stores gb*8 so attention can fold gb into the MFMA accumulator:
// score = (QK + gb8) * 0.125.
__global__ __launch_bounds__(256) void gb_mfma(
        const ushort* __restrict__ gk16, const ushort* __restrict__ K16r,
        const float* __restrict__ gamma, float* __restrict__ gb) {
    int lt = blockIdx.x >> 4, mt = blockIdx.x & 15;
    if (mt > lt) return;
    int b = blockIdx.y;
    __shared__ ushort As[4096];
    __shared__ ushort Bs[4096];
    int tid = threadIdx.x;
    int wid = tid >> 6, lane = tid & 63;
    int l0 = lt * 128, m0 = mt * 128;
    int wm = wid >> 1, wn = wid & 1;
    int quad = lane >> 4, l16 = lane & 15;

    f32x4 acc[4][4];
#pragma unroll
    for (int mi = 0; mi < 4; ++mi)
#pragma unroll
        for (int ni = 0; ni < 4; ++ni) acc[mi][ni] = (f32x4){0.f, 0.f, 0.f, 0.f};

    int c0 = wid * 128 + lane;
    int c1 = c0 + 64;
    const ushort* Ag0 = gk16 + ((size_t)b * LL + l0 + (c0 & 127)) * 1024 + (c0 >> 7) * 8;
    const ushort* Ag1 = gk16 + ((size_t)b * LL + l0 + (c1 & 127)) * 1024 + (c1 >> 7) * 8;
    const ushort* Bg0 = K16r + ((size_t)b * LL + m0 + (c0 & 127)) * 1024 + (c0 >> 7) * 8;
    const ushort* Bg1 = K16r + ((size_t)b * LL + m0 + (c1 & 127)) * 1024 + (c1 >> 7) * 8;
    ushort* Al0 = As + wid * 1024;
    ushort* Al1 = As + wid * 1024 + 512;
    ushort* Bl0 = Bs + wid * 1024;
    ushort* Bl1 = Bs + wid * 1024 + 512;

    const ushort* a_rd = &As[(quad * 128 + wm * 64 + l16) * 8];
    const ushort* b_rd = &Bs[(quad * 128 + wn * 64 + l16) * 8];

    for (int kb = 0; kb < 1024; kb += 32) {
        gl_lds16(Ag0 + kb, Al0);
        gl_lds16(Ag1 + kb, Al1);
        gl_lds16(Bg0 + kb, Bl0);
        gl_lds16(Bg1 + kb, Bl1);
        __syncthreads();
        short8 af[4], bf[4];
#pragma unroll
        for (int mi = 0; mi < 4; ++mi)
            af[mi] = *(const short8*)(a_rd + mi * 16 * 8);
#pragma unroll
        for (int ni = 0; ni < 4; ++ni)
            bf[ni] = *(const short8*)(b_rd + ni * 16 * 8);
#pragma unroll
        for (int mi = 0; mi < 4; ++mi)
#pragma unroll
            for (int ni = 0; ni < 4; ++ni)
                acc[mi][ni] = __builtin_amdgcn_mfma_f32_16x16x32_bf16(
                    af[mi], bf[ni], acc[mi][ni], 0, 0, 0);
        __syncthreads();
    }
    float scale = tanhf(gamma[0]) * 0.25f;   // (1/32) * 8
#pragma unroll
    for (int mi = 0; mi < 4; ++mi) {
#pragma unroll
        for (int r = 0; r < 4; ++r) {
            int row = l0 + wm * 64 + mi * 16 + quad * 4 + r;
            float* Cp = gb + ((size_t)b * LL + row) * LL;
#pragma unroll
            for (int ni = 0; ni < 4; ++ni)
                Cp[m0 + wn * 64 + ni * 16 + l16] = acc[mi][ni][r] * scale;
        }
    }
}

// ---------------- gate finisher ----------------
__global__ __launch_bounds__(256) void gate_fin_kernel(
        const float* __restrict__ H1, const float* __restrict__ w2,
        const float* __restrict__ b2, float* __restrict__ gate) {
    int row = blockIdx.x, tid = threadIdx.x;
    float x = H1[(size_t)row * HG + tid];
    float val = gelu_f(x) * w2[tid];
    for (int off = 32; off; off >>= 1) val += __shfl_down(val, off);
    __shared__ float part[4];
    if ((tid & 63) == 0) part[tid >> 6] = val;
    __syncthreads();
    if (tid == 0) {
        float acc = part[0] + part[1] + part[2] + part[3] + b2[0];
        gate[row] = 1.f / (1.f + expf(-acc));
    }
}

// ---------------- nu finisher ----------------
__global__ __launch_bounds__(128) void nu_fin_kernel(
        const float* __restrict__ N1, const float* __restrict__ w2,
        const float* __restrict__ b2, const float* __restrict__ nu_diff,
        const float* __restrict__ nu_adv, float* __restrict__ nub) {
    int row = blockIdx.x, tid = threadIdx.x;
    float t = tanhf(N1[(size_t)row * HN + tid]);
    float val = t * w2[tid];
    for (int off = 32; off; off >>= 1) val += __shfl_down(val, off);
    __shared__ float part[2];
    if ((tid & 63) == 0) part[tid >> 6] = val;
    __syncthreads();
    if (tid == 0) {
        float acc = part[0] + part[1] + b2[0];
        nub[row] = fabsf(nu_diff[0]) + tanhf(acc) * fabsf(nu_adv[0]);
    }
}

// ---------------- gated dual-base RoPE on Q and K -> bf16 head-blocked [b,h,L,64] -------
__global__ void rope_qk_bf16(const float* __restrict__ Q, const float* __restrict__ K,
                             const float* __restrict__ gate,
                             ushort* __restrict__ Q16, ushort* __restrict__ K16) {
    int idx = blockIdx.x * 256 + threadIdx.x;   // over MM*512
    int row = idx >> 9;
    int i = idx & 511;
    int b = row >> 11, t = row & (LL - 1);
    float g = gate[row];
    float fi = (float)i * (1.0f / 512.0f);
    float tf = (float)t;
    float af = tf * expf(-fi * LOG_FAST);
    float as = tf * expf(-fi * LOG_SLOW);
    float c = g * cosf(af) + (1.f - g) * cosf(as);
    float s = g * sinf(af) + (1.f - g) * sinf(as);
    size_t base = (size_t)row * DD;
    float x = Q[base + i], y = Q[base + 512 + i];
    float q1 = x * c - y * s, q2 = y * c + x * s;
    x = K[base + i]; y = K[base + 512 + i];
    float k1 = x * c - y * s, k2 = y * c + x * s;
    int h1 = i >> 6, d1 = i & 63;
    size_t o1 = ((size_t)(b * 16 + h1) * LL + t) * 64 + d1;
    size_t o2 = ((size_t)(b * 16 + 8 + h1) * LL + t) * 64 + d1;
    Q16[o1] = f2b(q1); Q16[o2] = f2b(q2);
    K16[o1] = f2b(k1); K16[o2] = f2b(k2);
}

// ---------------- V fp32 [b*L,1024] -> V^T bf16 [b,h,64,L] ----------------
__global__ __launch_bounds__(256) void vt16_kernel(const float* __restrict__ V,
                                                   ushort* __restrict__ VT) {
    __shared__ ushort t[64][72];
    int lb = blockIdx.x, hb = blockIdx.y, b = blockIdx.z;
    int tid = threadIdx.x;
    {
        int l = tid >> 2, c0 = (tid & 3) * 16;
        const float* Vp = V + ((size_t)(b * LL) + lb * 64 + l) * DD + hb * 64 + c0;
#pragma unroll
        for (int j = 0; j < 4; ++j) {
            float4 v = *(const float4*)(Vp + j * 4);
            t[l][c0 + j * 4 + 0] = f2b(v.x);
            t[l][c0 + j * 4 + 1] = f2b(v.y);
            t[l][c0 + j * 4 + 2] = f2b(v.z);
            t[l][c0 + j * 4 + 3] = f2b(v.w);
        }
    }
    __syncthreads();
    {
        int d = tid >> 2, l0 = (tid & 3) * 16;
        ushort tmp[16];
#pragma unroll
        for (int j = 0; j < 16; ++j) tmp[j] = t[l0 + j][d];
        ushort* Op = VT + ((size_t)((b * 16 + hb) * 64) + d) * LL + lb * 64 + l0;
        *(ushort4*)(Op + 0)  = *(ushort4*)&tmp[0];
        *(ushort4*)(Op + 4)  = *(ushort4*)&tmp[4];
        *(ushort4*)(Op + 8)  = *(ushort4*)&tmp[8];
        *(ushort4*)(Op + 12) = *(ushort4*)&tmp[12];
    }
}

// ---------------- fixed-base RoPE for GLU branch ----------------
__global__ void rope_glu_kernel(const float* __restrict__ z, float* __restrict__ zg) {
    int idx = blockIdx.x * 256 + threadIdx.x;
    int row = idx >> 9;
    int i = idx & 511;
    int t = row & (LL - 1);
    float fi = (float)i * (1.0f / 512.0f);
    float ag = (float)t * expf(-fi * LOG_GLU);
    float c = cosf(ag), s = sinf(ag);
    size_t base = (size_t)row * DD;
    float x = z[base + i], y = z[base + 512 + i];
    zg[base + i]       = x * c - y * s;
    zg[base + 512 + i] = y * c + x * s;
}

// ---------------- MFMA flash attention: grid (h=16, qt=32 LPT-reversed, b=2) ----------
// log2-domain softmax; gb8 folded into QK accumulator; row-sum via ones-column MFMA.
__global__ __launch_bounds__(256, 4) void attn_flash_mfma(
        const ushort* __restrict__ Q16, const ushort* __restrict__ K16,
        const ushort* __restrict__ VT16, const float* __restrict__ gb8,
        float* __restrict__ attn_out, float* __restrict__ stats) {
    int h = blockIdx.x, qt = 31 - blockIdx.y, b = blockIdx.z;
    __shared__ ushort Qs[4096], Ks[4096], Vs[4096];
    __shared__ ushort Ps[4][16 * 72];
    int tid = threadIdx.x, wid = tid >> 6, lane = tid & 63;
    int quad = lane >> 4, l16 = lane & 15;
    const ushort* Qg = Q16 + ((size_t)(b * 16 + h) * LL) * 64;
    const ushort* Kg = K16 + ((size_t)(b * 16 + h) * LL) * 64;
    const ushort* Vg = VT16 + ((size_t)(b * 16 + h) * 64) * LL;
    const float*  gbB = gb8 + (size_t)b * LL * LL;
    float* stB = stats + ((size_t)(b * 16 + h) * LL) * 2;
    int qrow = wid * 16 + quad * 4;
    int q0 = qt * 64;

    stage_tile(Qg + (size_t)q0 * 64, 64, Qs, tid);
    __syncthreads();
    short8 qf[2];
#pragma unroll
    for (int ks = 0; ks < 2; ++ks)
        qf[ks] = *(const short8*)(Qs + SWZC(wid * 16 + l16, ks * 4 + quad));

    // ones B-fragment: 64x16 matrix with ones in column 0 (for P row-sums)
    short ov = (l16 == 0) ? (short)0x3F80 : (short)0;
    short8 onesf = {ov, ov, ov, ov, ov, ov, ov, ov};

    f32x4 ofr[5];   // [0..3]=O cols, [4]=row-sum l (lives in l16==0 lanes)
    float m_r[4];
#pragma unroll
    for (int nt = 0; nt < 5; ++nt) ofr[nt] = (f32x4){0.f, 0.f, 0.f, 0.f};
#pragma unroll
    for (int r = 0; r < 4; ++r) m_r[r] = -3e38f;

    for (int kt = 0; kt <= qt; ++kt) {
        int k0 = kt * 64;
        // accumulator init = gb8 tile (score = (QK + gb8)*0.125)
        f32x4 sf[4];
#pragma unroll
        for (int r = 0; r < 4; ++r) {
            const float* gp = gbB + (size_t)(q0 + qrow + r) * LL + k0 + l16;
#pragma unroll
            for (int nt = 0; nt < 4; ++nt) sf[nt][r] = gp[nt * 16];
        }
        __syncthreads();
        stage_tile(Kg + (size_t)k0 * 64, 64, Ks, tid);
        stage_tile(Vg + k0, LL, Vs, tid);
        __syncthreads();
#pragma unroll
        for (int ks = 0; ks < 2; ++ks)
#pragma unroll
            for (int nt = 0; nt < 4; ++nt) {
                short8 kf = *(const short8*)(Ks + SWZC(nt * 16 + l16, ks * 4 + quad));
                sf[nt] = __builtin_amdgcn_mfma_f32_16x16x32_bf16(qf[ks], kf, sf[nt], 0, 0, 0);
            }
        if (kt == qt) {
#pragma unroll
            for (int nt = 0; nt < 4; ++nt)
#pragma unroll
                for (int r = 0; r < 4; ++r)
                    if (nt * 16 + l16 > qrow + r) sf[nt][r] = -1e30f;
        }
        float alpha[4], mS[4];
#pragma unroll
        for (int r = 0; r < 4; ++r) {
            float m = fmaxf(fmaxf(sf[0][r], sf[1][r]), fmaxf(sf[2][r], sf[3][r]));
#pragma unroll
            for (int off = 1; off < 16; off <<= 1)
                m = fmaxf(m, __shfl_xor(m, off));
            float nm = fmaxf(m_r[r], m);
            alpha[r] = __builtin_amdgcn_exp2f((m_r[r] - nm) * SCL);
            m_r[r] = nm;
            mS[r] = nm * SCL;
        }
#pragma unroll
        for (int nt = 0; nt < 4; ++nt)
#pragma unroll
            for (int r = 0; r < 4; ++r) {
                float p = __builtin_amdgcn_exp2f(fmaf(sf[nt][r], SCL, -mS[r]));
                Ps[wid][(quad * 4 + r) * 72 + nt * 16 + l16] = f2b(p);
            }
#pragma unroll
        for (int nt = 0; nt < 5; ++nt)
#pragma unroll
            for (int r = 0; r < 4; ++r) ofr[nt][r] *= alpha[r];
        short8 pf[2];
#pragma unroll
        for (int ks = 0; ks < 2; ++ks)
            pf[ks] = *(const short8*)(Ps[wid] + l16 * 72 + ks * 32 + quad * 8);
#pragma unroll
        for (int ks = 0; ks < 2; ++ks) {
#pragma unroll
            for (int nt = 0; nt < 4; ++nt) {
                short8 vf = *(const short8*)(Vs + SWZC(nt * 16 + l16, ks * 4 + quad));
                ofr[nt] = __builtin_amdgcn_mfma_f32_16x16x32_bf16(pf[ks], vf, ofr[nt], 0, 0, 0);
            }
            ofr[4] = __builtin_amdgcn_mfma_f32_16x16x32_bf16(pf[ks], onesf, ofr[4], 0, 0, 0);
        }
    }
#pragma unroll
    for (int r = 0; r < 4; ++r) {
        float l = __shfl(ofr[4][r], (lane & 48));   // broadcast from l16==0 of this quad
        float rinv = 1.0f / l;
        float* op = attn_out + ((size_t)(b * LL) + q0 + qrow + r) * DD + h * 64 + l16;
#pragma unroll
        for (int nt = 0; nt < 4; ++nt)
            op[nt * 16] = ofr[nt][r] * rinv;
    }
    if (l16 == 0) {
#pragma unroll
        for (int r = 0; r < 4; ++r) {
            size_t si = (size_t)(q0 + qrow + r) * 2;
            stB[si]     = m_r[r];        // raw (QK+gb8) domain max
            stB[si + 1] = ofr[4][r];     // linear-domain sum
        }
    }
}

// ---------------- attn_w = mean over heads (MFMA recompute from stats) ----------------
__global__ __launch_bounds__(256) void attn_w_mfma(
        const ushort* __restrict__ Q16, const ushort* __restrict__ K16,
        const float* __restrict__ gb8, const float* __restrict__ stats,
        float* __restrict__ aw) {
    int qt = blockIdx.x >> 5, kt = blockIdx.x & 31;
    int b = blockIdx.y;
    int tid = threadIdx.x, wid = tid >> 6, lane = tid & 63;
    int quad = lane >> 4, l16 = lane & 15;
    int q0 = qt * 64, k0 = kt * 64;
    int qrow = wid * 16 + quad * 4;
    if (kt > qt) {
        int rr = tid >> 2, c0 = (tid & 3) * 16;
        float4 zv = make_float4(0.f, 0.f, 0.f, 0.f);
        float* p = aw + ((size_t)(b * LL) + q0 + rr) * LL + k0 + c0;
#pragma unroll
        for (int j = 0; j < 4; ++j) *(float4*)(p + j * 4) = zv;
        return;
    }
    __shared__ ushort Qs[4096], Ks[4096];
    __shared__ float smS[64], sli[64];
    float acc[4][4];
#pragma unroll
    for (int nt = 0; nt < 4; ++nt)
#pragma unroll
        for (int r = 0; r < 4; ++r) acc[nt][r] = 0.f;
    // gb8 tile, reused as accumulator init for every head
    f32x4 gacc[4];
    const float* gbB = gb8 + (size_t)b * LL * LL;
#pragma unroll
    for (int r = 0; r < 4; ++r) {
        const float* gp = gbB + (size_t)(q0 + qrow + r) * LL + k0 + l16;
#pragma unroll
        for (int nt = 0; nt < 4; ++nt) gacc[nt][r] = gp[nt * 16];
    }
    bool diag = (kt == qt);
    for (int h = 0; h < NHH; ++h) {
        __syncthreads();
        stage_tile(Q16 + ((size_t)(b * 16 + h) * LL + q0) * 64, 64, Qs, tid);
        stage_tile(K16 + ((size_t)(b * 16 + h) * LL + k0) * 64, 64, Ks, tid);
        if (tid < 64) {
            const float* sp = stats + ((size_t)(b * 16 + h) * LL + q0 + tid) * 2;
            smS[tid] = sp[0] * SCL;
            sli[tid] = 1.0f / sp[1];
        }
        __syncthreads();
        short8 qf[2];
#pragma unroll
        for (int ks = 0; ks < 2; ++ks)
            qf[ks] = *(const short8*)(Qs + SWZC(wid * 16 + l16, ks * 4 + quad));
        f32x4 sf[4];
#pragma unroll
        for (int nt = 0; nt < 4; ++nt) sf[nt] = gacc[nt];
#pragma unroll
        for (int ks = 0; ks < 2; ++ks)
#pragma unroll
            for (int nt = 0; nt < 4; ++nt) {
                short8 kf = *(const short8*)(Ks + SWZC(nt * 16 + l16, ks * 4 + quad));
                sf[nt] = __builtin_amdgcn_mfma_f32_16x16x32_bf16(qf[ks], kf, sf[nt], 0, 0, 0);
            }
#pragma unroll
        for (int nt = 0; nt < 4; ++nt)
#pragma unroll
            for (int r = 0; r < 4; ++r) {
                int row = qrow + r;
                if (!diag || (nt * 16 + l16 <= row))
                    acc[nt][r] += __builtin_amdgcn_exp2f(fmaf(sf[nt][r], SCL, -smS[row])) * sli[row];
            }
    }
#pragma unroll
    for (int r = 0; r < 4; ++r) {
        float* op = aw + ((size_t)(b * LL) + q0 + qrow + r) * LL + k0 + l16;
#pragma unroll
        for (int nt = 0; nt < 4; ++nt)
            op[nt * 16] = acc[nt][r] * 0.0625f;
    }
}

// ---------------- adv = -nu*U*G, layernorm -> adv_n ----------------
__global__ __launch_bounds__(256) void adv_ln_kernel(
        const float* __restrict__ U, const float* __restrict__ G,
        const float* __restrict__ nub, const float* __restrict__ lnw,
        const float* __restrict__ lnb, float* __restrict__ out) {
    int row = blockIdx.x, tid = threadIdx.x;
    size_t base = (size_t)row * DD + tid * 4;
    float4 u4 = *(const float4*)&U[base];
    float4 g4 = *(const float4*)&G[base];
    float nu = nub[row];
    float a[4];
    a[0] = -nu * u4.x * g4.x;
    a[1] = -nu * u4.y * g4.y;
    a[2] = -nu * u4.z * g4.z;
    a[3] = -nu * u4.w * g4.w;
    float ts = a[0] + a[1] + a[2] + a[3];
    float tq = a[0] * a[0] + a[1] * a[1] + a[2] * a[2] + a[3] * a[3];
    for (int off = 32; off; off >>= 1) {
        ts += __shfl_down(ts, off);
        tq += __shfl_down(tq, off);
    }
    __shared__ float r1[4], r2[4];
    if ((tid & 63) == 0) { r1[tid >> 6] = ts; r2[tid >> 6] = tq; }
    __syncthreads();
    __shared__ float s_mu, s_rs;
    if (tid == 0) {
        float S  = r1[0] + r1[1] + r1[2] + r1[3];
        float Qq = r2[0] + r2[1] + r2[2] + r2[3];
        float mu = S * (1.0f / 1024.f);
        float var = Qq * (1.0f / 1024.f) - mu * mu;
        s_mu = mu;
        s_rs = rsqrtf(var + 1e-5f);
    }
    __syncthreads();
    float mu = s_mu, rs = s_rs;
    float4 w4 = *(const float4*)&lnw[tid * 4];
    float4 b4 = *(const float4*)&lnb[tid * 4];
    float4 ov;
    ov.x = (a[0] - mu) * rs * w4.x + b4.x;
    ov.y = (a[1] - mu) * rs * w4.y + b4.y;
    ov.z = (a[2] - mu) * rs * w4.z + b4.z;
    ov.w = (a[3] - mu) * rs * w4.w + b4.w;
    *(float4*)&out[base] = ov;
}

// ---------------- final residual combine ----------------
__global__ void final_kernel(const float* __restrict__ z, const float* __restrict__ ao,
                             const float* __restrict__ mlp, float* __restrict__ out) {
    size_t i = ((size_t)blockIdx.x * 256 + threadIdx.x) * 4;
    float4 z4 = *(const float4*)&z[i];
    float4 a4 = *(const float4*)&ao[i];
    float4 m4 = *(const float4*)&mlp[i];
    float4 o;
    o.x = z4.x + 0.42f * a4.x + 1.07f * m4.x;
    o.y = z4.y + 0.42f * a4.y + 1.07f * m4.y;
    o.z = z4.z + 0.42f * a4.z + 1.07f * m4.z;
    o.w = z4.w + 0.42f * a4.w + 1.07f * m4.w;
    *(float4*)&out[i] = o;
}

extern "C" void kernel_launch(void* const* d_in, const int* in_sizes, int n_in,
                              void* d_out, int out_size, void* d_ws, size_t ws_size,
                              hipStream_t stream) {
    const float* z       = (const float*)d_in[0];
    const float* Wq      = (const float*)d_in[1];
    const float* bq      = (const float*)d_in[2];
    const float* Wk      = (const float*)d_in[3];
    const float* bk      = (const float*)d_in[4];
    const float* Wv      = (const float*)d_in[5];
    const float* bv      = (const float*)d_in[6];
    const float* Wcoh    = (const float*)d_in[7];
    const float* gamma   = (const float*)d_in[8];
    const float* rg_w1   = (const float*)d_in[9];
    const float* rg_b1   = (const float*)d_in[10];
    const float* rg_w2   = (const float*)d_in[11];
    const float* rg_b2   = (const float*)d_in[12];
    const float* nu_diff = (const float*)d_in[13];
    const float* nu_adv  = (const float*)d_in[14];
    const float* nu_w1   = (const float*)d_in[15];
    const float* nu_b1   = (const float*)d_in[16];
    const float* nu_w2   = (const float*)d_in[17];
    const float* nu_b2   = (const float*)d_in[18];
    const float* Wu      = (const float*)d_in[19];
    const float* bu      = (const float*)d_in[20];
    const float* Wg      = (const float*)d_in[21];
    const float* bg      = (const float*)d_in[22];
    const float* ln_w    = (const float*)d_in[23];
    const float* ln_b    = (const float*)d_in[24];
    const float* Cw      = (const float*)d_in[25];
    const float* Cb      = (const float*)d_in[26];

    float* out_z  = (float*)d_out;
    float* out_aw = out_z + (size_t)MM * DD;

    float* ws = (float*)d_ws;
    const size_t MD = (size_t)MM * DD;   // 4,194,304
    float* pool  = ws;               // later: VT16 (bf16), then z_glu
    float* Qb    = ws + MD;          // later U, later mlp_out
    float* Kb    = ws + 2 * MD;      // later G
    float* Vb    = ws + 3 * MD;      // later Q16/K16 (bf16), then adv_n
    float* gkb   = ws + 4 * MD;      // gk16+K16r (bf16); later attn_out
    float* gbb   = ws + 5 * MD;      // B*L*L = 2*MD (gb8); Ab/Wb alias when gb dead
    float* H1    = ws + 7 * MD;      // MM*256
    float* N1    = H1 + (size_t)MM * HG;
    float* gate  = N1 + (size_t)MM * HN;
    float* nub   = gate + MM;
    float* stats = nub + MM;                       // B*NH*L*2
    float* ctot  = stats + (size_t)BB * NHH * LL * 2;  // B*NCH*DD

    // bf16 aliases
    ushort* Ab   = (ushort*)gbb;                 // staging for GEMM A
    ushort* Wb   = (ushort*)(gbb + MD / 2);      // staging for GEMM W^T
    ushort* Q16  = (ushort*)Vb;                  // [b,h,L,64]
    ushort* K16  = (ushort*)Vb + MD;             // [b,h,L,64]
    ushort* VT16 = (ushort*)pool;                // [b,h,64,L]
    ushort* gk16 = (ushort*)gkb;                 // [b*L,1024] bf16
    ushort* K16r = (ushort*)gkb + MD;            // [b*L,1024] bf16 (pre-RoPE K)

    dim3 g128(8, 32);
    dim3 cvt_g(4096);
    dim3 wT_g(32, 32);

    // 1. pool (parallel scan)
    pool_scan1<<<dim3(NCH, 4, BB), 256, 0, stream>>>(z, pool, ctot);
    pool_scan2<<<dim3(NCH, 4, BB), 256, 0, stream>>>(ctot, pool);
    // 2. zb -> Ab; Q,K,V GEMMs
    f2b_kernel<<<cvt_g, 256, 0, stream>>>(z, Ab);
    f2bT_kernel<<<wT_g, 256, 0, stream>>>(Wq, Wb, DD);
    gemm_mfma<<<g128, 256, 0, stream>>>(Ab, Wb, bq, Qb, DD);
    f2bT_kernel<<<wT_g, 256, 0, stream>>>(Wk, Wb, DD);
    gemm_mfma<<<g128, 256, 0, stream>>>(Ab, Wb, bk, Kb, DD);
    f2bT_kernel<<<wT_g, 256, 0, stream>>>(Wv, Wb, DD);
    gemm_mfma<<<g128, 256, 0, stream>>>(Ab, Wb, bv, Vb, DD);
    // 2b. K_raw bf16 copy for gb
    f2b_kernel<<<cvt_g, 256, 0, stream>>>(Kb, K16r);
    // 3. pool GEMMs: gk (bf16 out), H1, N1
    f2b_kernel<<<cvt_g, 256, 0, stream>>>(pool, Ab);
    f2bT_kernel<<<wT_g, 256, 0, stream>>>(Wcoh, Wb, DD);
    gemm_mfma_b16out<<<g128, 256, 0, stream>>>(Ab, Wb, gk16, DD);
    f2bT_kernel<<<dim3(8, 32), 256, 0, stream>>>(rg_w1, Wb, HG);
    gemm_mfma<<<dim3(2, 32), 256, 0, stream>>>(Ab, Wb, rg_b1, H1, HG);
    f2bT_kernel<<<dim3(4, 32), 256, 0, stream>>>(nu_w1, Wb, HN);
    gemm_mfma<<<dim3(1, 32), 256, 0, stream>>>(Ab, Wb, nu_b1, N1, HN);
    // 4. gb8 (MFMA) — writes gbb (Ab/Wb dead from here until step 11)
    gb_mfma<<<dim3(256, BB), 256, 0, stream>>>(gk16, K16r, gamma, gbb);
    // 5. gate / nu finishers
    gate_fin_kernel<<<dim3(MM), 256, 0, stream>>>(H1, rg_w2, rg_b2, gate);
    nu_fin_kernel<<<dim3(MM), 128, 0, stream>>>(N1, nu_w2, nu_b2, nu_diff, nu_adv, nub);
    // 6. V^T bf16 (reads Vb fp32, writes pool region) — BEFORE rope overwrites Vb
    vt16_kernel<<<dim3(32, 16, BB), 256, 0, stream>>>(Vb, VT16);
    // 7. rope Q,K -> bf16 head-blocked (into Vb region)
    rope_qk_bf16<<<dim3((MM * 512) / 256), 256, 0, stream>>>(Qb, Kb, gate, Q16, K16);
    // 8. MFMA flash attention -> attn_out (gkb; gk16/K16r dead) + stats
    attn_flash_mfma<<<dim3(NHH, 32, BB), 256, 0, stream>>>(Q16, K16, VT16, gbb, gkb, stats);
    // 9. attn_w -> second half of d_out
    attn_w_mfma<<<dim3(1024, BB), 256, 0, stream>>>(Q16, K16, gbb, stats, out_aw);
    // 10. z_glu (reuses pool buffer; VT16 dead)
    rope_glu_kernel<<<dim3((MM * 512) / 256), 256, 0, stream>>>(z, pool);
    // 11. U, G GEMMs (gb dead -> Ab/Wb free)
    f2b_kernel<<<cvt_g, 256, 0, stream>>>(pool, Ab);
    f2bT_kernel<<<wT_g, 256, 0, stream>>>(Wu, Wb, DD);
    gemm_mfma<<<g128, 256, 0, stream>>>(Ab, Wb, bu, Qb, DD);
    f2bT_kernel<<<wT_g, 256, 0, stream>>>(Wg, Wb, DD);
    gemm_mfma<<<g128, 256, 0, stream>>>(Ab, Wb, bg, Kb, DD);
    // 12. adv + layernorm -> Vb (Q16/K16 dead)
    adv_ln_kernel<<<dim3(MM), 256, 0, stream>>>(Qb, Kb, nub, ln_w, ln_b, Vb);
    // 13. mlp_out = adv_n @ Cw + Cb -> Qb
    f2b_kernel<<<cvt_g, 256, 0, stream>>>(Vb, Ab);
    f2bT_kernel<<<wT_g, 256, 0, stream>>>(Cw, Wb, DD);
    gemm_mfma<<<g128, 256, 0, stream>>>(Ab, Wb, Cb, Qb, DD);
    // 14. final combine
    final_kernel<<<dim3(MD / 4 / 256), 256, 0, stream>>>(z, gkb, Qb, out_z);
}

// Round 6
// 626.547 us; speedup vs baseline: 5.5382x; 1.1468x over previous
//
#include <hip/hip_runtime.h>

#define DD 1024
#define NHH 16
#define HDD 64
#define BB 2
#define LL 2048
#define MM (BB*LL)          // 4096 rows
#define HG 256
#define HN 128

#define LOG_FAST 0.48121182f   // ln((1+sqrt(5))/2)
#define LOG_SLOW 7.3889461f    // ln(1618.0)
#define LOG_GLU  9.6915312f    // ln(16180.0)
#define SCL 0.18033688f        // 0.125 * log2(e); scores kept in (QK + 8*gb) raw domain

typedef __attribute__((ext_vector_type(8))) short short8;
typedef __attribute__((ext_vector_type(4))) float f32x4;

__device__ __forceinline__ float gelu_f(float x) {
    return 0.5f * x * (1.0f + erff(x * 0.70710678f));
}

__device__ __forceinline__ ushort f2b(float x) {
    unsigned u = __float_as_uint(x);
    unsigned r = (u + 0x7FFFu + ((u >> 16) & 1u)) >> 16;
    return (ushort)r;
}

__device__ __forceinline__ float b2f(ushort x) {
    return __uint_as_float(((unsigned)x) << 16);
}

__device__ __forceinline__ void gl_lds16(const ushort* g, ushort* l) {
    __builtin_amdgcn_global_load_lds(
        (const __attribute__((address_space(1))) unsigned int*)g,
        (__attribute__((address_space(3))) unsigned int*)l, 16, 0, 0);
}

// ushort offset of swizzled 16B chunk within a 64x64 bf16 tile
#define SWZC(row, c8) (((((row) << 3) | ((c8) ^ ((row) & 7)))) << 3)

// Stage a 64x64 bf16 tile (row-major, rstride in elements) into LDS with XOR swizzle.
__device__ __forceinline__ void stage_tile(const ushort* gsrc, int rstride,
                                           ushort* lds, int tid) {
    int wid = tid >> 6;
#pragma unroll
    for (int r = 0; r < 2; ++r) {
        int c = r * 256 + tid;
        int row = c >> 3;
        int c8 = (c & 7) ^ (row & 7);
        gl_lds16(gsrc + (size_t)row * rstride + c8 * 8,
                 lds + (size_t)(r * 256 + wid * 64) * 8);
    }
}

// ---------------- parallel causal cumulative mean pool ----------------
#define LCH 128
#define NCH 16
__global__ void pool_scan1(const float* __restrict__ z, float* __restrict__ pool,
                           float* __restrict__ ctot) {
    int ch = blockIdx.x, dg = blockIdx.y, b = blockIdx.z;
    int d = dg * 256 + threadIdx.x;
    const float* zp = z + ((size_t)b * LL + ch * LCH) * DD + d;
    float* pp = pool + ((size_t)b * LL + ch * LCH) * DD + d;
    float s = 0.f;
    for (int t = 0; t < LCH; ++t) {
        s += zp[(size_t)t * DD];
        pp[(size_t)t * DD] = s;
    }
    ctot[((size_t)b * NCH + ch) * DD + d] = s;
}
__global__ void pool_scan2(const float* __restrict__ ctot, float* __restrict__ pool) {
    int ch = blockIdx.x, dg = blockIdx.y, b = blockIdx.z;
    int d = dg * 256 + threadIdx.x;
    float off = 0.f;
    for (int c = 0; c < ch; ++c) off += ctot[((size_t)b * NCH + c) * DD + d];
    int t0 = ch * LCH;
    float* pp = pool + ((size_t)b * LL + t0) * DD + d;
    for (int t = 0; t < LCH; ++t) {
        pp[(size_t)t * DD] = (pp[(size_t)t * DD] + off) / (float)(t0 + t + 1);
    }
}

// ---------------- fp32 -> bf16 converters ----------------
__global__ void f2b_kernel(const float* __restrict__ in, ushort* __restrict__ out) {
    size_t i = ((size_t)blockIdx.x * 256 + threadIdx.x) * 4;
    float4 v = *(const float4*)&in[i];
    ushort4 o;
    o.x = f2b(v.x); o.y = f2b(v.y); o.z = f2b(v.z); o.w = f2b(v.w);
    *(ushort4*)&out[i] = o;
}

// W (1024 x Ndim) fp32 -> Wt (Ndim x 1024) bf16
__global__ void f2bT_kernel(const float* __restrict__ W, ushort* __restrict__ Wt, int Ndim) {
    __shared__ float t[32][33];
    int n0 = blockIdx.x * 32, k0 = blockIdx.y * 32;
    int tx = threadIdx.x & 31, ty = threadIdx.x >> 5;   // ty 0..7
#pragma unroll
    for (int j = 0; j < 4; ++j)
        t[ty + j * 8][tx] = W[(size_t)(k0 + ty + j * 8) * Ndim + n0 + tx];
    __syncthreads();
#pragma unroll
    for (int j = 0; j < 4; ++j)
        Wt[(size_t)(n0 + ty + j * 8) * 1024 + k0 + tx] = f2b(t[tx][ty + j * 8]);
}

// three square 1024x1024 weights -> transposed bf16 slots (z selects)
__global__ void f2bT3_kernel(const float* __restrict__ W0, const float* __restrict__ W1,
                             const float* __restrict__ W2, ushort* __restrict__ Wt) {
    const float* W = blockIdx.z == 0 ? W0 : (blockIdx.z == 1 ? W1 : W2);
    ushort* dst = Wt + (size_t)blockIdx.z * 1024 * 1024;
    __shared__ float t[32][33];
    int n0 = blockIdx.x * 32, k0 = blockIdx.y * 32;
    int tx = threadIdx.x & 31, ty = threadIdx.x >> 5;
#pragma unroll
    for (int j = 0; j < 4; ++j)
        t[ty + j * 8][tx] = W[(size_t)(k0 + ty + j * 8) * 1024 + n0 + tx];
    __syncthreads();
#pragma unroll
    for (int j = 0; j < 4; ++j)
        dst[(size_t)(n0 + ty + j * 8) * 1024 + k0 + tx] = f2b(t[tx][ty + j * 8]);
}

// ---------------- bf16 MFMA GEMM: C(fp32, M x Ndim) = A(M x 1024 bf16) @ Wt^T + bias
__global__ __launch_bounds__(256) void gemm_mfma(
        const ushort* __restrict__ A, const ushort* __restrict__ Wt,
        const float* __restrict__ bias, float* __restrict__ C, int Ndim) {
    __shared__ ushort As[4096];   // [quad][row 0..127][8]
    __shared__ ushort Bs[4096];
    int tid = threadIdx.x;
    int wid = tid >> 6, lane = tid & 63;
    int n0 = blockIdx.x * 128, m0 = blockIdx.y * 128;
    int wm = wid >> 1, wn = wid & 1;
    int quad = lane >> 4, l16 = lane & 15;

    f32x4 acc[4][4];
#pragma unroll
    for (int mi = 0; mi < 4; ++mi)
#pragma unroll
        for (int ni = 0; ni < 4; ++ni) acc[mi][ni] = (f32x4){0.f, 0.f, 0.f, 0.f};

    int c0 = wid * 128 + lane;
    int c1 = c0 + 64;
    const ushort* Ag0 = A + (size_t)(m0 + (c0 & 127)) * 1024 + (c0 >> 7) * 8;
    const ushort* Ag1 = A + (size_t)(m0 + (c1 & 127)) * 1024 + (c1 >> 7) * 8;
    const ushort* Bg0 = Wt + (size_t)(n0 + (c0 & 127)) * 1024 + (c0 >> 7) * 8;
    const ushort* Bg1 = Wt + (size_t)(n0 + (c1 & 127)) * 1024 + (c1 >> 7) * 8;
    ushort* Al0 = As + wid * 1024;
    ushort* Al1 = As + wid * 1024 + 512;
    ushort* Bl0 = Bs + wid * 1024;
    ushort* Bl1 = Bs + wid * 1024 + 512;

    const ushort* a_rd = &As[(quad * 128 + wm * 64 + l16) * 8];
    const ushort* b_rd = &Bs[(quad * 128 + wn * 64 + l16) * 8];

    for (int kb = 0; kb < 1024; kb += 32) {
        gl_lds16(Ag0 + kb, Al0);
        gl_lds16(Ag1 + kb, Al1);
        gl_lds16(Bg0 + kb, Bl0);
        gl_lds16(Bg1 + kb, Bl1);
        __syncthreads();
        short8 af[4], bf[4];
#pragma unroll
        for (int mi = 0; mi < 4; ++mi)
            af[mi] = *(const short8*)(a_rd + mi * 16 * 8);
#pragma unroll
        for (int ni = 0; ni < 4; ++ni)
            bf[ni] = *(const short8*)(b_rd + ni * 16 * 8);
#pragma unroll
        for (int mi = 0; mi < 4; ++mi)
#pragma unroll
            for (int ni = 0; ni < 4; ++ni)
                acc[mi][ni] = __builtin_amdgcn_mfma_f32_16x16x32_bf16(
                    af[mi], bf[ni], acc[mi][ni], 0, 0, 0);
        __syncthreads();
    }
    int bcol[4];
    float bval[4];
#pragma unroll
    for (int ni = 0; ni < 4; ++ni) {
        bcol[ni] = n0 + wn * 64 + ni * 16 + l16;
        bval[ni] = bias ? bias[bcol[ni]] : 0.f;
    }
#pragma unroll
    for (int mi = 0; mi < 4; ++mi) {
#pragma unroll
        for (int r = 0; r < 4; ++r) {
            int row = m0 + wm * 64 + mi * 16 + quad * 4 + r;
            float* Cp = C + (size_t)row * Ndim;
#pragma unroll
            for (int ni = 0; ni < 4; ++ni)
                Cp[bcol[ni]] = acc[mi][ni][r] + bval[ni];
        }
    }
}

// ---------------- fused multi-weight GEMM (Ndim=1024): z selects weight slot / bias / C
__global__ __launch_bounds__(256) void gemm_mfma3(
        const ushort* __restrict__ A, const ushort* __restrict__ Wt,
        const float* __restrict__ b0, const float* __restrict__ b1,
        const float* __restrict__ b2, float* __restrict__ C) {
    int zid = blockIdx.z;
    const ushort* W = Wt + (size_t)zid * 1024 * 1024;
    const float* bias = zid == 0 ? b0 : (zid == 1 ? b1 : b2);
    float* Cz = C + (size_t)zid * (size_t)MM * DD;
    __shared__ ushort As[4096];
    __shared__ ushort Bs[4096];
    int tid = threadIdx.x;
    int wid = tid >> 6, lane = tid & 63;
    int n0 = blockIdx.x * 128, m0 = blockIdx.y * 128;
    int wm = wid >> 1, wn = wid & 1;
    int quad = lane >> 4, l16 = lane & 15;

    f32x4 acc[4][4];
#pragma unroll
    for (int mi = 0; mi < 4; ++mi)
#pragma unroll
        for (int ni = 0; ni < 4; ++ni) acc[mi][ni] = (f32x4){0.f, 0.f, 0.f, 0.f};

    int c0 = wid * 128 + lane;
    int c1 = c0 + 64;
    const ushort* Ag0 = A + (size_t)(m0 + (c0 & 127)) * 1024 + (c0 >> 7) * 8;
    const ushort* Ag1 = A + (size_t)(m0 + (c1 & 127)) * 1024 + (c1 >> 7) * 8;
    const ushort* Bg0 = W + (size_t)(n0 + (c0 & 127)) * 1024 + (c0 >> 7) * 8;
    const ushort* Bg1 = W + (size_t)(n0 + (c1 & 127)) * 1024 + (c1 >> 7) * 8;
    ushort* Al0 = As + wid * 1024;
    ushort* Al1 = As + wid * 1024 + 512;
    ushort* Bl0 = Bs + wid * 1024;
    ushort* Bl1 = Bs + wid * 1024 + 512;

    const ushort* a_rd = &As[(quad * 128 + wm * 64 + l16) * 8];
    const ushort* b_rd = &Bs[(quad * 128 + wn * 64 + l16) * 8];

    for (int kb = 0; kb < 1024; kb += 32) {
        gl_lds16(Ag0 + kb, Al0);
        gl_lds16(Ag1 + kb, Al1);
        gl_lds16(Bg0 + kb, Bl0);
        gl_lds16(Bg1 + kb, Bl1);
        __syncthreads();
        short8 af[4], bf[4];
#pragma unroll
        for (int mi = 0; mi < 4; ++mi)
            af[mi] = *(const short8*)(a_rd + mi * 16 * 8);
#pragma unroll
        for (int ni = 0; ni < 4; ++ni)
            bf[ni] = *(const short8*)(b_rd + ni * 16 * 8);
#pragma unroll
        for (int mi = 0; mi < 4; ++mi)
#pragma unroll
            for (int ni = 0; ni < 4; ++ni)
                acc[mi][ni] = __builtin_amdgcn_mfma_f32_16x16x32_bf16(
                    af[mi], bf[ni], acc[mi][ni], 0, 0, 0);
        __syncthreads();
    }
    float bval[4];
    int bcol[4];
#pragma unroll
    for (int ni = 0; ni < 4; ++ni) {
        bcol[ni] = n0 + wn * 64 + ni * 16 + l16;
        bval[ni] = bias[bcol[ni]];
    }
#pragma unroll
    for (int mi = 0; mi < 4; ++mi) {
#pragma unroll
        for (int r = 0; r < 4; ++r) {
            int row = m0 + wm * 64 + mi * 16 + quad * 4 + r;
            float* Cp = Cz + (size_t)row * 1024;
#pragma unroll
            for (int ni = 0; ni < 4; ++ni)
                Cp[bcol[ni]] = acc[mi][ni][r] + bval[ni];
        }
    }
}

// ---------------- same GEMM but bf16 output, no bias (for gk) ----------------
__global__ __launch_bounds__(256) void gemm_mfma_b16out(
        const ushort* __restrict__ A, const ushort* __restrict__ Wt,
        ushort* __restrict__ C, int Ndim) {
    __shared__ ushort As[4096];
    __shared__ ushort Bs[4096];
    int tid = threadIdx.x;
    int wid = tid >> 6, lane = tid & 63;
    int n0 = blockIdx.x * 128, m0 = blockIdx.y * 128;
    int wm = wid >> 1, wn = wid & 1;
    int quad = lane >> 4, l16 = lane & 15;

    f32x4 acc[4][4];
#pragma unroll
    for (int mi = 0; mi < 4; ++mi)
#pragma unroll
        for (int ni = 0; ni < 4; ++ni) acc[mi][ni] = (f32x4){0.f, 0.f, 0.f, 0.f};

    int c0 = wid * 128 + lane;
    int c1 = c0 + 64;
    const ushort* Ag0 = A + (size_t)(m0 + (c0 & 127)) * 1024 + (c0 >> 7) * 8;
    const ushort* Ag1 = A + (size_t)(m0 + (c1 & 127)) * 1024 + (c1 >> 7) * 8;
    const ushort* Bg0 = Wt + (size_t)(n0 + (c0 & 127)) * 1024 + (c0 >> 7) * 8;
    const ushort* Bg1 = Wt + (size_t)(n0 + (c1 & 127)) * 1024 + (c1 >> 7) * 8;
    ushort* Al0 = As + wid * 1024;
    ushort* Al1 = As + wid * 1024 + 512;
    ushort* Bl0 = Bs + wid * 1024;
    ushort* Bl1 = Bs + wid * 1024 + 512;

    const ushort* a_rd = &As[(quad * 128 + wm * 64 + l16) * 8];
    const ushort* b_rd = &Bs[(quad * 128 + wn * 64 + l16) * 8];

    for (int kb = 0; kb < 1024; kb += 32) {
        gl_lds16(Ag0 + kb, Al0);
        gl_lds16(Ag1 + kb, Al1);
        gl_lds16(Bg0 + kb, Bl0);
        gl_lds16(Bg1 + kb, Bl1);
        __syncthreads();
        short8 af[4], bf[4];
#pragma unroll
        for (int mi = 0; mi < 4; ++mi)
            af[mi] = *(const short8*)(a_rd + mi * 16 * 8);
#pragma unroll
        for (int ni = 0; ni < 4; ++ni)
            bf[ni] = *(const short8*)(b_rd + ni * 16 * 8);
#pragma unroll
        for (int mi = 0; mi < 4; ++mi)
#pragma unroll
            for (int ni = 0; ni < 4; ++ni)
                acc[mi][ni] = __builtin_amdgcn_mfma_f32_16x16x32_bf16(
                    af[mi], bf[ni], acc[mi][ni], 0, 0, 0);
        __syncthreads();
    }
#pragma unroll
    for (int mi = 0; mi < 4; ++mi) {
#pragma unroll
        for (int r = 0; r < 4; ++r) {
            int row = m0 + wm * 64 + mi * 16 + quad * 4 + r;
            ushort* Cp = C + (size_t)row * Ndim;
#pragma unroll
            for (int ni = 0; ni < 4; ++ni)
                Cp[n0 + wn * 64 + ni * 16 + l16] = f2b(acc[mi][ni][r]);
        }
    }
}

// ---------------- gb8 (bf16) = 8*tanh(gamma)/32 * gk16 @ K16r^T (causal-lower, MFMA) ----
__global__ __launch_bounds__(256) void gb_mfma(
        const ushort* __restrict__ gk16, const ushort* __restrict__ K16r,
        const float* __restrict__ gamma, ushort* __restrict__ gb) {
    int lt = blockIdx.x >> 4, mt = blockIdx.x & 15;
    if (mt > lt) return;
    int b = blockIdx.y;
    __shared__ ushort As[4096];
    __shared__ ushort Bs[4096];
    int tid = threadIdx.x;
    int wid = tid >> 6, lane = tid & 63;
    int l0 = lt * 128, m0 = mt * 128;
    int wm = wid >> 1, wn = wid & 1;
    int quad = lane >> 4, l16 = lane & 15;

    f32x4 acc[4][4];
#pragma unroll
    for (int mi = 0; mi < 4; ++mi)
#pragma unroll
        for (int ni = 0; ni < 4; ++ni) acc[mi][ni] = (f32x4){0.f, 0.f, 0.f, 0.f};

    int c0 = wid * 128 + lane;
    int c1 = c0 + 64;
    const ushort* Ag0 = gk16 + ((size_t)b * LL + l0 + (c0 & 127)) * 1024 + (c0 >> 7) * 8;
    const ushort* Ag1 = gk16 + ((size_t)b * LL + l0 + (c1 & 127)) * 1024 + (c1 >> 7) * 8;
    const ushort* Bg0 = K16r + ((size_t)b * LL + m0 + (c0 & 127)) * 1024 + (c0 >> 7) * 8;
    const ushort* Bg1 = K16r + ((size_t)b * LL + m0 + (c1 & 127)) * 1024 + (c1 >> 7) * 8;
    ushort* Al0 = As + wid * 1024;
    ushort* Al1 = As + wid * 1024 + 512;
    ushort* Bl0 = Bs + wid * 1024;
    ushort* Bl1 = Bs + wid * 1024 + 512;

    const ushort* a_rd = &As[(quad * 128 + wm * 64 + l16) * 8];
    const ushort* b_rd = &Bs[(quad * 128 + wn * 64 + l16) * 8];

    for (int kb = 0; kb < 1024; kb += 32) {
        gl_lds16(Ag0 + kb, Al0);
        gl_lds16(Ag1 + kb, Al1);
        gl_lds16(Bg0 + kb, Bl0);
        gl_lds16(Bg1 + kb, Bl1);
        __syncthreads();
        short8 af[4], bf[4];
#pragma unroll
        for (int mi = 0; mi < 4; ++mi)
            af[mi] = *(const short8*)(a_rd + mi * 16 * 8);
#pragma unroll
        for (int ni = 0; ni < 4; ++ni)
            bf[ni] = *(const short8*)(b_rd + ni * 16 * 8);
#pragma unroll
        for (int mi = 0; mi < 4; ++mi)
#pragma unroll
            for (int ni = 0; ni < 4; ++ni)
                acc[mi][ni] = __builtin_amdgcn_mfma_f32_16x16x32_bf16(
                    af[mi], bf[ni], acc[mi][ni], 0, 0, 0);
        __syncthreads();
    }
    float scale = tanhf(gamma[0]) * 0.25f;   // (1/32) * 8
#pragma unroll
    for (int mi = 0; mi < 4; ++mi) {
#pragma unroll
        for (int r = 0; r < 4; ++r) {
            int row = l0 + wm * 64 + mi * 16 + quad * 4 + r;
            ushort* Cp = gb + ((size_t)b * LL + row) * LL;
#pragma unroll
            for (int ni = 0; ni < 4; ++ni)
                Cp[m0 + wn * 64 + ni * 16 + l16] = f2b(acc[mi][ni][r] * scale);
        }
    }
}

// ---------------- gate finisher ----------------
__global__ __launch_bounds__(256) void gate_fin_kernel(
        const float* __restrict__ H1, const float* __restrict__ w2,
        const float* __restrict__ b2, float* __restrict__ gate) {
    int row = blockIdx.x, tid = threadIdx.x;
    float x = H1[(size_t)row * HG + tid];
    float val = gelu_f(x) * w2[tid];
    for (int off = 32; off; off >>= 1) val += __shfl_down(val, off);
    __shared__ float part[4];
    if ((tid & 63) == 0) part[tid >> 6] = val;
    __syncthreads();
    if (tid == 0) {
        float acc = part[0] + part[1] + part[2] + part[3] + b2[0];
        gate[row] = 1.f / (1.f + expf(-acc));
    }
}

// ---------------- nu finisher ----------------
__global__ __launch_bounds__(128) void nu_fin_kernel(
        const float* __restrict__ N1, const float* __restrict__ w2,
        const float* __restrict__ b2, const float* __restrict__ nu_diff,
        const float* __restrict__ nu_adv, float* __restrict__ nub) {
    int row = blockIdx.x, tid = threadIdx.x;
    float t = tanhf(N1[(size_t)row * HN + tid]);
    float val = t * w2[tid];
    for (int off = 32; off; off >>= 1) val += __shfl_down(val, off);
    __shared__ float part[2];
    if ((tid & 63) == 0) part[tid >> 6] = val;
    __syncthreads();
    if (tid == 0) {
        float acc = part[0] + part[1] + b2[0];
        nub[row] = fabsf(nu_diff[0]) + tanhf(acc) * fabsf(nu_adv[0]);
    }
}

// ---------------- gated dual-base RoPE on Q and K -> bf16 head-blocked [b,h,L,64] -------
__global__ void rope_qk_bf16(const float* __restrict__ Q, const float* __restrict__ K,
                             const float* __restrict__ gate,
                             ushort* __restrict__ Q16, ushort* __restrict__ K16) {
    int idx = blockIdx.x * 256 + threadIdx.x;   // over MM*512
    int row = idx >> 9;
    int i = idx & 511;
    int b = row >> 11, t = row & (LL - 1);
    float g = gate[row];
    float fi = (float)i * (1.0f / 512.0f);
    float tf = (float)t;
    float af = tf * expf(-fi * LOG_FAST);
    float as = tf * expf(-fi * LOG_SLOW);
    float c = g * cosf(af) + (1.f - g) * cosf(as);
    float s = g * sinf(af) + (1.f - g) * sinf(as);
    size_t base = (size_t)row * DD;
    float x = Q[base + i], y = Q[base + 512 + i];
    float q1 = x * c - y * s, q2 = y * c + x * s;
    x = K[base + i]; y = K[base + 512 + i];
    float k1 = x * c - y * s, k2 = y * c + x * s;
    int h1 = i >> 6, d1 = i & 63;
    size_t o1 = ((size_t)(b * 16 + h1) * LL + t) * 64 + d1;
    size_t o2 = ((size_t)(b * 16 + 8 + h1) * LL + t) * 64 + d1;
    Q16[o1] = f2b(q1); Q16[o2] = f2b(q2);
    K16[o1] = f2b(k1); K16[o2] = f2b(k2);
}

// ---------------- V fp32 [b*L,1024] -> V^T bf16 [b,h,64,L] ----------------
__global__ __launch_bounds__(256) void vt16_kernel(const float* __restrict__ V,
                                                   ushort* __restrict__ VT) {
    __shared__ ushort t[64][72];
    int lb = blockIdx.x, hb = blockIdx.y, b = blockIdx.z;
    int tid = threadIdx.x;
    {
        int l = tid >> 2, c0 = (tid & 3) * 16;
        const float* Vp = V + ((size_t)(b * LL) + lb * 64 + l) * DD + hb * 64 + c0;
#pragma unroll
        for (int j = 0; j < 4; ++j) {
            float4 v = *(const float4*)(Vp + j * 4);
            t[l][c0 + j * 4 + 0] = f2b(v.x);
            t[l][c0 + j * 4 + 1] = f2b(v.y);
            t[l][c0 + j * 4 + 2] = f2b(v.z);
            t[l][c0 + j * 4 + 3] = f2b(v.w);
        }
    }
    __syncthreads();
    {
        int d = tid >> 2, l0 = (tid & 3) * 16;
        ushort tmp[16];
#pragma unroll
        for (int j = 0; j < 16; ++j) tmp[j] = t[l0 + j][d];
        ushort* Op = VT + ((size_t)((b * 16 + hb) * 64) + d) * LL + lb * 64 + l0;
        *(ushort4*)(Op + 0)  = *(ushort4*)&tmp[0];
        *(ushort4*)(Op + 4)  = *(ushort4*)&tmp[4];
        *(ushort4*)(Op + 8)  = *(ushort4*)&tmp[8];
        *(ushort4*)(Op + 12) = *(ushort4*)&tmp[12];
    }
}

// ---------------- fixed-base RoPE for GLU branch, bf16 output ----------------
__global__ void rope_glu_b16(const float* __restrict__ z, ushort* __restrict__ zg) {
    int idx = blockIdx.x * 256 + threadIdx.x;
    int row = idx >> 9;
    int i = idx & 511;
    int t = row & (LL - 1);
    float fi = (float)i * (1.0f / 512.0f);
    float ag = (float)t * expf(-fi * LOG_GLU);
    float c = cosf(ag), s = sinf(ag);
    size_t base = (size_t)row * DD;
    float x = z[base + i], y = z[base + 512 + i];
    zg[base + i]       = f2b(x * c - y * s);
    zg[base + 512 + i] = f2b(y * c + x * s);
}

// ---------------- MFMA flash attention: double-buffered K/V, one barrier/iter ---------
__global__ __launch_bounds__(256, 3) void attn_flash_mfma(
        const ushort* __restrict__ Q16, const ushort* __restrict__ K16,
        const ushort* __restrict__ VT16, const ushort* __restrict__ gb16,
        float* __restrict__ attn_out, float* __restrict__ stats) {
    int h = blockIdx.x, qt = 31 - blockIdx.y, b = blockIdx.z;
    __shared__ ushort Qs[4096], Ks[2][4096], Vs[2][4096];
    __shared__ ushort Ps[4][1152];
    int tid = threadIdx.x, wid = tid >> 6, lane = tid & 63;
    int quad = lane >> 4, l16 = lane & 15;
    const ushort* Qg = Q16 + ((size_t)(b * 16 + h) * LL) * 64;
    const ushort* Kg = K16 + ((size_t)(b * 16 + h) * LL) * 64;
    const ushort* Vg = VT16 + ((size_t)(b * 16 + h) * 64) * LL;
    const ushort* gbB = gb16 + (size_t)b * LL * LL;
    float* stB = stats + ((size_t)(b * 16 + h) * LL) * 2;
    int qrow = wid * 16 + quad * 4;
    int q0 = qt * 64;

    stage_tile(Qg + (size_t)q0 * 64, 64, Qs, tid);
    stage_tile(Kg, 64, Ks[0], tid);
    stage_tile(Vg, LL, Vs[0], tid);
    __syncthreads();
    short8 qf[2];
#pragma unroll
    for (int ks = 0; ks < 2; ++ks)
        qf[ks] = *(const short8*)(Qs + SWZC(wid * 16 + l16, ks * 4 + quad));

    // ones B-fragment: 64x16 matrix with ones in column 0 (for P row-sums)
    short ov = (l16 == 0) ? (short)0x3F80 : (short)0;
    short8 onesf = {ov, ov, ov, ov, ov, ov, ov, ov};

    f32x4 ofr[5];   // [0..3]=O cols, [4]=row-sum l (lives in l16==0 lanes)
    float m_r[4];
#pragma unroll
    for (int nt = 0; nt < 5; ++nt) ofr[nt] = (f32x4){0.f, 0.f, 0.f, 0.f};
#pragma unroll
    for (int r = 0; r < 4; ++r) m_r[r] = -3e38f;

    for (int kt = 0; kt <= qt; ++kt) {
        int cur = kt & 1;
        int k0 = kt * 64;
        // gb loads first (older than prefetch: waiting on them leaves prefetch in flight)
        ushort gw[4][4];
#pragma unroll
        for (int r = 0; r < 4; ++r) {
            const ushort* gp = gbB + (size_t)(q0 + qrow + r) * LL + k0 + l16;
#pragma unroll
            for (int nt = 0; nt < 4; ++nt) gw[nt][r] = gp[nt * 16];
        }
        // prefetch next K/V tiles into the alternate buffer
        if (kt < qt) {
            stage_tile(Kg + (size_t)(k0 + 64) * 64, 64, Ks[cur ^ 1], tid);
            stage_tile(Vg + (k0 + 64), LL, Vs[cur ^ 1], tid);
        }
        f32x4 sf[4];
#pragma unroll
        for (int nt = 0; nt < 4; ++nt)
#pragma unroll
            for (int r = 0; r < 4; ++r) sf[nt][r] = b2f(gw[nt][r]);
#pragma unroll
        for (int ks = 0; ks < 2; ++ks)
#pragma unroll
            for (int nt = 0; nt < 4; ++nt) {
                short8 kf = *(const short8*)(Ks[cur] + SWZC(nt * 16 + l16, ks * 4 + quad));
                sf[nt] = __builtin_amdgcn_mfma_f32_16x16x32_bf16(qf[ks], kf, sf[nt], 0, 0, 0);
            }
        if (kt == qt) {
#pragma unroll
            for (int nt = 0; nt < 4; ++nt)
#pragma unroll
                for (int r = 0; r < 4; ++r)
                    if (nt * 16 + l16 > qrow + r) sf[nt][r] = -1e30f;
        }
        float alpha[4], mS[4];
#pragma unroll
        for (int r = 0; r < 4; ++r) {
            float m = fmaxf(fmaxf(sf[0][r], sf[1][r]), fmaxf(sf[2][r], sf[3][r]));
#pragma unroll
            for (int off = 1; off < 16; off <<= 1)
                m = fmaxf(m, __shfl_xor(m, off));
            float nm = fmaxf(m_r[r], m);
            alpha[r] = __builtin_amdgcn_exp2f((m_r[r] - nm) * SCL);
            m_r[r] = nm;
            mS[r] = nm * SCL;
        }
#pragma unroll
        for (int nt = 0; nt < 4; ++nt)
#pragma unroll
            for (int r = 0; r < 4; ++r) {
                float p = __builtin_amdgcn_exp2f(fmaf(sf[nt][r], SCL, -mS[r]));
                Ps[wid][(quad * 4 + r) * 72 + nt * 16 + l16] = f2b(p);
            }
#pragma unroll
        for (int nt = 0; nt < 5; ++nt)
#pragma unroll
            for (int r = 0; r < 4; ++r) ofr[nt][r] *= alpha[r];
        short8 pf[2];
#pragma unroll
        for (int ks = 0; ks < 2; ++ks)
            pf[ks] = *(const short8*)(Ps[wid] + l16 * 72 + ks * 32 + quad * 8);
#pragma unroll
        for (int ks = 0; ks < 2; ++ks) {
#pragma unroll
            for (int nt = 0; nt < 4; ++nt) {
                short8 vf = *(const short8*)(Vs[cur] + SWZC(nt * 16 + l16, ks * 4 + quad));
                ofr[nt] = __builtin_amdgcn_mfma_f32_16x16x32_bf16(pf[ks], vf, ofr[nt], 0, 0, 0);
            }
            ofr[4] = __builtin_amdgcn_mfma_f32_16x16x32_bf16(pf[ks], onesf, ofr[4], 0, 0, 0);
        }
        __syncthreads();
    }
#pragma unroll
    for (int r = 0; r < 4; ++r) {
        float l = __shfl(ofr[4][r], (lane & 48));   // broadcast from l16==0 of this quad
        float rinv = 1.0f / l;
        float* op = attn_out + ((size_t)(b * LL) + q0 + qrow + r) * DD + h * 64 + l16;
#pragma unroll
        for (int nt = 0; nt < 4; ++nt)
            op[nt * 16] = ofr[nt][r] * rinv;
    }
    if (l16 == 0) {
#pragma unroll
        for (int r = 0; r < 4; ++r) {
            size_t si = (size_t)(q0 + qrow + r) * 2;
            stB[si]     = m_r[r];        // raw (QK+gb8) domain max
            stB[si + 1] = ofr[4][r];     // linear-domain sum
        }
    }
}

// ---------------- attn_w: double-buffered over heads, one barrier/head ----------------
__global__ __launch_bounds__(256, 4) void attn_w_mfma(
        const ushort* __restrict__ Q16, const ushort* __restrict__ K16,
        const ushort* __restrict__ gb16, const float* __restrict__ stats,
        float* __restrict__ aw) {
    int qt = blockIdx.x >> 5, kt = blockIdx.x & 31;
    int b = blockIdx.y;
    int tid = threadIdx.x, wid = tid >> 6, lane = tid & 63;
    int quad = lane >> 4, l16 = lane & 15;
    int q0 = qt * 64, k0 = kt * 64;
    int qrow = wid * 16 + quad * 4;
    if (kt > qt) {
        int rr = tid >> 2, c0 = (tid & 3) * 16;
        float4 zv = make_float4(0.f, 0.f, 0.f, 0.f);
        float* p = aw + ((size_t)(b * LL) + q0 + rr) * LL + k0 + c0;
#pragma unroll
        for (int j = 0; j < 4; ++j) *(float4*)(p + j * 4) = zv;
        return;
    }
    __shared__ ushort Qs[2][4096], Ks[2][4096];
    float acc[4][4];
#pragma unroll
    for (int nt = 0; nt < 4; ++nt)
#pragma unroll
        for (int r = 0; r < 4; ++r) acc[nt][r] = 0.f;
    // gb8 tile (bf16), reused as accumulator init for every head
    f32x4 gacc[4];
    const ushort* gbB = gb16 + (size_t)b * LL * LL;
#pragma unroll
    for (int r = 0; r < 4; ++r) {
        const ushort* gp = gbB + (size_t)(q0 + qrow + r) * LL + k0 + l16;
#pragma unroll
        for (int nt = 0; nt < 4; ++nt) gacc[nt][r] = b2f(gp[nt * 16]);
    }
    bool diag = (kt == qt);
    stage_tile(Q16 + ((size_t)(b * 16) * LL + q0) * 64, 64, Qs[0], tid);
    stage_tile(K16 + ((size_t)(b * 16) * LL + k0) * 64, 64, Ks[0], tid);
    __syncthreads();
    for (int h = 0; h < NHH; ++h) {
        int cur = h & 1;
        // stats loads first (older than prefetch)
        float mS[4], li[4];
        const float* sp = stats + ((size_t)(b * 16 + h) * LL + q0 + qrow) * 2;
#pragma unroll
        for (int r = 0; r < 4; ++r) {
            mS[r] = sp[r * 2] * SCL;
            li[r] = 1.0f / sp[r * 2 + 1];
        }
        if (h < 15) {
            stage_tile(Q16 + ((size_t)(b * 16 + h + 1) * LL + q0) * 64, 64, Qs[cur ^ 1], tid);
            stage_tile(K16 + ((size_t)(b * 16 + h + 1) * LL + k0) * 64, 64, Ks[cur ^ 1], tid);
        }
        short8 qf[2];
#pragma unroll
        for (int ks = 0; ks < 2; ++ks)
            qf[ks] = *(const short8*)(Qs[cur] + SWZC(wid * 16 + l16, ks * 4 + quad));
        f32x4 sf[4];
#pragma unroll
        for (int nt = 0; nt < 4; ++nt) sf[nt] = gacc[nt];
#pragma unroll
        for (int ks = 0; ks < 2; ++ks)
#pragma unroll
            for (int nt = 0; nt < 4; ++nt) {
                short8 kf = *(const short8*)(Ks[cur] + SWZC(nt * 16 + l16, ks * 4 + quad));
                sf[nt] = __builtin_amdgcn_mfma_f32_16x16x32_bf16(qf[ks], kf, sf[nt], 0, 0, 0);
            }
#pragma unroll
        for (int nt = 0; nt < 4; ++nt)
#pragma unroll
            for (int r = 0; r < 4; ++r) {
                int row = qrow + r;
                if (!diag || (nt * 16 + l16 <= row))
                    acc[nt][r] += __builtin_amdgcn_exp2f(fmaf(sf[nt][r], SCL, -mS[r])) * li[r];
            }
        __syncthreads();
    }
#pragma unroll
    for (int r = 0; r < 4; ++r) {
        float* op = aw + ((size_t)(b * LL) + q0 + qrow + r) * LL + k0 + l16;
#pragma unroll
        for (int nt = 0; nt < 4; ++nt)
            op[nt * 16] = acc[nt][r] * 0.0625f;
    }
}

// ---------------- adv = -nu*U*G, layernorm -> adv_n (bf16 out) ----------------
__global__ __launch_bounds__(256) void adv_ln_kernel(
        const float* __restrict__ U, const float* __restrict__ G,
        const float* __restrict__ nub, const float* __restrict__ lnw,
        const float* __restrict__ lnb, ushort* __restrict__ out) {
    int row = blockIdx.x, tid = threadIdx.x;
    size_t base = (size_t)row * DD + tid * 4;
    float4 u4 = *(const float4*)&U[base];
    float4 g4 = *(const float4*)&G[base];
    float nu = nub[row];
    float a[4];
    a[0] = -nu * u4.x * g4.x;
    a[1] = -nu * u4.y * g4.y;
    a[2] = -nu * u4.z * g4.z;
    a[3] = -nu * u4.w * g4.w;
    float ts = a[0] + a[1] + a[2] + a[3];
    float tq = a[0] * a[0] + a[1] * a[1] + a[2] * a[2] + a[3] * a[3];
    for (int off = 32; off; off >>= 1) {
        ts += __shfl_down(ts, off);
        tq += __shfl_down(tq, off);
    }
    __shared__ float r1[4], r2[4];
    if ((tid & 63) == 0) { r1[tid >> 6] = ts; r2[tid >> 6] = tq; }
    __syncthreads();
    __shared__ float s_mu, s_rs;
    if (tid == 0) {
        float S  = r1[0] + r1[1] + r1[2] + r1[3];
        float Qq = r2[0] + r2[1] + r2[2] + r2[3];
        float mu = S * (1.0f / 1024.f);
        float var = Qq * (1.0f / 1024.f) - mu * mu;
        s_mu = mu;
        s_rs = rsqrtf(var + 1e-5f);
    }
    __syncthreads();
    float mu = s_mu, rs = s_rs;
    float4 w4 = *(const float4*)&lnw[tid * 4];
    float4 b4 = *(const float4*)&lnb[tid * 4];
    ushort4 ov;
    ov.x = f2b((a[0] - mu) * rs * w4.x + b4.x);
    ov.y = f2b((a[1] - mu) * rs * w4.y + b4.y);
    ov.z = f2b((a[2] - mu) * rs * w4.z + b4.z);
    ov.w = f2b((a[3] - mu) * rs * w4.w + b4.w);
    *(ushort4*)&out[base] = ov;
}

// ---------------- final residual combine ----------------
__global__ void final_kernel(const float* __restrict__ z, const float* __restrict__ ao,
                             const float* __restrict__ mlp, float* __restrict__ out) {
    size_t i = ((size_t)blockIdx.x * 256 + threadIdx.x) * 4;
    float4 z4 = *(const float4*)&z[i];
    float4 a4 = *(const float4*)&ao[i];
    float4 m4 = *(const float4*)&mlp[i];
    float4 o;
    o.x = z4.x + 0.42f * a4.x + 1.07f * m4.x;
    o.y = z4.y + 0.42f * a4.y + 1.07f * m4.y;
    o.z = z4.z + 0.42f * a4.z + 1.07f * m4.z;
    o.w = z4.w + 0.42f * a4.w + 1.07f * m4.w;
    *(float4*)&out[i] = o;
}

extern "C" void kernel_launch(void* const* d_in, const int* in_sizes, int n_in,
                              void* d_out, int out_size, void* d_ws, size_t ws_size,
                              hipStream_t stream) {
    const float* z       = (const float*)d_in[0];
    const float* Wq      = (const float*)d_in[1];
    const float* bq      = (const float*)d_in[2];
    const float* Wk      = (const float*)d_in[3];
    const float* bk      = (const float*)d_in[4];
    const float* Wv      = (const float*)d_in[5];
    const float* bv      = (const float*)d_in[6];
    const float* Wcoh    = (const float*)d_in[7];
    const float* gamma   = (const float*)d_in[8];
    const float* rg_w1   = (const float*)d_in[9];
    const float* rg_b1   = (const float*)d_in[10];
    const float* rg_w2   = (const float*)d_in[11];
    const float* rg_b2   = (const float*)d_in[12];
    const float* nu_diff = (const float*)d_in[13];
    const float* nu_adv  = (const float*)d_in[14];
    const float* nu_w1   = (const float*)d_in[15];
    const float* nu_b1   = (const float*)d_in[16];
    const float* nu_w2   = (const float*)d_in[17];
    const float* nu_b2   = (const float*)d_in[18];
    const float* Wu      = (const float*)d_in[19];
    const float* bu      = (const float*)d_in[20];
    const float* Wg      = (const float*)d_in[21];
    const float* bg      = (const float*)d_in[22];
    const float* ln_w    = (const float*)d_in[23];
    const float* ln_b    = (const float*)d_in[24];
    const float* Cw      = (const float*)d_in[25];
    const float* Cb      = (const float*)d_in[26];

    float* out_z  = (float*)d_out;
    float* out_aw = out_z + (size_t)MM * DD;

    float* ws = (float*)d_ws;
    const size_t MD = (size_t)MM * DD;   // 4,194,304
    float* pool  = ws;               // later: VT16 (bf16)
    float* Qb    = ws + MD;          // later U, later mlp_out
    float* Kb    = ws + 2 * MD;      // later G
    float* Vb    = ws + 3 * MD;      // later Q16/K16 (bf16)
    float* gkb   = ws + 4 * MD;      // gk16+K16r (bf16); later attn_out
    float* gbb   = ws + 5 * MD;      // 32MB region: Ab(8MB)+Wb(6MB) | gb16(16MB)
    float* H1    = ws + 7 * MD;      // MM*256
    float* N1    = H1 + (size_t)MM * HG;
    float* gate  = N1 + (size_t)MM * HN;
    float* nub   = gate + MM;
    float* stats = nub + MM;                       // B*NH*L*2
    float* ctot  = stats + (size_t)BB * NHH * LL * 2;  // B*NCH*DD

    // bf16 aliases inside the gbb region (Ab/Wb and gb16 are spatially disjoint)
    char* gbase  = (char*)gbb;
    ushort* Ab   = (ushort*)gbase;                               // 8 MB: GEMM A staging
    ushort* Wb   = (ushort*)(gbase + (size_t)8 * 1024 * 1024);   // 6 MB: 3 transposed weights
    ushort* gb16 = (ushort*)(gbase + (size_t)16 * 1024 * 1024);  // 16 MB: gb8 bf16
    ushort* Q16  = (ushort*)Vb;                  // [b,h,L,64]
    ushort* K16  = (ushort*)Vb + MD;             // [b,h,L,64]
    ushort* VT16 = (ushort*)pool;                // [b,h,64,L]
    ushort* gk16 = (ushort*)gkb;                 // [b*L,1024] bf16
    ushort* K16r = (ushort*)gkb + MD;            // [b*L,1024] bf16 (pre-RoPE K)

    dim3 g128(8, 32);
    dim3 cvt_g(4096);
    dim3 wT_g(32, 32);

    // 1. pool (parallel scan)
    pool_scan1<<<dim3(NCH, 4, BB), 256, 0, stream>>>(z, pool, ctot);
    pool_scan2<<<dim3(NCH, 4, BB), 256, 0, stream>>>(ctot, pool);
    // 2. zb -> Ab; fused QKV GEMM (768 blocks = 3 blocks/CU)
    f2b_kernel<<<cvt_g, 256, 0, stream>>>(z, Ab);
    f2bT3_kernel<<<dim3(32, 32, 3), 256, 0, stream>>>(Wq, Wk, Wv, Wb);
    gemm_mfma3<<<dim3(8, 32, 3), 256, 0, stream>>>(Ab, Wb, bq, bk, bv, Qb);
    // 2b. K_raw bf16 copy for gb
    f2b_kernel<<<cvt_g, 256, 0, stream>>>(Kb, K16r);
    // 3. pool GEMMs: gk (bf16 out), H1, N1
    f2b_kernel<<<cvt_g, 256, 0, stream>>>(pool, Ab);
    f2bT_kernel<<<wT_g, 256, 0, stream>>>(Wcoh, Wb, DD);
    gemm_mfma_b16out<<<g128, 256, 0, stream>>>(Ab, Wb, gk16, DD);
    f2bT_kernel<<<dim3(8, 32), 256, 0, stream>>>(rg_w1, Wb, HG);
    gemm_mfma<<<dim3(2, 32), 256, 0, stream>>>(Ab, Wb, rg_b1, H1, HG);
    f2bT_kernel<<<dim3(4, 32), 256, 0, stream>>>(nu_w1, Wb, HN);
    gemm_mfma<<<dim3(1, 32), 256, 0, stream>>>(Ab, Wb, nu_b1, N1, HN);
    // 4. gb8 (MFMA, bf16 out) — disjoint from Ab/Wb now
    gb_mfma<<<dim3(256, BB), 256, 0, stream>>>(gk16, K16r, gamma, gb16);
    // 5. gate / nu finishers
    gate_fin_kernel<<<dim3(MM), 256, 0, stream>>>(H1, rg_w2, rg_b2, gate);
    nu_fin_kernel<<<dim3(MM), 128, 0, stream>>>(N1, nu_w2, nu_b2, nu_diff, nu_adv, nub);
    // 6. V^T bf16 (reads Vb fp32, writes pool region) — BEFORE rope overwrites Vb
    vt16_kernel<<<dim3(32, 16, BB), 256, 0, stream>>>(Vb, VT16);
    // 7. rope Q,K -> bf16 head-blocked (into Vb region)
    rope_qk_bf16<<<dim3((MM * 512) / 256), 256, 0, stream>>>(Qb, Kb, gate, Q16, K16);
    // 8. MFMA flash attention (double-buffered) -> attn_out (gkb) + stats
    attn_flash_mfma<<<dim3(NHH, 32, BB), 256, 0, stream>>>(Q16, K16, VT16, gb16, gkb, stats);
    // 9. attn_w -> second half of d_out
    attn_w_mfma<<<dim3(1024, BB), 256, 0, stream>>>(Q16, K16, gb16, stats, out_aw);
    // 10. z_glu bf16 directly into Ab
    rope_glu_b16<<<dim3((MM * 512) / 256), 256, 0, stream>>>(z, Ab);
    // 11. fused U,G GEMM (512 blocks = 2 blocks/CU)
    f2bT3_kernel<<<dim3(32, 32, 2), 256, 0, stream>>>(Wu, Wg, Wg, Wb);
    gemm_mfma3<<<dim3(8, 32, 2), 256, 0, stream>>>(Ab, Wb, bu, bg, bg, Qb);
    // 12. adv + layernorm -> Ab (bf16, direct GEMM input)
    adv_ln_kernel<<<dim3(MM), 256, 0, stream>>>(Qb, Kb, nub, ln_w, ln_b, Ab);
    // 13. mlp_out = adv_n @ Cw + Cb -> Qb
    f2bT_kernel<<<wT_g, 256, 0, stream>>>(Cw, Wb, DD);
    gemm_mfma<<<g128, 256, 0, stream>>>(Ab, Wb, Cb, Qb, DD);
    // 14. final combine
    final_kernel<<<dim3(MD / 4 / 256), 256, 0, stream>>>(z, gkb, Qb, out_z);
}

// Round 7
// 582.743 us; speedup vs baseline: 5.9545x; 1.0752x over previous
//
#include <hip/hip_runtime.h>

#define DD 1024
#define NHH 16
#define HDD 64
#define BB 2
#define LL 2048
#define MM (BB*LL)          // 4096 rows
#define HG 256
#define HN 128

#define LOG_FAST 0.48121182f   // ln((1+sqrt(5))/2)
#define LOG_SLOW 7.3889461f    // ln(1618.0)
#define LOG_GLU  9.6915312f    // ln(16180.0)
#define SCL 0.18033688f        // 0.125 * log2(e); scores kept in (QK + 8*gb) raw domain

typedef __attribute__((ext_vector_type(8))) short short8;
typedef __attribute__((ext_vector_type(4))) float f32x4;

__device__ __forceinline__ float gelu_f(float x) {
    return 0.5f * x * (1.0f + erff(x * 0.70710678f));
}

__device__ __forceinline__ ushort f2b(float x) {
    unsigned u = __float_as_uint(x);
    unsigned r = (u + 0x7FFFu + ((u >> 16) & 1u)) >> 16;
    return (ushort)r;
}

__device__ __forceinline__ float b2f(ushort x) {
    return __uint_as_float(((unsigned)x) << 16);
}

__device__ __forceinline__ void gl_lds16(const ushort* g, ushort* l) {
    __builtin_amdgcn_global_load_lds(
        (const __attribute__((address_space(1))) unsigned int*)g,
        (__attribute__((address_space(3))) unsigned int*)l, 16, 0, 0);
}

// ushort offset of swizzled 16B chunk within a 64x64 bf16 tile
#define SWZC(row, c8) (((((row) << 3) | ((c8) ^ ((row) & 7)))) << 3)

// Stage a 64x64 bf16 tile (row-major, rstride in elements) into LDS with XOR swizzle.
__device__ __forceinline__ void stage_tile(const ushort* gsrc, int rstride,
                                           ushort* lds, int tid) {
    int wid = tid >> 6;
#pragma unroll
    for (int r = 0; r < 2; ++r) {
        int c = r * 256 + tid;
        int row = c >> 3;
        int c8 = (c & 7) ^ (row & 7);
        gl_lds16(gsrc + (size_t)row * rstride + c8 * 8,
                 lds + (size_t)(r * 256 + wid * 64) * 8);
    }
}

// ---------------- parallel causal cumulative mean pool (+ z->bf16 fused) ----------------
#define LCH 128
#define NCH 16
__global__ void pool_scan1(const float* __restrict__ z, float* __restrict__ part,
                           float* __restrict__ ctot, ushort* __restrict__ zb) {
    int ch = blockIdx.x, dg = blockIdx.y, b = blockIdx.z;
    int d = dg * 256 + threadIdx.x;
    size_t base = ((size_t)b * LL + ch * LCH) * DD + d;
    const float* zp = z + base;
    float* pp = part + base;
    ushort* zo = zb + base;
    float s = 0.f;
    for (int t = 0; t < LCH; ++t) {
        float v = zp[(size_t)t * DD];
        s += v;
        pp[(size_t)t * DD] = s;
        zo[(size_t)t * DD] = f2b(v);
    }
    ctot[((size_t)b * NCH + ch) * DD + d] = s;
}
__global__ void pool_scan2(const float* __restrict__ part, const float* __restrict__ ctot,
                           ushort* __restrict__ poolb) {
    int ch = blockIdx.x, dg = blockIdx.y, b = blockIdx.z;
    int d = dg * 256 + threadIdx.x;
    float off = 0.f;
    for (int c = 0; c < ch; ++c) off += ctot[((size_t)b * NCH + c) * DD + d];
    int t0 = ch * LCH;
    size_t base = ((size_t)b * LL + t0) * DD + d;
    const float* pp = part + base;
    ushort* po = poolb + base;
    for (int t = 0; t < LCH; ++t) {
        po[(size_t)t * DD] = f2b((pp[(size_t)t * DD] + off) / (float)(t0 + t + 1));
    }
}

// ---------------- weight transpose converters ----------------
// four square 1024x1024 weights -> transposed bf16 slots (z selects)
__global__ void f2bT4_kernel(const float* __restrict__ W0, const float* __restrict__ W1,
                             const float* __restrict__ W2, const float* __restrict__ W3,
                             ushort* __restrict__ Wt) {
    const float* W = blockIdx.z == 0 ? W0 : (blockIdx.z == 1 ? W1 :
                     (blockIdx.z == 2 ? W2 : W3));
    ushort* dst = Wt + (size_t)blockIdx.z * 1024 * 1024;
    __shared__ float t[32][33];
    int n0 = blockIdx.x * 32, k0 = blockIdx.y * 32;
    int tx = threadIdx.x & 31, ty = threadIdx.x >> 5;
#pragma unroll
    for (int j = 0; j < 4; ++j)
        t[ty + j * 8][tx] = W[(size_t)(k0 + ty + j * 8) * 1024 + n0 + tx];
    __syncthreads();
#pragma unroll
    for (int j = 0; j < 4; ++j)
        dst[(size_t)(n0 + ty + j * 8) * 1024 + k0 + tx] = f2b(t[tx][ty + j * 8]);
}

// rg_w1 (1024x256) and nu_w1 (1024x128) -> transposed bf16 (z selects)
__global__ void f2bT_rgnu(const float* __restrict__ Wrg, const float* __restrict__ Wnu,
                          ushort* __restrict__ WtRG, ushort* __restrict__ WtNU) {
    int zc = blockIdx.z;
    if (zc == 1 && blockIdx.x >= 4) return;
    const float* W = zc == 0 ? Wrg : Wnu;
    ushort* dst = zc == 0 ? WtRG : WtNU;
    int Ndim = zc == 0 ? HG : HN;
    __shared__ float t[32][33];
    int n0 = blockIdx.x * 32, k0 = blockIdx.y * 32;
    int tx = threadIdx.x & 31, ty = threadIdx.x >> 5;
#pragma unroll
    for (int j = 0; j < 4; ++j)
        t[ty + j * 8][tx] = W[(size_t)(k0 + ty + j * 8) * Ndim + n0 + tx];
    __syncthreads();
#pragma unroll
    for (int j = 0; j < 4; ++j)
        dst[(size_t)(n0 + ty + j * 8) * 1024 + k0 + tx] = f2b(t[tx][ty + j * 8]);
}

// three square 1024x1024 weights -> transposed bf16 slots
__global__ void f2bT3_kernel(const float* __restrict__ W0, const float* __restrict__ W1,
                             const float* __restrict__ W2, ushort* __restrict__ Wt) {
    const float* W = blockIdx.z == 0 ? W0 : (blockIdx.z == 1 ? W1 : W2);
    ushort* dst = Wt + (size_t)blockIdx.z * 1024 * 1024;
    __shared__ float t[32][33];
    int n0 = blockIdx.x * 32, k0 = blockIdx.y * 32;
    int tx = threadIdx.x & 31, ty = threadIdx.x >> 5;
#pragma unroll
    for (int j = 0; j < 4; ++j)
        t[ty + j * 8][tx] = W[(size_t)(k0 + ty + j * 8) * 1024 + n0 + tx];
    __syncthreads();
#pragma unroll
    for (int j = 0; j < 4; ++j)
        dst[(size_t)(n0 + ty + j * 8) * 1024 + k0 + tx] = f2b(t[tx][ty + j * 8]);
}

// ---------------- bf16 MFMA GEMM: C(fp32, M x Ndim) = A(M x 1024 bf16) @ Wt^T + bias
__global__ __launch_bounds__(256) void gemm_mfma(
        const ushort* __restrict__ A, const ushort* __restrict__ Wt,
        const float* __restrict__ bias, float* __restrict__ C, int Ndim) {
    __shared__ ushort As[4096];
    __shared__ ushort Bs[4096];
    int tid = threadIdx.x;
    int wid = tid >> 6, lane = tid & 63;
    int n0 = blockIdx.x * 128, m0 = blockIdx.y * 128;
    int wm = wid >> 1, wn = wid & 1;
    int quad = lane >> 4, l16 = lane & 15;

    f32x4 acc[4][4];
#pragma unroll
    for (int mi = 0; mi < 4; ++mi)
#pragma unroll
        for (int ni = 0; ni < 4; ++ni) acc[mi][ni] = (f32x4){0.f, 0.f, 0.f, 0.f};

    int c0 = wid * 128 + lane;
    int c1 = c0 + 64;
    const ushort* Ag0 = A + (size_t)(m0 + (c0 & 127)) * 1024 + (c0 >> 7) * 8;
    const ushort* Ag1 = A + (size_t)(m0 + (c1 & 127)) * 1024 + (c1 >> 7) * 8;
    const ushort* Bg0 = Wt + (size_t)(n0 + (c0 & 127)) * 1024 + (c0 >> 7) * 8;
    const ushort* Bg1 = Wt + (size_t)(n0 + (c1 & 127)) * 1024 + (c1 >> 7) * 8;
    ushort* Al0 = As + wid * 1024;
    ushort* Al1 = As + wid * 1024 + 512;
    ushort* Bl0 = Bs + wid * 1024;
    ushort* Bl1 = Bs + wid * 1024 + 512;

    const ushort* a_rd = &As[(quad * 128 + wm * 64 + l16) * 8];
    const ushort* b_rd = &Bs[(quad * 128 + wn * 64 + l16) * 8];

    for (int kb = 0; kb < 1024; kb += 32) {
        gl_lds16(Ag0 + kb, Al0);
        gl_lds16(Ag1 + kb, Al1);
        gl_lds16(Bg0 + kb, Bl0);
        gl_lds16(Bg1 + kb, Bl1);
        __syncthreads();
        short8 af[4], bf[4];
#pragma unroll
        for (int mi = 0; mi < 4; ++mi)
            af[mi] = *(const short8*)(a_rd + mi * 16 * 8);
#pragma unroll
        for (int ni = 0; ni < 4; ++ni)
            bf[ni] = *(const short8*)(b_rd + ni * 16 * 8);
#pragma unroll
        for (int mi = 0; mi < 4; ++mi)
#pragma unroll
            for (int ni = 0; ni < 4; ++ni)
                acc[mi][ni] = __builtin_amdgcn_mfma_f32_16x16x32_bf16(
                    af[mi], bf[ni], acc[mi][ni], 0, 0, 0);
        __syncthreads();
    }
    int bcol[4];
    float bval[4];
#pragma unroll
    for (int ni = 0; ni < 4; ++ni) {
        bcol[ni] = n0 + wn * 64 + ni * 16 + l16;
        bval[ni] = bias ? bias[bcol[ni]] : 0.f;
    }
#pragma unroll
    for (int mi = 0; mi < 4; ++mi) {
#pragma unroll
        for (int r = 0; r < 4; ++r) {
            int row = m0 + wm * 64 + mi * 16 + quad * 4 + r;
            float* Cp = C + (size_t)row * Ndim;
#pragma unroll
            for (int ni = 0; ni < 4; ++ni)
                Cp[bcol[ni]] = acc[mi][ni][r] + bval[ni];
        }
    }
}

// ---------------- fused multi-weight GEMM; zid==1 also emits bf16 copy (K16r) ---------
__global__ __launch_bounds__(256) void gemm_mfma3(
        const ushort* __restrict__ A, const ushort* __restrict__ Wt,
        const float* __restrict__ b0, const float* __restrict__ b1,
        const float* __restrict__ b2, float* __restrict__ C,
        ushort* __restrict__ K16r) {
    int zid = blockIdx.z;
    const ushort* W = Wt + (size_t)zid * 1024 * 1024;
    const float* bias = zid == 0 ? b0 : (zid == 1 ? b1 : b2);
    float* Cz = C + (size_t)zid * (size_t)MM * DD;
    __shared__ ushort As[4096];
    __shared__ ushort Bs[4096];
    int tid = threadIdx.x;
    int wid = tid >> 6, lane = tid & 63;
    int n0 = blockIdx.x * 128, m0 = blockIdx.y * 128;
    int wm = wid >> 1, wn = wid & 1;
    int quad = lane >> 4, l16 = lane & 15;

    f32x4 acc[4][4];
#pragma unroll
    for (int mi = 0; mi < 4; ++mi)
#pragma unroll
        for (int ni = 0; ni < 4; ++ni) acc[mi][ni] = (f32x4){0.f, 0.f, 0.f, 0.f};

    int c0 = wid * 128 + lane;
    int c1 = c0 + 64;
    const ushort* Ag0 = A + (size_t)(m0 + (c0 & 127)) * 1024 + (c0 >> 7) * 8;
    const ushort* Ag1 = A + (size_t)(m0 + (c1 & 127)) * 1024 + (c1 >> 7) * 8;
    const ushort* Bg0 = W + (size_t)(n0 + (c0 & 127)) * 1024 + (c0 >> 7) * 8;
    const ushort* Bg1 = W + (size_t)(n0 + (c1 & 127)) * 1024 + (c1 >> 7) * 8;
    ushort* Al0 = As + wid * 1024;
    ushort* Al1 = As + wid * 1024 + 512;
    ushort* Bl0 = Bs + wid * 1024;
    ushort* Bl1 = Bs + wid * 1024 + 512;

    const ushort* a_rd = &As[(quad * 128 + wm * 64 + l16) * 8];
    const ushort* b_rd = &Bs[(quad * 128 + wn * 64 + l16) * 8];

    for (int kb = 0; kb < 1024; kb += 32) {
        gl_lds16(Ag0 + kb, Al0);
        gl_lds16(Ag1 + kb, Al1);
        gl_lds16(Bg0 + kb, Bl0);
        gl_lds16(Bg1 + kb, Bl1);
        __syncthreads();
        short8 af[4], bf[4];
#pragma unroll
        for (int mi = 0; mi < 4; ++mi)
            af[mi] = *(const short8*)(a_rd + mi * 16 * 8);
#pragma unroll
        for (int ni = 0; ni < 4; ++ni)
            bf[ni] = *(const short8*)(b_rd + ni * 16 * 8);
#pragma unroll
        for (int mi = 0; mi < 4; ++mi)
#pragma unroll
            for (int ni = 0; ni < 4; ++ni)
                acc[mi][ni] = __builtin_amdgcn_mfma_f32_16x16x32_bf16(
                    af[mi], bf[ni], acc[mi][ni], 0, 0, 0);
        __syncthreads();
    }
    float bval[4];
    int bcol[4];
#pragma unroll
    for (int ni = 0; ni < 4; ++ni) {
        bcol[ni] = n0 + wn * 64 + ni * 16 + l16;
        bval[ni] = bias[bcol[ni]];
    }
    bool doK = (zid == 1) && (K16r != nullptr);
#pragma unroll
    for (int mi = 0; mi < 4; ++mi) {
#pragma unroll
        for (int r = 0; r < 4; ++r) {
            int row = m0 + wm * 64 + mi * 16 + quad * 4 + r;
            float* Cp = Cz + (size_t)row * 1024;
            ushort* Kp = K16r + (size_t)row * 1024;
#pragma unroll
            for (int ni = 0; ni < 4; ++ni) {
                float v = acc[mi][ni][r] + bval[ni];
                Cp[bcol[ni]] = v;
                if (doK) Kp[bcol[ni]] = f2b(v);
            }
        }
    }
}

// ---------------- same GEMM but bf16 output, no bias (for gk) ----------------
__global__ __launch_bounds__(256) void gemm_mfma_b16out(
        const ushort* __restrict__ A, const ushort* __restrict__ Wt,
        ushort* __restrict__ C, int Ndim) {
    __shared__ ushort As[4096];
    __shared__ ushort Bs[4096];
    int tid = threadIdx.x;
    int wid = tid >> 6, lane = tid & 63;
    int n0 = blockIdx.x * 128, m0 = blockIdx.y * 128;
    int wm = wid >> 1, wn = wid & 1;
    int quad = lane >> 4, l16 = lane & 15;

    f32x4 acc[4][4];
#pragma unroll
    for (int mi = 0; mi < 4; ++mi)
#pragma unroll
        for (int ni = 0; ni < 4; ++ni) acc[mi][ni] = (f32x4){0.f, 0.f, 0.f, 0.f};

    int c0 = wid * 128 + lane;
    int c1 = c0 + 64;
    const ushort* Ag0 = A + (size_t)(m0 + (c0 & 127)) * 1024 + (c0 >> 7) * 8;
    const ushort* Ag1 = A + (size_t)(m0 + (c1 & 127)) * 1024 + (c1 >> 7) * 8;
    const ushort* Bg0 = Wt + (size_t)(n0 + (c0 & 127)) * 1024 + (c0 >> 7) * 8;
    const ushort* Bg1 = Wt + (size_t)(n0 + (c1 & 127)) * 1024 + (c1 >> 7) * 8;
    ushort* Al0 = As + wid * 1024;
    ushort* Al1 = As + wid * 1024 + 512;
    ushort* Bl0 = Bs + wid * 1024;
    ushort* Bl1 = Bs + wid * 1024 + 512;

    const ushort* a_rd = &As[(quad * 128 + wm * 64 + l16) * 8];
    const ushort* b_rd = &Bs[(quad * 128 + wn * 64 + l16) * 8];

    for (int kb = 0; kb < 1024; kb += 32) {
        gl_lds16(Ag0 + kb, Al0);
        gl_lds16(Ag1 + kb, Al1);
        gl_lds16(Bg0 + kb, Bl0);
        gl_lds16(Bg1 + kb, Bl1);
        __syncthreads();
        short8 af[4], bf[4];
#pragma unroll
        for (int mi = 0; mi < 4; ++mi)
            af[mi] = *(const short8*)(a_rd + mi * 16 * 8);
#pragma unroll
        for (int ni = 0; ni < 4; ++ni)
            bf[ni] = *(const short8*)(b_rd + ni * 16 * 8);
#pragma unroll
        for (int mi = 0; mi < 4; ++mi)
#pragma unroll
            for (int ni = 0; ni < 4; ++ni)
                acc[mi][ni] = __builtin_amdgcn_mfma_f32_16x16x32_bf16(
                    af[mi], bf[ni], acc[mi][ni], 0, 0, 0);
        __syncthreads();
    }
#pragma unroll
    for (int mi = 0; mi < 4; ++mi) {
#pragma unroll
        for (int r = 0; r < 4; ++r) {
            int row = m0 + wm * 64 + mi * 16 + quad * 4 + r;
            ushort* Cp = C + (size_t)row * Ndim;
#pragma unroll
            for (int ni = 0; ni < 4; ++ni)
                Cp[n0 + wn * 64 + ni * 16 + l16] = f2b(acc[mi][ni][r]);
        }
    }
}

// ---------------- fused H1/N1 GEMM: blockIdx.x<2 -> H1 (Ndim 256), else N1 (128) ------
__global__ __launch_bounds__(256) void gemm_gates(
        const ushort* __restrict__ A, const ushort* __restrict__ WtRG,
        const ushort* __restrict__ WtNU, const float* __restrict__ rg_b1,
        const float* __restrict__ nu_b1, float* __restrict__ H1,
        float* __restrict__ N1) {
    int bx = blockIdx.x;
    bool isH = bx < 2;
    const ushort* Wt = isH ? WtRG : WtNU;
    const float* bias = isH ? rg_b1 : nu_b1;
    float* C = isH ? H1 : N1;
    int Ndim = isH ? HG : HN;
    int n0 = isH ? bx * 128 : 0;
    int m0 = blockIdx.y * 128;
    __shared__ ushort As[4096];
    __shared__ ushort Bs[4096];
    int tid = threadIdx.x;
    int wid = tid >> 6, lane = tid & 63;
    int wm = wid >> 1, wn = wid & 1;
    int quad = lane >> 4, l16 = lane & 15;

    f32x4 acc[4][4];
#pragma unroll
    for (int mi = 0; mi < 4; ++mi)
#pragma unroll
        for (int ni = 0; ni < 4; ++ni) acc[mi][ni] = (f32x4){0.f, 0.f, 0.f, 0.f};

    int c0 = wid * 128 + lane;
    int c1 = c0 + 64;
    const ushort* Ag0 = A + (size_t)(m0 + (c0 & 127)) * 1024 + (c0 >> 7) * 8;
    const ushort* Ag1 = A + (size_t)(m0 + (c1 & 127)) * 1024 + (c1 >> 7) * 8;
    const ushort* Bg0 = Wt + (size_t)(n0 + (c0 & 127)) * 1024 + (c0 >> 7) * 8;
    const ushort* Bg1 = Wt + (size_t)(n0 + (c1 & 127)) * 1024 + (c1 >> 7) * 8;
    ushort* Al0 = As + wid * 1024;
    ushort* Al1 = As + wid * 1024 + 512;
    ushort* Bl0 = Bs + wid * 1024;
    ushort* Bl1 = Bs + wid * 1024 + 512;

    const ushort* a_rd = &As[(quad * 128 + wm * 64 + l16) * 8];
    const ushort* b_rd = &Bs[(quad * 128 + wn * 64 + l16) * 8];

    for (int kb = 0; kb < 1024; kb += 32) {
        gl_lds16(Ag0 + kb, Al0);
        gl_lds16(Ag1 + kb, Al1);
        gl_lds16(Bg0 + kb, Bl0);
        gl_lds16(Bg1 + kb, Bl1);
        __syncthreads();
        short8 af[4], bf[4];
#pragma unroll
        for (int mi = 0; mi < 4; ++mi)
            af[mi] = *(const short8*)(a_rd + mi * 16 * 8);
#pragma unroll
        for (int ni = 0; ni < 4; ++ni)
            bf[ni] = *(const short8*)(b_rd + ni * 16 * 8);
#pragma unroll
        for (int mi = 0; mi < 4; ++mi)
#pragma unroll
            for (int ni = 0; ni < 4; ++ni)
                acc[mi][ni] = __builtin_amdgcn_mfma_f32_16x16x32_bf16(
                    af[mi], bf[ni], acc[mi][ni], 0, 0, 0);
        __syncthreads();
    }
    int bcol[4];
    float bval[4];
#pragma unroll
    for (int ni = 0; ni < 4; ++ni) {
        bcol[ni] = n0 + wn * 64 + ni * 16 + l16;
        bval[ni] = bias[bcol[ni]];
    }
#pragma unroll
    for (int mi = 0; mi < 4; ++mi) {
#pragma unroll
        for (int r = 0; r < 4; ++r) {
            int row = m0 + wm * 64 + mi * 16 + quad * 4 + r;
            float* Cp = C + (size_t)row * Ndim;
#pragma unroll
            for (int ni = 0; ni < 4; ++ni)
                Cp[bcol[ni]] = acc[mi][ni][r] + bval[ni];
        }
    }
}

// ---------------- gb8 (bf16) = 8*tanh(gamma)/32 * gk16 @ K16r^T (causal-lower, MFMA) ----
__global__ __launch_bounds__(256) void gb_mfma(
        const ushort* __restrict__ gk16, const ushort* __restrict__ K16r,
        const float* __restrict__ gamma, ushort* __restrict__ gb) {
    int lt = blockIdx.x >> 4, mt = blockIdx.x & 15;
    if (mt > lt) return;
    int b = blockIdx.y;
    __shared__ ushort As[4096];
    __shared__ ushort Bs[4096];
    int tid = threadIdx.x;
    int wid = tid >> 6, lane = tid & 63;
    int l0 = lt * 128, m0 = mt * 128;
    int wm = wid >> 1, wn = wid & 1;
    int quad = lane >> 4, l16 = lane & 15;

    f32x4 acc[4][4];
#pragma unroll
    for (int mi = 0; mi < 4; ++mi)
#pragma unroll
        for (int ni = 0; ni < 4; ++ni) acc[mi][ni] = (f32x4){0.f, 0.f, 0.f, 0.f};

    int c0 = wid * 128 + lane;
    int c1 = c0 + 64;
    const ushort* Ag0 = gk16 + ((size_t)b * LL + l0 + (c0 & 127)) * 1024 + (c0 >> 7) * 8;
    const ushort* Ag1 = gk16 + ((size_t)b * LL + l0 + (c1 & 127)) * 1024 + (c1 >> 7) * 8;
    const ushort* Bg0 = K16r + ((size_t)b * LL + m0 + (c0 & 127)) * 1024 + (c0 >> 7) * 8;
    const ushort* Bg1 = K16r + ((size_t)b * LL + m0 + (c1 & 127)) * 1024 + (c1 >> 7) * 8;
    ushort* Al0 = As + wid * 1024;
    ushort* Al1 = As + wid * 1024 + 512;
    ushort* Bl0 = Bs + wid * 1024;
    ushort* Bl1 = Bs + wid * 1024 + 512;

    const ushort* a_rd = &As[(quad * 128 + wm * 64 + l16) * 8];
    const ushort* b_rd = &Bs[(quad * 128 + wn * 64 + l16) * 8];

    for (int kb = 0; kb < 1024; kb += 32) {
        gl_lds16(Ag0 + kb, Al0);
        gl_lds16(Ag1 + kb, Al1);
        gl_lds16(Bg0 + kb, Bl0);
        gl_lds16(Bg1 + kb, Bl1);
        __syncthreads();
        short8 af[4], bf[4];
#pragma unroll
        for (int mi = 0; mi < 4; ++mi)
            af[mi] = *(const short8*)(a_rd + mi * 16 * 8);
#pragma unroll
        for (int ni = 0; ni < 4; ++ni)
            bf[ni] = *(const short8*)(b_rd + ni * 16 * 8);
#pragma unroll
        for (int mi = 0; mi < 4; ++mi)
#pragma unroll
            for (int ni = 0; ni < 4; ++ni)
                acc[mi][ni] = __builtin_amdgcn_mfma_f32_16x16x32_bf16(
                    af[mi], bf[ni], acc[mi][ni], 0, 0, 0);
        __syncthreads();
    }
    float scale = tanhf(gamma[0]) * 0.25f;   // (1/32) * 8
#pragma unroll
    for (int mi = 0; mi < 4; ++mi) {
#pragma unroll
        for (int r = 0; r < 4; ++r) {
            int row = l0 + wm * 64 + mi * 16 + quad * 4 + r;
            ushort* Cp = gb + ((size_t)b * LL + row) * LL;
#pragma unroll
            for (int ni = 0; ni < 4; ++ni)
                Cp[m0 + wn * 64 + ni * 16 + l16] = f2b(acc[mi][ni][r] * scale);
        }
    }
}

// ---------------- fused gate + nu finisher ----------------
__global__ __launch_bounds__(256) void gatenu_fin(
        const float* __restrict__ H1, const float* __restrict__ N1,
        const float* __restrict__ rg_w2, const float* __restrict__ rg_b2,
        const float* __restrict__ nu_w2, const float* __restrict__ nu_b2,
        const float* __restrict__ nu_diff, const float* __restrict__ nu_adv,
        float* __restrict__ gate, float* __restrict__ nub) {
    int row = blockIdx.x, tid = threadIdx.x;
    float gv = gelu_f(H1[(size_t)row * HG + tid]) * rg_w2[tid];
    float nv = (tid < HN) ? tanhf(N1[(size_t)row * HN + tid]) * nu_w2[tid] : 0.f;
    for (int off = 32; off; off >>= 1) {
        gv += __shfl_down(gv, off);
        nv += __shfl_down(nv, off);
    }
    __shared__ float pg[4], pn[4];
    if ((tid & 63) == 0) { pg[tid >> 6] = gv; pn[tid >> 6] = nv; }
    __syncthreads();
    if (tid == 0) {
        float ga = pg[0] + pg[1] + pg[2] + pg[3] + rg_b2[0];
        gate[row] = 1.f / (1.f + expf(-ga));
        float na = pn[0] + pn[1] + pn[2] + pn[3] + nu_b2[0];
        nub[row] = fabsf(nu_diff[0]) + tanhf(na) * fabsf(nu_adv[0]);
    }
}

// ---------------- gated dual-base RoPE on Q and K -> bf16 head-blocked [b,h,L,64] -------
__global__ void rope_qk_bf16(const float* __restrict__ Q, const float* __restrict__ K,
                             const float* __restrict__ gate,
                             ushort* __restrict__ Q16, ushort* __restrict__ K16) {
    int idx = blockIdx.x * 256 + threadIdx.x;   // over MM*512
    int row = idx >> 9;
    int i = idx & 511;
    int b = row >> 11, t = row & (LL - 1);
    float g = gate[row];
    float fi = (float)i * (1.0f / 512.0f);
    float tf = (float)t;
    float af = tf * expf(-fi * LOG_FAST);
    float as = tf * expf(-fi * LOG_SLOW);
    float c = g * cosf(af) + (1.f - g) * cosf(as);
    float s = g * sinf(af) + (1.f - g) * sinf(as);
    size_t base = (size_t)row * DD;
    float x = Q[base + i], y = Q[base + 512 + i];
    float q1 = x * c - y * s, q2 = y * c + x * s;
    x = K[base + i]; y = K[base + 512 + i];
    float k1 = x * c - y * s, k2 = y * c + x * s;
    int h1 = i >> 6, d1 = i & 63;
    size_t o1 = ((size_t)(b * 16 + h1) * LL + t) * 64 + d1;
    size_t o2 = ((size_t)(b * 16 + 8 + h1) * LL + t) * 64 + d1;
    Q16[o1] = f2b(q1); Q16[o2] = f2b(q2);
    K16[o1] = f2b(k1); K16[o2] = f2b(k2);
}

// ---------------- V fp32 [b*L,1024] -> V^T bf16 [b,h,64,L] ----------------
__global__ __launch_bounds__(256) void vt16_kernel(const float* __restrict__ V,
                                                   ushort* __restrict__ VT) {
    __shared__ ushort t[64][72];
    int lb = blockIdx.x, hb = blockIdx.y, b = blockIdx.z;
    int tid = threadIdx.x;
    {
        int l = tid >> 2, c0 = (tid & 3) * 16;
        const float* Vp = V + ((size_t)(b * LL) + lb * 64 + l) * DD + hb * 64 + c0;
#pragma unroll
        for (int j = 0; j < 4; ++j) {
            float4 v = *(const float4*)(Vp + j * 4);
            t[l][c0 + j * 4 + 0] = f2b(v.x);
            t[l][c0 + j * 4 + 1] = f2b(v.y);
            t[l][c0 + j * 4 + 2] = f2b(v.z);
            t[l][c0 + j * 4 + 3] = f2b(v.w);
        }
    }
    __syncthreads();
    {
        int d = tid >> 2, l0 = (tid & 3) * 16;
        ushort tmp[16];
#pragma unroll
        for (int j = 0; j < 16; ++j) tmp[j] = t[l0 + j][d];
        ushort* Op = VT + ((size_t)((b * 16 + hb) * 64) + d) * LL + lb * 64 + l0;
        *(ushort4*)(Op + 0)  = *(ushort4*)&tmp[0];
        *(ushort4*)(Op + 4)  = *(ushort4*)&tmp[4];
        *(ushort4*)(Op + 8)  = *(ushort4*)&tmp[8];
        *(ushort4*)(Op + 12) = *(ushort4*)&tmp[12];
    }
}

// ---------------- fixed-base RoPE for GLU branch, bf16 output ----------------
__global__ void rope_glu_b16(const float* __restrict__ z, ushort* __restrict__ zg) {
    int idx = blockIdx.x * 256 + threadIdx.x;
    int row = idx >> 9;
    int i = idx & 511;
    int t = row & (LL - 1);
    float fi = (float)i * (1.0f / 512.0f);
    float ag = (float)t * expf(-fi * LOG_GLU);
    float c = cosf(ag), s = sinf(ag);
    size_t base = (size_t)row * DD;
    float x = z[base + i], y = z[base + 512 + i];
    zg[base + i]       = f2b(x * c - y * s);
    zg[base + 512 + i] = f2b(y * c + x * s);
}

// ---------------- MFMA flash attention: 4 blocks/CU, K-dbuf, V-single, P aliases Q ----
__global__ __launch_bounds__(256, 4) void attn_flash_mfma(
        const ushort* __restrict__ Q16, const ushort* __restrict__ K16,
        const ushort* __restrict__ VT16, const ushort* __restrict__ gb16,
        float* __restrict__ attn_out, float* __restrict__ stats) {
    int h = blockIdx.x, qt = 31 - blockIdx.y, b = blockIdx.z;
    __shared__ ushort QP[4608];        // Q stage (4096) then per-wave P (wid*1152)
    __shared__ ushort Ks[2][4096];
    __shared__ ushort Vs[4096];
    int tid = threadIdx.x, wid = tid >> 6, lane = tid & 63;
    int quad = lane >> 4, l16 = lane & 15;
    const ushort* Qg = Q16 + ((size_t)(b * 16 + h) * LL) * 64;
    const ushort* Kg = K16 + ((size_t)(b * 16 + h) * LL) * 64;
    const ushort* Vg = VT16 + ((size_t)(b * 16 + h) * 64) * LL;
    const ushort* gbB = gb16 + (size_t)b * LL * LL;
    float* stB = stats + ((size_t)(b * 16 + h) * LL) * 2;
    int qrow = wid * 16 + quad * 4;
    int q0 = qt * 64;

    stage_tile(Qg + (size_t)q0 * 64, 64, QP, tid);
    stage_tile(Kg, 64, Ks[0], tid);
    stage_tile(Vg, LL, Vs, tid);
    __syncthreads();
    short8 qf[2];
#pragma unroll
    for (int ks = 0; ks < 2; ++ks)
        qf[ks] = *(const short8*)(QP + SWZC(wid * 16 + l16, ks * 4 + quad));
    __syncthreads();   // all Q reads complete before P overwrites the region
    ushort* Pw = QP + wid * 1152;

    // ones B-fragment: 64x16 matrix with ones in column 0 (for P row-sums)
    short ov = (l16 == 0) ? (short)0x3F80 : (short)0;
    short8 onesf = {ov, ov, ov, ov, ov, ov, ov, ov};

    f32x4 ofr[5];   // [0..3]=O cols, [4]=row-sum l (lives in l16==0 lanes)
    float m_r[4];
#pragma unroll
    for (int nt = 0; nt < 5; ++nt) ofr[nt] = (f32x4){0.f, 0.f, 0.f, 0.f};
#pragma unroll
    for (int r = 0; r < 4; ++r) m_r[r] = -3e38f;

    for (int kt = 0; kt <= qt; ++kt) {
        int cur = kt & 1;
        int k0 = kt * 64;
        // gb loads first (oldest: waiting on them keeps V/K staging in flight)
        ushort gw[4][4];
#pragma unroll
        for (int r = 0; r < 4; ++r) {
            const ushort* gp = gbB + (size_t)(q0 + qrow + r) * LL + k0 + l16;
#pragma unroll
            for (int nt = 0; nt < 4; ++nt) gw[nt][r] = gp[nt * 16];
        }
        // V for this tile (single buffer; prior readers cleared by last barrier)
        if (kt > 0) stage_tile(Vg + k0, LL, Vs, tid);
        // K prefetch for next tile
        if (kt < qt) stage_tile(Kg + (size_t)(k0 + 64) * 64, 64, Ks[cur ^ 1], tid);

        f32x4 sf[4];
#pragma unroll
        for (int nt = 0; nt < 4; ++nt)
#pragma unroll
            for (int r = 0; r < 4; ++r) sf[nt][r] = b2f(gw[nt][r]);
#pragma unroll
        for (int ks = 0; ks < 2; ++ks)
#pragma unroll
            for (int nt = 0; nt < 4; ++nt) {
                short8 kf = *(const short8*)(Ks[cur] + SWZC(nt * 16 + l16, ks * 4 + quad));
                sf[nt] = __builtin_amdgcn_mfma_f32_16x16x32_bf16(qf[ks], kf, sf[nt], 0, 0, 0);
            }
        if (kt == qt) {
#pragma unroll
            for (int nt = 0; nt < 4; ++nt)
#pragma unroll
                for (int r = 0; r < 4; ++r)
                    if (nt * 16 + l16 > qrow + r) sf[nt][r] = -1e30f;
        }
        float alpha[4], mS[4];
#pragma unroll
        for (int r = 0; r < 4; ++r) {
            float m = fmaxf(fmaxf(sf[0][r], sf[1][r]), fmaxf(sf[2][r], sf[3][r]));
#pragma unroll
            for (int off = 1; off < 16; off <<= 1)
                m = fmaxf(m, __shfl_xor(m, off));
            float nm = fmaxf(m_r[r], m);
            alpha[r] = __builtin_amdgcn_exp2f((m_r[r] - nm) * SCL);
            m_r[r] = nm;
            mS[r] = nm * SCL;
        }
#pragma unroll
        for (int nt = 0; nt < 4; ++nt)
#pragma unroll
            for (int r = 0; r < 4; ++r) {
                float p = __builtin_amdgcn_exp2f(fmaf(sf[nt][r], SCL, -mS[r]));
                Pw[(quad * 4 + r) * 72 + nt * 16 + l16] = f2b(p);
            }
#pragma unroll
        for (int nt = 0; nt < 5; ++nt)
#pragma unroll
            for (int r = 0; r < 4; ++r) ofr[nt][r] *= alpha[r];
        short8 pf[2];
#pragma unroll
        for (int ks = 0; ks < 2; ++ks)
            pf[ks] = *(const short8*)(Pw + l16 * 72 + ks * 32 + quad * 8);
#pragma unroll
        for (int ks = 0; ks < 2; ++ks) {
#pragma unroll
            for (int nt = 0; nt < 4; ++nt) {
                short8 vf = *(const short8*)(Vs + SWZC(nt * 16 + l16, ks * 4 + quad));
                ofr[nt] = __builtin_amdgcn_mfma_f32_16x16x32_bf16(pf[ks], vf, ofr[nt], 0, 0, 0);
            }
            ofr[4] = __builtin_amdgcn_mfma_f32_16x16x32_bf16(pf[ks], onesf, ofr[4], 0, 0, 0);
        }
        __syncthreads();
    }
#pragma unroll
    for (int r = 0; r < 4; ++r) {
        float l = __shfl(ofr[4][r], (lane & 48));   // broadcast from l16==0 of this quad
        float rinv = 1.0f / l;
        float* op = attn_out + ((size_t)(b * LL) + q0 + qrow + r) * DD + h * 64 + l16;
#pragma unroll
        for (int nt = 0; nt < 4; ++nt)
            op[nt * 16] = ofr[nt][r] * rinv;
    }
    if (l16 == 0) {
#pragma unroll
        for (int r = 0; r < 4; ++r) {
            size_t si = (size_t)(q0 + qrow + r) * 2;
            stB[si]     = m_r[r];        // raw (QK+gb8) domain max
            stB[si + 1] = ofr[4][r];     // linear-domain sum
        }
    }
}

// ---------------- attn_w: double-buffered over heads, one barrier/head ----------------
__global__ __launch_bounds__(256, 4) void attn_w_mfma(
        const ushort* __restrict__ Q16, const ushort* __restrict__ K16,
        const ushort* __restrict__ gb16, const float* __restrict__ stats,
        float* __restrict__ aw) {
    int qt = blockIdx.x >> 5, kt = blockIdx.x & 31;
    int b = blockIdx.y;
    int tid = threadIdx.x, wid = tid >> 6, lane = tid & 63;
    int quad = lane >> 4, l16 = lane & 15;
    int q0 = qt * 64, k0 = kt * 64;
    int qrow = wid * 16 + quad * 4;
    if (kt > qt) {
        int rr = tid >> 2, c0 = (tid & 3) * 16;
        float4 zv = make_float4(0.f, 0.f, 0.f, 0.f);
        float* p = aw + ((size_t)(b * LL) + q0 + rr) * LL + k0 + c0;
#pragma unroll
        for (int j = 0; j < 4; ++j) *(float4*)(p + j * 4) = zv;
        return;
    }
    __shared__ ushort Qs[2][4096], Ks[2][4096];
    float acc[4][4];
#pragma unroll
    for (int nt = 0; nt < 4; ++nt)
#pragma unroll
        for (int r = 0; r < 4; ++r) acc[nt][r] = 0.f;
    f32x4 gacc[4];
    const ushort* gbB = gb16 + (size_t)b * LL * LL;
#pragma unroll
    for (int r = 0; r < 4; ++r) {
        const ushort* gp = gbB + (size_t)(q0 + qrow + r) * LL + k0 + l16;
#pragma unroll
        for (int nt = 0; nt < 4; ++nt) gacc[nt][r] = b2f(gp[nt * 16]);
    }
    bool diag = (kt == qt);
    stage_tile(Q16 + ((size_t)(b * 16) * LL + q0) * 64, 64, Qs[0], tid);
    stage_tile(K16 + ((size_t)(b * 16) * LL + k0) * 64, 64, Ks[0], tid);
    __syncthreads();
    for (int h = 0; h < NHH; ++h) {
        int cur = h & 1;
        float mS[4], li[4];
        const float* sp = stats + ((size_t)(b * 16 + h) * LL + q0 + qrow) * 2;
#pragma unroll
        for (int r = 0; r < 4; ++r) {
            mS[r] = sp[r * 2] * SCL;
            li[r] = 1.0f / sp[r * 2 + 1];
        }
        if (h < 15) {
            stage_tile(Q16 + ((size_t)(b * 16 + h + 1) * LL + q0) * 64, 64, Qs[cur ^ 1], tid);
            stage_tile(K16 + ((size_t)(b * 16 + h + 1) * LL + k0) * 64, 64, Ks[cur ^ 1], tid);
        }
        short8 qf[2];
#pragma unroll
        for (int ks = 0; ks < 2; ++ks)
            qf[ks] = *(const short8*)(Qs[cur] + SWZC(wid * 16 + l16, ks * 4 + quad));
        f32x4 sf[4];
#pragma unroll
        for (int nt = 0; nt < 4; ++nt) sf[nt] = gacc[nt];
#pragma unroll
        for (int ks = 0; ks < 2; ++ks)
#pragma unroll
            for (int nt = 0; nt < 4; ++nt) {
                short8 kf = *(const short8*)(Ks[cur] + SWZC(nt * 16 + l16, ks * 4 + quad));
                sf[nt] = __builtin_amdgcn_mfma_f32_16x16x32_bf16(qf[ks], kf, sf[nt], 0, 0, 0);
            }
#pragma unroll
        for (int nt = 0; nt < 4; ++nt)
#pragma unroll
            for (int r = 0; r < 4; ++r) {
                int row = qrow + r;
                if (!diag || (nt * 16 + l16 <= row))
                    acc[nt][r] += __builtin_amdgcn_exp2f(fmaf(sf[nt][r], SCL, -mS[r])) * li[r];
            }
        __syncthreads();
    }
#pragma unroll
    for (int r = 0; r < 4; ++r) {
        float* op = aw + ((size_t)(b * LL) + q0 + qrow + r) * LL + k0 + l16;
#pragma unroll
        for (int nt = 0; nt < 4; ++nt)
            op[nt * 16] = acc[nt][r] * 0.0625f;
    }
}

// ---------------- adv = -nu*U*G, layernorm -> adv_n (bf16 out) ----------------
__global__ __launch_bounds__(256) void adv_ln_kernel(
        const float* __restrict__ U, const float* __restrict__ G,
        const float* __restrict__ nub, const float* __restrict__ lnw,
        const float* __restrict__ lnb, ushort* __restrict__ out) {
    int row = blockIdx.x, tid = threadIdx.x;
    size_t base = (size_t)row * DD + tid * 4;
    float4 u4 = *(const float4*)&U[base];
    float4 g4 = *(const float4*)&G[base];
    float nu = nub[row];
    float a[4];
    a[0] = -nu * u4.x * g4.x;
    a[1] = -nu * u4.y * g4.y;
    a[2] = -nu * u4.z * g4.z;
    a[3] = -nu * u4.w * g4.w;
    float ts = a[0] + a[1] + a[2] + a[3];
    float tq = a[0] * a[0] + a[1] * a[1] + a[2] * a[2] + a[3] * a[3];
    for (int off = 32; off; off >>= 1) {
        ts += __shfl_down(ts, off);
        tq += __shfl_down(tq, off);
    }
    __shared__ float r1[4], r2[4];
    if ((tid & 63) == 0) { r1[tid >> 6] = ts; r2[tid >> 6] = tq; }
    __syncthreads();
    __shared__ float s_mu, s_rs;
    if (tid == 0) {
        float S  = r1[0] + r1[1] + r1[2] + r1[3];
        float Qq = r2[0] + r2[1] + r2[2] + r2[3];
        float mu = S * (1.0f / 1024.f);
        float var = Qq * (1.0f / 1024.f) - mu * mu;
        s_mu = mu;
        s_rs = rsqrtf(var + 1e-5f);
    }
    __syncthreads();
    float mu = s_mu, rs = s_rs;
    float4 w4 = *(const float4*)&lnw[tid * 4];
    float4 b4 = *(const float4*)&lnb[tid * 4];
    ushort4 ov;
    ov.x = f2b((a[0] - mu) * rs * w4.x + b4.x);
    ov.y = f2b((a[1] - mu) * rs * w4.y + b4.y);
    ov.z = f2b((a[2] - mu) * rs * w4.z + b4.z);
    ov.w = f2b((a[3] - mu) * rs * w4.w + b4.w);
    *(ushort4*)&out[base] = ov;
}

// ---------------- final residual combine ----------------
__global__ void final_kernel(const float* __restrict__ z, const float* __restrict__ ao,
                             const float* __restrict__ mlp, float* __restrict__ out) {
    size_t i = ((size_t)blockIdx.x * 256 + threadIdx.x) * 4;
    float4 z4 = *(const float4*)&z[i];
    float4 a4 = *(const float4*)&ao[i];
    float4 m4 = *(const float4*)&mlp[i];
    float4 o;
    o.x = z4.x + 0.42f * a4.x + 1.07f * m4.x;
    o.y = z4.y + 0.42f * a4.y + 1.07f * m4.y;
    o.z = z4.z + 0.42f * a4.z + 1.07f * m4.z;
    o.w = z4.w + 0.42f * a4.w + 1.07f * m4.w;
    *(float4*)&out[i] = o;
}

extern "C" void kernel_launch(void* const* d_in, const int* in_sizes, int n_in,
                              void* d_out, int out_size, void* d_ws, size_t ws_size,
                              hipStream_t stream) {
    const float* z       = (const float*)d_in[0];
    const float* Wq      = (const float*)d_in[1];
    const float* bq      = (const float*)d_in[2];
    const float* Wk      = (const float*)d_in[3];
    const float* bk      = (const float*)d_in[4];
    const float* Wv      = (const float*)d_in[5];
    const float* bv      = (const float*)d_in[6];
    const float* Wcoh    = (const float*)d_in[7];
    const float* gamma   = (const float*)d_in[8];
    const float* rg_w1   = (const float*)d_in[9];
    const float* rg_b1   = (const float*)d_in[10];
    const float* rg_w2   = (const float*)d_in[11];
    const float* rg_b2   = (const float*)d_in[12];
    const float* nu_diff = (const float*)d_in[13];
    const float* nu_adv  = (const float*)d_in[14];
    const float* nu_w1   = (const float*)d_in[15];
    const float* nu_b1   = (const float*)d_in[16];
    const float* nu_w2   = (const float*)d_in[17];
    const float* nu_b2   = (const float*)d_in[18];
    const float* Wu      = (const float*)d_in[19];
    const float* bu      = (const float*)d_in[20];
    const float* Wg      = (const float*)d_in[21];
    const float* bg      = (const float*)d_in[22];
    const float* ln_w    = (const float*)d_in[23];
    const float* ln_b    = (const float*)d_in[24];
    const float* Cw      = (const float*)d_in[25];
    const float* Cb      = (const float*)d_in[26];

    float* out_z  = (float*)d_out;
    float* out_aw = out_z + (size_t)MM * DD;

    float* ws = (float*)d_ws;
    const size_t MD = (size_t)MM * DD;   // 4,194,304
    float* pool  = ws;               // poolb (bf16, 8MB) then VT16 (bf16, reuses base)
    float* Qb    = ws + MD;          // later U, later mlp_out
    float* Kb    = ws + 2 * MD;      // later G
    float* Vb    = ws + 3 * MD;      // later Q16/K16 (bf16)
    float* gkb   = ws + 4 * MD;      // scan partials; then gk16+K16r (bf16); then attn_out
    float* gbb   = ws + 5 * MD;      // Ab(8MB) + Wb(8MB, 4 slots) + gb16(16MB)
    float* H1    = ws + 7 * MD;      // MM*256
    float* N1    = H1 + (size_t)MM * HG;
    float* gate  = N1 + (size_t)MM * HN;
    float* nub   = gate + MM;
    float* stats = nub + MM;                       // B*NH*L*2
    float* ctot  = stats + (size_t)BB * NHH * LL * 2;  // B*NCH*DD

    char* gbase  = (char*)gbb;
    ushort* Ab   = (ushort*)gbase;                               // zb / z_glu / adv_n
    ushort* Wb   = (ushort*)(gbase + (size_t)8 * 1024 * 1024);   // 4 transposed weight slots
    ushort* gb16 = (ushort*)(gbase + (size_t)16 * 1024 * 1024);  // gb8 bf16
    ushort* WtRG = Wb;                           // reuse slot 0 for rg after QKV
    ushort* WtNU = Wb + (size_t)1024 * 1024;     // slot 1 for nu
    ushort* Q16  = (ushort*)Vb;                  // [b,h,L,64]
    ushort* K16  = (ushort*)Vb + MD;             // [b,h,L,64]
    ushort* VT16 = (ushort*)pool;                // [b,h,64,L]
    ushort* poolb = (ushort*)pool;               // [b*L,1024] bf16 (dead before VT16)
    float*  part = gkb;                          // scan partials (fp32)
    ushort* gk16 = (ushort*)gkb;                 // [b*L,1024] bf16
    ushort* K16r = (ushort*)gkb + MD;            // [b*L,1024] bf16 (pre-RoPE K)

    dim3 g128(8, 32);
    dim3 wT_g(32, 32);

    // 1. pool scan (also emits z bf16 into Ab)
    pool_scan1<<<dim3(NCH, 4, BB), 256, 0, stream>>>(z, part, ctot, Ab);
    pool_scan2<<<dim3(NCH, 4, BB), 256, 0, stream>>>(part, ctot, poolb);
    // 2. weights QKV + Wcoh in one transpose-convert
    f2bT4_kernel<<<dim3(32, 32, 4), 256, 0, stream>>>(Wq, Wk, Wv, Wcoh, Wb);
    // 3. fused QKV GEMM (768 blocks); zid==1 also emits K16r bf16
    gemm_mfma3<<<dim3(8, 32, 3), 256, 0, stream>>>(Ab, Wb, bq, bk, bv, Qb, K16r);
    // 4. gk = poolb @ Wcoh (bf16 out, slot 3)
    gemm_mfma_b16out<<<g128, 256, 0, stream>>>(poolb, Wb + (size_t)3 * 1024 * 1024, gk16, DD);
    // 5. rg/nu weight transposes (slots 0,1 now free) + fused H1/N1 GEMM
    f2bT_rgnu<<<dim3(8, 32, 2), 256, 0, stream>>>(rg_w1, nu_w1, WtRG, WtNU);
    gemm_gates<<<dim3(3, 32), 256, 0, stream>>>(poolb, WtRG, WtNU, rg_b1, nu_b1, H1, N1);
    // 6. gb8 (MFMA, bf16 out)
    gb_mfma<<<dim3(256, BB), 256, 0, stream>>>(gk16, K16r, gamma, gb16);
    // 7. fused gate/nu finisher
    gatenu_fin<<<dim3(MM), 256, 0, stream>>>(H1, N1, rg_w2, rg_b2, nu_w2, nu_b2,
                                             nu_diff, nu_adv, gate, nub);
    // 8. V^T bf16 (poolb dead -> VT16 at pool base)
    vt16_kernel<<<dim3(32, 16, BB), 256, 0, stream>>>(Vb, VT16);
    // 9. rope Q,K -> bf16 head-blocked (into Vb region)
    rope_qk_bf16<<<dim3((MM * 512) / 256), 256, 0, stream>>>(Qb, Kb, gate, Q16, K16);
    // 10. MFMA flash attention (4 blocks/CU) -> attn_out (gkb) + stats
    attn_flash_mfma<<<dim3(NHH, 32, BB), 256, 0, stream>>>(Q16, K16, VT16, gb16, gkb, stats);
    // 11. attn_w -> second half of d_out
    attn_w_mfma<<<dim3(1024, BB), 256, 0, stream>>>(Q16, K16, gb16, stats, out_aw);
    // 12. z_glu bf16 directly into Ab
    rope_glu_b16<<<dim3((MM * 512) / 256), 256, 0, stream>>>(z, Ab);
    // 13. Wu/Wg/Cw transposes in one launch; fused U,G GEMM
    f2bT3_kernel<<<dim3(32, 32, 3), 256, 0, stream>>>(Wu, Wg, Cw, Wb);
    gemm_mfma3<<<dim3(8, 32, 2), 256, 0, stream>>>(Ab, Wb, bu, bg, bg, Qb, nullptr);
    // 14. adv + layernorm -> Ab (bf16, direct GEMM input)
    adv_ln_kernel<<<dim3(MM), 256, 0, stream>>>(Qb, Kb, nub, ln_w, ln_b, Ab);
    // 15. mlp_out = adv_n @ Cw + Cb -> Qb (slot 2 holds Cw^T)
    gemm_mfma<<<g128, 256, 0, stream>>>(Ab, Wb + (size_t)2 * 1024 * 1024, Cb, Qb, DD);
    // 16. final combine
    final_kernel<<<dim3(MD / 4 / 256), 256, 0, stream>>>(z, gkb, Qb, out_z);
}